// Round 2
// baseline (1711.041 us; speedup 1.0000x reference)
//
#include <hip/hip_runtime.h>

#define NEG_SLOPE 0.2f
#define EPS_F 1e-16f

__device__ __forceinline__ void atomicMaxFloat(float* addr, float v) {
    if (v >= 0.f) atomicMax((int*)addr, __float_as_int(v));
    else          atomicMin((unsigned int*)addr, __float_as_uint(v));
}

// Y[N,M] = X[N,K] @ W[K,M].  One block computes ROWS rows x all M cols.
template<int ROWS>
__global__ void gemm_kernel(const float* __restrict__ X, const float* __restrict__ W,
                            float* __restrict__ Y, int N, int K, int M) {
    extern __shared__ float xs[];  // ROWS * K
    int n0 = blockIdx.x * ROWS;
    for (int i = threadIdx.x; i < ROWS * K; i += blockDim.x) {
        int r = i / K, k = i - r * K;
        int n = n0 + r;
        xs[i] = (n < N) ? X[(size_t)n * K + k] : 0.f;
    }
    __syncthreads();
    for (int m = threadIdx.x; m < M; m += blockDim.x) {
        float acc[ROWS];
#pragma unroll
        for (int r = 0; r < ROWS; ++r) acc[r] = 0.f;
        for (int k = 0; k < K; ++k) {
            float wv = W[(size_t)k * M + m];
#pragma unroll
            for (int r = 0; r < ROWS; ++r) acc[r] += xs[r * K + k] * wv;
        }
#pragma unroll
        for (int r = 0; r < ROWS; ++r) {
            int n = n0 + r;
            if (n < N) Y[(size_t)n * M + m] = acc[r];
        }
    }
}

// alpha_src[n,h] = sum_c h[n,h,c]*a_src[h,c]; same for dst. One wave per (n,h).
__global__ void alpha_kernel(const float* __restrict__ h, const float* __restrict__ a_src,
                             const float* __restrict__ a_dst, float* __restrict__ as_out,
                             float* __restrict__ ad_out, int N, int H, int C) {
    int wid  = (blockIdx.x * blockDim.x + threadIdx.x) >> 6;
    int lane = threadIdx.x & 63;
    if (wid >= N * H) return;
    int n = wid / H, hh = wid - n * H;
    const float* hp  = h + (size_t)n * H * C + (size_t)hh * C;
    const float* asv = a_src + hh * C;
    const float* adv = a_dst + hh * C;
    float s1 = 0.f, s2 = 0.f;
    for (int c = lane; c < C; c += 64) {
        float v = hp[c];
        s1 += v * asv[c];
        s2 += v * adv[c];
    }
    for (int off = 32; off; off >>= 1) {
        s1 += __shfl_down(s1, off);
        s2 += __shfl_down(s2, off);
    }
    if (lane == 0) { as_out[wid] = s1; ad_out[wid] = s2; }
}

// Per edge: e = leaky_relu(as[src]+ad[dst]); store; atomic segment-max into m[dst].
__global__ void edge_score_max(const int* __restrict__ ei, int E, int N, int H,
                               const float* __restrict__ as, const float* __restrict__ ad,
                               float* __restrict__ esc, float* __restrict__ m) {
    int e = blockIdx.x * blockDim.x + threadIdx.x;
    int Etot = E + N;
    if (e >= Etot) return;
    int s, d;
    if (e < E) { s = ei[e]; d = ei[E + e]; } else { s = d = e - E; }
    for (int h = 0; h < H; ++h) {
        float v = as[s * H + h] + ad[d * H + h];
        v = (v > 0.f) ? v : NEG_SLOPE * v;
        esc[(size_t)e * H + h] = v;
        atomicMaxFloat(&m[d * H + h], v);
    }
}

// Per edge: ex = exp(e - m[dst]); overwrite esc; atomicAdd into s[dst].
__global__ void edge_exp_sum(const int* __restrict__ ei, int E, int N, int H,
                             const float* __restrict__ m, float* __restrict__ esc,
                             float* __restrict__ ssum) {
    int e = blockIdx.x * blockDim.x + threadIdx.x;
    int Etot = E + N;
    if (e >= Etot) return;
    int d;
    if (e < E) { d = ei[E + e]; } else { d = e - E; }
    for (int h = 0; h < H; ++h) {
        float ex = expf(esc[(size_t)e * H + h] - m[d * H + h]);
        esc[(size_t)e * H + h] = ex;
        atomicAdd(&ssum[d * H + h], ex);
    }
}

// agg[dst, c] += esc[e, h(c)] * h[src, c]   (unnormalized; normalized in finalize)
__global__ void aggregate_kernel(const int* __restrict__ ei, int E, int N, int H,
                                 int Mshift, int Cshift,
                                 const float* __restrict__ esc, const float* __restrict__ h,
                                 float* __restrict__ agg) {
    int M = 1 << Mshift;
    long long idx = (long long)blockIdx.x * blockDim.x + threadIdx.x;
    long long total = (long long)(E + N) << Mshift;
    if (idx >= total) return;
    int e = (int)(idx >> Mshift);
    int c = (int)(idx & (M - 1));
    int hh = c >> Cshift;
    int s, d;
    if (e < E) { s = ei[e]; d = ei[E + e]; } else { s = d = e - E; }
    float w = esc[(size_t)e * H + hh];
    atomicAdd(&agg[((size_t)d << Mshift) + c], w * h[((size_t)s << Mshift) + c]);
}

// io[n,c] = act( io[n,c]/(s[n,h]+eps) + bias[c] )
__global__ void finalize_kernel(float* __restrict__ io, const float* __restrict__ ssum,
                                const float* __restrict__ bias, int N, int H,
                                int Mshift, int Cshift, int do_relu) {
    int M = 1 << Mshift;
    long long idx = (long long)blockIdx.x * blockDim.x + threadIdx.x;
    long long total = (long long)N << Mshift;
    if (idx >= total) return;
    int n = (int)(idx >> Mshift);
    int c = (int)(idx & (M - 1));
    int hh = c >> Cshift;
    float v = io[idx] / (ssum[n * H + hh] + EPS_F) + bias[c];
    if (do_relu) v = fmaxf(v, 0.f);
    io[idx] = v;
}

// out[i] = dot(z[pa[i]], z[pb[i]]) over D dims. One wave per positive edge.
__global__ void decode_kernel(const int* __restrict__ pei, int Ep,
                              const float* __restrict__ z, int D,
                              float* __restrict__ out) {
    int wid  = (blockIdx.x * blockDim.x + threadIdx.x) >> 6;
    int lane = threadIdx.x & 63;
    if (wid >= Ep) return;
    int a = pei[wid], b = pei[Ep + wid];
    const float* za = z + (size_t)a * D;
    const float* zb = z + (size_t)b * D;
    float s = 0.f;
    for (int c = lane; c < D; c += 64) s += za[c] * zb[c];
    for (int off = 32; off; off >>= 1) s += __shfl_down(s, off);
    if (lane == 0) out[wid] = s;
}

static inline int ilog2(int v) { int s = 0; while ((1 << s) < v) ++s; return s; }

extern "C" void kernel_launch(void* const* d_in, const int* in_sizes, int n_in,
                              void* d_out, int out_size, void* d_ws, size_t ws_size,
                              hipStream_t stream) {
    const float* x   = (const float*)d_in[0];
    const int*   ei  = (const int*)d_in[1];
    const int*   pei = (const int*)d_in[2];
    const float* W1  = (const float*)d_in[3];
    const float* a1s = (const float*)d_in[4];
    const float* a1d = (const float*)d_in[5];
    const float* b1  = (const float*)d_in[6];
    const float* W2  = (const float*)d_in[7];
    const float* a2s = (const float*)d_in[8];
    const float* a2d = (const float*)d_in[9];
    const float* b2  = (const float*)d_in[10];
    float* out = (float*)d_out;

    const int M1  = in_sizes[6];            // 256 = H*C1
    const int Fin = in_sizes[3] / M1;       // 128
    const int N   = in_sizes[0] / Fin;      // 50000
    const int E   = in_sizes[1] / 2;        // 800000
    const int Ep  = in_sizes[2] / 2;        // 100000
    const int M2  = in_sizes[10];           // 128 = H*C2
    const int H   = 2;
    const int C1  = M1 / H, C2 = M2 / H;
    const int Etot = E + N;
    const int M1s = ilog2(M1), C1s = ilog2(C1);
    const int M2s = ilog2(M2), C2s = ilog2(C2);

    // workspace layout (floats)
    float* bufA = (float*)d_ws;                         // N*M1  (h_pre L1; then [h_pre2 | agg2] L2)
    float* bufB = bufA + (size_t)N * M1;                // N*M1  (agg1 -> h1 in place)
    float* esc  = bufB + (size_t)N * M1;                // Etot*H
    float* as_  = esc + (size_t)Etot * H;               // N*H
    float* ad_  = as_ + (size_t)N * H;                  // N*H
    float* mbuf = ad_ + (size_t)N * H;                  // N*H
    float* sbuf = mbuf + (size_t)N * H;                 // N*H

    const int ROWS = 8;
    dim3 blk256(256);

    // ---------------- Layer 1 ----------------
    {
        int gemm_grid = (N + ROWS - 1) / ROWS;
        gemm_kernel<ROWS><<<gemm_grid, blk256, ROWS * Fin * sizeof(float), stream>>>(
            x, W1, bufA, N, Fin, M1);

        int nwaves = N * H;
        alpha_kernel<<<(nwaves * 64 + 255) / 256, blk256, 0, stream>>>(
            bufA, a1s, a1d, as_, ad_, N, H, C1);

        hipMemsetAsync(mbuf, 0xFF, (size_t)N * H * sizeof(float), stream);
        hipMemsetAsync(sbuf, 0, (size_t)N * H * sizeof(float), stream);

        edge_score_max<<<(Etot + 255) / 256, blk256, 0, stream>>>(
            ei, E, N, H, as_, ad_, esc, mbuf);
        edge_exp_sum<<<(Etot + 255) / 256, blk256, 0, stream>>>(
            ei, E, N, H, mbuf, esc, sbuf);

        hipMemsetAsync(bufB, 0, (size_t)N * M1 * sizeof(float), stream);
        long long total = (long long)Etot << M1s;
        aggregate_kernel<<<(int)((total + 255) / 256), blk256, 0, stream>>>(
            ei, E, N, H, M1s, C1s, esc, bufA, bufB);

        long long ntot = (long long)N << M1s;
        finalize_kernel<<<(int)((ntot + 255) / 256), blk256, 0, stream>>>(
            bufB, sbuf, b1, N, H, M1s, C1s, 1);
    }

    // ---------------- Layer 2 ----------------
    float* hpre2 = bufA;                     // N*M2
    float* agg2  = bufA + (size_t)N * M2;    // N*M2
    {
        int gemm_grid = (N + ROWS - 1) / ROWS;
        gemm_kernel<ROWS><<<gemm_grid, blk256, ROWS * M1 * sizeof(float), stream>>>(
            bufB, W2, hpre2, N, M1, M2);

        int nwaves = N * H;
        alpha_kernel<<<(nwaves * 64 + 255) / 256, blk256, 0, stream>>>(
            hpre2, a2s, a2d, as_, ad_, N, H, C2);

        hipMemsetAsync(mbuf, 0xFF, (size_t)N * H * sizeof(float), stream);
        hipMemsetAsync(sbuf, 0, (size_t)N * H * sizeof(float), stream);

        edge_score_max<<<(Etot + 255) / 256, blk256, 0, stream>>>(
            ei, E, N, H, as_, ad_, esc, mbuf);
        edge_exp_sum<<<(Etot + 255) / 256, blk256, 0, stream>>>(
            ei, E, N, H, mbuf, esc, sbuf);

        hipMemsetAsync(agg2, 0, (size_t)N * M2 * sizeof(float), stream);
        long long total = (long long)Etot << M2s;
        aggregate_kernel<<<(int)((total + 255) / 256), blk256, 0, stream>>>(
            ei, E, N, H, M2s, C2s, esc, hpre2, agg2);

        long long ntot = (long long)N << M2s;
        finalize_kernel<<<(int)((ntot + 255) / 256), blk256, 0, stream>>>(
            agg2, sbuf, b2, N, H, M2s, C2s, 0);
    }

    // ---------------- Decode ----------------
    decode_kernel<<<(Ep * 64 + 255) / 256, blk256, 0, stream>>>(
        pei, Ep, agg2, M2, out);
}

// Round 3
// 704.420 us; speedup vs baseline: 2.4290x; 2.4290x over previous
//
#include <hip/hip_runtime.h>

#define NEG_SLOPE 0.2f
#define EPS_F 1e-16f

// ---------------- GEMM: Y[N,M] = X[N,K] @ W[K,M] ----------------
template<int ROWS>
__global__ void gemm_kernel(const float* __restrict__ X, const float* __restrict__ W,
                            float* __restrict__ Y, int N, int K, int M) {
    extern __shared__ float xs[];  // ROWS * K
    int n0 = blockIdx.x * ROWS;
    for (int i = threadIdx.x; i < ROWS * K; i += blockDim.x) {
        int r = i / K, k = i - r * K;
        int n = n0 + r;
        xs[i] = (n < N) ? X[(size_t)n * K + k] : 0.f;
    }
    __syncthreads();
    for (int m = threadIdx.x; m < M; m += blockDim.x) {
        float acc[ROWS];
#pragma unroll
        for (int r = 0; r < ROWS; ++r) acc[r] = 0.f;
        for (int k = 0; k < K; ++k) {
            float wv = W[(size_t)k * M + m];
#pragma unroll
            for (int r = 0; r < ROWS; ++r) acc[r] += xs[r * K + k] * wv;
        }
#pragma unroll
        for (int r = 0; r < ROWS; ++r) {
            int n = n0 + r;
            if (n < N) Y[(size_t)n * M + m] = acc[r];
        }
    }
}

// ---------------- alpha_src/dst[n,h] = sum_c h[n,h,c]*a[h,c]; one wave per (n,h) ----------------
__global__ void alpha_kernel(const float* __restrict__ h, const float* __restrict__ a_src,
                             const float* __restrict__ a_dst, float* __restrict__ as_out,
                             float* __restrict__ ad_out, int N, int H, int C) {
    int wid  = (blockIdx.x * blockDim.x + threadIdx.x) >> 6;
    int lane = threadIdx.x & 63;
    if (wid >= N * H) return;
    int n = wid / H, hh = wid - n * H;
    const float* hp  = h + (size_t)n * H * C + (size_t)hh * C;
    const float* asv = a_src + hh * C;
    const float* adv = a_dst + hh * C;
    float s1 = 0.f, s2 = 0.f;
    for (int c = lane; c < C; c += 64) {
        float v = hp[c];
        s1 += v * asv[c];
        s2 += v * adv[c];
    }
    for (int off = 32; off; off >>= 1) {
        s1 += __shfl_down(s1, off);
        s2 += __shfl_down(s2, off);
    }
    if (lane == 0) { as_out[wid] = s1; ad_out[wid] = s2; }
}

// ---------------- CSR build ----------------
__global__ void hist_kernel(const int* __restrict__ ei, int E, int N, int* __restrict__ deg) {
    int e = blockIdx.x * blockDim.x + threadIdx.x;
    if (e >= E + N) return;
    int d = (e < E) ? ei[E + e] : e - E;
    atomicAdd(&deg[d], 1);
}

// single-block exclusive scan; rowptr[N] = total
__global__ void scan_kernel(const int* __restrict__ deg, int* __restrict__ rowptr, int N) {
    __shared__ int tmp[1024];
    __shared__ int carry_sh;
    int tid = threadIdx.x;
    if (tid == 0) carry_sh = 0;
    __syncthreads();
    for (int base = 0; base < N; base += 1024) {
        int i = base + tid;
        int v = (i < N) ? deg[i] : 0;
        tmp[tid] = v;
        __syncthreads();
        for (int off = 1; off < 1024; off <<= 1) {
            int add = (tid >= off) ? tmp[tid - off] : 0;
            __syncthreads();
            tmp[tid] += add;
            __syncthreads();
        }
        int carry = carry_sh;
        if (i < N) rowptr[i] = carry + tmp[tid] - v;   // exclusive
        __syncthreads();
        if (tid == 1023) carry_sh = carry + tmp[1023];
        __syncthreads();
    }
    if (tid == 0) rowptr[N] = carry_sh;
}

__global__ void fill_kernel(const int* __restrict__ ei, int E, int N,
                            const int* __restrict__ rowptr, int* __restrict__ cursor,
                            int* __restrict__ csr_src) {
    int e = blockIdx.x * blockDim.x + threadIdx.x;
    if (e >= E + N) return;
    int s, d;
    if (e < E) { s = ei[e]; d = ei[E + e]; } else { s = d = e - E; }
    int pos = atomicAdd(&cursor[d], 1);
    csr_src[rowptr[d] + pos] = s;
}

// ---------------- fused per-dst online-softmax + aggregation ----------------
// One block of M threads per destination node. Thread c owns output channel c.
// Online softmax per head over chunks of <=M in-edges staged in LDS.
template<int M, int C>
__global__ void fused_attn_agg(const int* __restrict__ rowptr, const int* __restrict__ csr_src,
                               const float* __restrict__ as_, const float* __restrict__ ad_,
                               const float* __restrict__ hfeat, const float* __restrict__ bias,
                               float* __restrict__ outp, int do_relu) {
    __shared__ float sc[M][2];
    __shared__ int   ssrc[M];
    int n  = blockIdx.x;
    int c  = threadIdx.x;
    int hh = c / C;
    int r0 = rowptr[n], r1 = rowptr[n + 1];
    float adv0 = ad_[n * 2 + 0], adv1 = ad_[n * 2 + 1];
    float m_old = -INFINITY;
    float acc = 0.f, ssum = 0.f;
    for (int base = r0; base < r1; base += M) {
        int cnt = min(M, r1 - base);
        if (c < cnt) {
            int s = csr_src[base + c];
            ssrc[c] = s;
            float e0 = as_[s * 2 + 0] + adv0;
            float e1 = as_[s * 2 + 1] + adv1;
            sc[c][0] = (e0 > 0.f) ? e0 : NEG_SLOPE * e0;
            sc[c][1] = (e1 > 0.f) ? e1 : NEG_SLOPE * e1;
        }
        __syncthreads();
        float m_new = m_old;
        for (int e = 0; e < cnt; ++e) m_new = fmaxf(m_new, sc[e][hh]);
        float f = expf(m_old - m_new);          // 0 on first chunk (m_old = -inf)
        acc  *= f;
        ssum *= f;
        for (int e = 0; e < cnt; ++e) {
            float ex = expf(sc[e][hh] - m_new);
            acc  += ex * hfeat[(size_t)ssrc[e] * M + c];
            ssum += ex;
        }
        m_old = m_new;
        __syncthreads();
    }
    float v = acc / (ssum + EPS_F) + bias[c];
    if (do_relu) v = fmaxf(v, 0.f);
    outp[(size_t)n * M + c] = v;
}

// ---------------- decode: out[i] = dot(z[a], z[b]); one wave per positive edge ----------------
__global__ void decode_kernel(const int* __restrict__ pei, int Ep,
                              const float* __restrict__ z, int D,
                              float* __restrict__ out) {
    int wid  = (blockIdx.x * blockDim.x + threadIdx.x) >> 6;
    int lane = threadIdx.x & 63;
    if (wid >= Ep) return;
    int a = pei[wid], b = pei[Ep + wid];
    const float* za = z + (size_t)a * D;
    const float* zb = z + (size_t)b * D;
    float s = 0.f;
    for (int c = lane; c < D; c += 64) s += za[c] * zb[c];
    for (int off = 32; off; off >>= 1) s += __shfl_down(s, off);
    if (lane == 0) out[wid] = s;
}

extern "C" void kernel_launch(void* const* d_in, const int* in_sizes, int n_in,
                              void* d_out, int out_size, void* d_ws, size_t ws_size,
                              hipStream_t stream) {
    const float* x   = (const float*)d_in[0];
    const int*   ei  = (const int*)d_in[1];
    const int*   pei = (const int*)d_in[2];
    const float* W1  = (const float*)d_in[3];
    const float* a1s = (const float*)d_in[4];
    const float* a1d = (const float*)d_in[5];
    const float* b1  = (const float*)d_in[6];
    const float* W2  = (const float*)d_in[7];
    const float* a2s = (const float*)d_in[8];
    const float* a2d = (const float*)d_in[9];
    const float* b2  = (const float*)d_in[10];
    float* out = (float*)d_out;

    const int M1  = in_sizes[6];            // 256 = H*C1
    const int Fin = in_sizes[3] / M1;       // 128
    const int N   = in_sizes[0] / Fin;      // 50000
    const int E   = in_sizes[1] / 2;        // 800000
    const int Ep  = in_sizes[2] / 2;        // 100000
    const int M2  = in_sizes[10];           // 128 = H*C2
    const int H   = 2;
    const int C1  = M1 / H, C2 = M2 / H;
    const int Etot = E + N;

    // workspace layout
    float* bufA    = (float*)d_ws;                      // N*M1
    float* bufB    = bufA + (size_t)N * M1;             // N*M1
    float* as_     = bufB + (size_t)N * M1;             // N*H
    float* ad_     = as_ + (size_t)N * H;               // N*H
    int*   deg     = (int*)(ad_ + (size_t)N * H);       // N
    int*   rowptr  = deg + N;                           // N+1
    int*   cursor  = rowptr + (N + 1);                  // N
    int*   csr_src = cursor + N;                        // Etot

    const int ROWS = 8;
    dim3 blk256(256);

    // ---- CSR build (shared by both layers) ----
    hipMemsetAsync(deg, 0, (size_t)N * sizeof(int), stream);
    hipMemsetAsync(cursor, 0, (size_t)N * sizeof(int), stream);
    hist_kernel<<<(Etot + 255) / 256, blk256, 0, stream>>>(ei, E, N, deg);
    scan_kernel<<<1, 1024, 0, stream>>>(deg, rowptr, N);
    fill_kernel<<<(Etot + 255) / 256, blk256, 0, stream>>>(ei, E, N, rowptr, cursor, csr_src);

    // ---- Layer 1: x(bufA via gemm) -> h1 in bufB ----
    {
        int gemm_grid = (N + ROWS - 1) / ROWS;
        gemm_kernel<ROWS><<<gemm_grid, blk256, ROWS * Fin * sizeof(float), stream>>>(
            x, W1, bufA, N, Fin, M1);
        alpha_kernel<<<(N * H * 64 + 255) / 256, blk256, 0, stream>>>(
            bufA, a1s, a1d, as_, ad_, N, H, C1);
        fused_attn_agg<256, 128><<<N, 256, 0, stream>>>(
            rowptr, csr_src, as_, ad_, bufA, b1, bufB, 1);
    }

    // ---- Layer 2: h1(bufB) -> z in bufB ----
    {
        int gemm_grid = (N + ROWS - 1) / ROWS;
        gemm_kernel<ROWS><<<gemm_grid, blk256, ROWS * M1 * sizeof(float), stream>>>(
            bufB, W2, bufA, N, M1, M2);
        alpha_kernel<<<(N * H * 64 + 255) / 256, blk256, 0, stream>>>(
            bufA, a2s, a2d, as_, ad_, N, H, C2);
        fused_attn_agg<128, 64><<<N, 128, 0, stream>>>(
            rowptr, csr_src, as_, ad_, bufA, b2, bufB, 0);
    }

    // ---- Decode ----
    decode_kernel<<<(Ep * 64 + 255) / 256, blk256, 0, stream>>>(
        pei, Ep, bufB, M2, out);
}

// Round 4
// 619.091 us; speedup vs baseline: 2.7638x; 1.1378x over previous
//
#include <hip/hip_runtime.h>

#define NEG_SLOPE 0.2f
#define EPS_F 1e-16f

// ---------------- GEMM: Y[N,M] = X[N,K] @ W[K,M] ----------------
template<int ROWS>
__global__ void gemm_kernel(const float* __restrict__ X, const float* __restrict__ W,
                            float* __restrict__ Y, int N, int K, int M) {
    extern __shared__ float xs[];  // ROWS * K
    int n0 = blockIdx.x * ROWS;
    for (int i = threadIdx.x; i < ROWS * K; i += blockDim.x) {
        int r = i / K, k = i - r * K;
        int n = n0 + r;
        xs[i] = (n < N) ? X[(size_t)n * K + k] : 0.f;
    }
    __syncthreads();
    for (int m = threadIdx.x; m < M; m += blockDim.x) {
        float acc[ROWS];
#pragma unroll
        for (int r = 0; r < ROWS; ++r) acc[r] = 0.f;
        for (int k = 0; k < K; ++k) {
            float wv = W[(size_t)k * M + m];
#pragma unroll
            for (int r = 0; r < ROWS; ++r) acc[r] += xs[r * K + k] * wv;
        }
#pragma unroll
        for (int r = 0; r < ROWS; ++r) {
            int n = n0 + r;
            if (n < N) Y[(size_t)n * M + m] = acc[r];
        }
    }
}

// ---------------- alpha_src/dst[n,h] = sum_c h[n,h,c]*a[h,c]; one wave per (n,h) ----------------
__global__ void alpha_kernel(const float* __restrict__ h, const float* __restrict__ a_src,
                             const float* __restrict__ a_dst, float* __restrict__ as_out,
                             float* __restrict__ ad_out, int N, int H, int C) {
    int wid  = (blockIdx.x * blockDim.x + threadIdx.x) >> 6;
    int lane = threadIdx.x & 63;
    if (wid >= N * H) return;
    int n = wid / H, hh = wid - n * H;
    const float* hp  = h + (size_t)n * H * C + (size_t)hh * C;
    const float* asv = a_src + hh * C;
    const float* adv = a_dst + hh * C;
    float s1 = 0.f, s2 = 0.f;
    for (int c = lane; c < C; c += 64) {
        float v = hp[c];
        s1 += v * asv[c];
        s2 += v * adv[c];
    }
    for (int off = 32; off; off >>= 1) {
        s1 += __shfl_down(s1, off);
        s2 += __shfl_down(s2, off);
    }
    if (lane == 0) { as_out[wid] = s1; ad_out[wid] = s2; }
}

// ---------------- CSR build ----------------
__global__ void hist_kernel(const int* __restrict__ ei, int E, int N, int* __restrict__ deg) {
    int e = blockIdx.x * blockDim.x + threadIdx.x;
    if (e >= E + N) return;
    int d = (e < E) ? ei[E + e] : e - E;
    atomicAdd(&deg[d], 1);
}

// single-block exclusive scan via wave shfl; rowptr[N] = total
__global__ void scan_kernel(const int* __restrict__ deg, int* __restrict__ rowptr, int N) {
    __shared__ int wsum[16];
    __shared__ int carry_sh;
    int tid = threadIdx.x, lane = tid & 63, wid = tid >> 6;
    if (tid == 0) carry_sh = 0;
    __syncthreads();
    for (int base = 0; base < N; base += 1024) {
        int i = base + tid;
        int v = (i < N) ? deg[i] : 0;
        int x = v;  // inclusive wave scan
#pragma unroll
        for (int off = 1; off < 64; off <<= 1) {
            int y = __shfl_up(x, off);
            if (lane >= off) x += y;
        }
        if (lane == 63) wsum[wid] = x;
        __syncthreads();
        if (wid == 0 && lane < 16) {
            int w = wsum[lane];
            int xx = w;
#pragma unroll
            for (int off = 1; off < 16; off <<= 1) {
                int y = __shfl_up(xx, off);
                if (lane >= off) xx += y;
            }
            wsum[lane] = xx - w;  // exclusive wave-sum prefix
        }
        __syncthreads();
        int carry = carry_sh;
        if (i < N) rowptr[i] = carry + wsum[wid] + x - v;
        __syncthreads();
        if (tid == 1023) carry_sh = carry + wsum[15] + x;
        __syncthreads();
    }
    if (threadIdx.x == 0) rowptr[N] = carry_sh;
}

__global__ void fill_kernel(const int* __restrict__ ei, int E, int N,
                            const int* __restrict__ rowptr, int* __restrict__ cursor,
                            int* __restrict__ csr_src) {
    int e = blockIdx.x * blockDim.x + threadIdx.x;
    if (e >= E + N) return;
    int s, d;
    if (e < E) { s = ei[e]; d = ei[E + e]; } else { s = d = e - E; }
    int pos = atomicAdd(&cursor[d], 1);
    csr_src[rowptr[d] + pos] = s;
}

// ---------------- fused per-dst online-softmax + aggregation (v2) ----------------
// One block of M threads per destination node; thread c owns output channel c.
// Chunked online softmax; exp computed ONCE per (edge,head) in LDS; denom via
// wave shuffle-reduce. Inner loop: 1 LDS broadcast + 1 gather fma per edge-channel.
template<int M, int C>
__global__ void fused_attn_agg(const int* __restrict__ rowptr, const int* __restrict__ csr_src,
                               const float* __restrict__ as_, const float* __restrict__ ad_,
                               const float* __restrict__ hfeat, const float* __restrict__ bias,
                               float* __restrict__ outp, int do_relu) {
    __shared__ float sc[M][2];   // raw leaky-relu scores
    __shared__ float px[M][2];   // exp(score - m_new)
    __shared__ int   ssrc[M];
    int n    = blockIdx.x;
    int c    = threadIdx.x;
    int lane = c & 63;
    int hh   = c / C;
    int r0 = rowptr[n], r1 = rowptr[n + 1];
    const float2* as2 = (const float2*)as_;
    float2 adv = ((const float2*)ad_)[n];
    float m0 = -INFINITY, m1 = -INFINITY;   // running maxes, both heads (uniform)
    float s0 = 0.f, s1 = 0.f;               // running denoms, both heads (uniform)
    float acc = 0.f;
    for (int base = r0; base < r1; base += M) {
        int cnt = min(M, r1 - base);
        if (c < cnt) {
            int s = csr_src[base + c];
            ssrc[c] = s;
            float2 asv = as2[s];
            float e0 = asv.x + adv.x;
            float e1 = asv.y + adv.y;
            sc[c][0] = (e0 > 0.f) ? e0 : NEG_SLOPE * e0;
            sc[c][1] = (e1 > 0.f) ? e1 : NEG_SLOPE * e1;
        }
        __syncthreads();
        // chunk max for both heads (each wave computes the full reduction)
        float pm0 = -INFINITY, pm1 = -INFINITY;
#pragma unroll
        for (int k = 0; k < M / 64; ++k) {
            int e = lane + 64 * k;
            if (e < cnt) { pm0 = fmaxf(pm0, sc[e][0]); pm1 = fmaxf(pm1, sc[e][1]); }
        }
#pragma unroll
        for (int off = 32; off; off >>= 1) {
            pm0 = fmaxf(pm0, __shfl_xor(pm0, off));
            pm1 = fmaxf(pm1, __shfl_xor(pm1, off));
        }
        float mn0 = fmaxf(m0, pm0), mn1 = fmaxf(m1, pm1);
        // stage exp once per (edge,head)
        if (c < cnt) {
            px[c][0] = expf(sc[c][0] - mn0);
            px[c][1] = expf(sc[c][1] - mn1);
        }
        // rescale running state (f = 0 on first chunk since m = -inf)
        float f0 = expf(m0 - mn0), f1 = expf(m1 - mn1);
        s0 *= f0; s1 *= f1;
        acc *= (hh == 0) ? f0 : f1;
        m0 = mn0; m1 = mn1;
        __syncthreads();
        // chunk denominator, wave-parallel
        float ps0 = 0.f, ps1 = 0.f;
#pragma unroll
        for (int k = 0; k < M / 64; ++k) {
            int e = lane + 64 * k;
            if (e < cnt) { ps0 += px[e][0]; ps1 += px[e][1]; }
        }
#pragma unroll
        for (int off = 32; off; off >>= 1) {
            ps0 += __shfl_xor(ps0, off);
            ps1 += __shfl_xor(ps1, off);
        }
        s0 += ps0; s1 += ps1;
        // accumulate: irreducible gather-fma
        for (int e = 0; e < cnt; ++e) {
            acc += px[e][hh] * hfeat[(size_t)ssrc[e] * M + c];
        }
        __syncthreads();
    }
    float ssum = (hh == 0) ? s0 : s1;
    float v = acc / (ssum + EPS_F) + bias[c];
    if (do_relu) v = fmaxf(v, 0.f);
    outp[(size_t)n * M + c] = v;
}

// ---------------- decode: out[i] = dot(z[a], z[b]); one wave per positive edge ----------------
__global__ void decode_kernel(const int* __restrict__ pei, int Ep,
                              const float* __restrict__ z, int D,
                              float* __restrict__ out) {
    int wid  = (blockIdx.x * blockDim.x + threadIdx.x) >> 6;
    int lane = threadIdx.x & 63;
    if (wid >= Ep) return;
    int a = pei[wid], b = pei[Ep + wid];
    const float* za = z + (size_t)a * D;
    const float* zb = z + (size_t)b * D;
    float s = 0.f;
    for (int c = lane; c < D; c += 64) s += za[c] * zb[c];
    for (int off = 32; off; off >>= 1) s += __shfl_down(s, off);
    if (lane == 0) out[wid] = s;
}

extern "C" void kernel_launch(void* const* d_in, const int* in_sizes, int n_in,
                              void* d_out, int out_size, void* d_ws, size_t ws_size,
                              hipStream_t stream) {
    const float* x   = (const float*)d_in[0];
    const int*   ei  = (const int*)d_in[1];
    const int*   pei = (const int*)d_in[2];
    const float* W1  = (const float*)d_in[3];
    const float* a1s = (const float*)d_in[4];
    const float* a1d = (const float*)d_in[5];
    const float* b1  = (const float*)d_in[6];
    const float* W2  = (const float*)d_in[7];
    const float* a2s = (const float*)d_in[8];
    const float* a2d = (const float*)d_in[9];
    const float* b2  = (const float*)d_in[10];
    float* out = (float*)d_out;

    const int M1  = in_sizes[6];            // 256 = H*C1
    const int Fin = in_sizes[3] / M1;       // 128
    const int N   = in_sizes[0] / Fin;      // 50000
    const int E   = in_sizes[1] / 2;        // 800000
    const int Ep  = in_sizes[2] / 2;        // 100000
    const int M2  = in_sizes[10];           // 128 = H*C2
    const int H   = 2;
    const int C1  = M1 / H, C2 = M2 / H;
    const int Etot = E + N;

    // workspace layout
    float* bufA    = (float*)d_ws;                      // N*M1
    float* bufB    = bufA + (size_t)N * M1;             // N*M1
    float* as_     = bufB + (size_t)N * M1;             // N*H
    float* ad_     = as_ + (size_t)N * H;               // N*H
    int*   deg     = (int*)(ad_ + (size_t)N * H);       // N
    int*   rowptr  = deg + N;                           // N+1
    int*   cursor  = rowptr + (N + 1);                  // N
    int*   csr_src = cursor + N;                        // Etot

    const int ROWS = 8;
    dim3 blk256(256);

    // ---- CSR build (shared by both layers) ----
    hipMemsetAsync(deg, 0, (size_t)N * sizeof(int), stream);
    hipMemsetAsync(cursor, 0, (size_t)N * sizeof(int), stream);
    hist_kernel<<<(Etot + 255) / 256, blk256, 0, stream>>>(ei, E, N, deg);
    scan_kernel<<<1, 1024, 0, stream>>>(deg, rowptr, N);
    fill_kernel<<<(Etot + 255) / 256, blk256, 0, stream>>>(ei, E, N, rowptr, cursor, csr_src);

    // ---- Layer 1: x -> gemm(bufA) -> attn -> h1 (bufB) ----
    {
        int gemm_grid = (N + ROWS - 1) / ROWS;
        gemm_kernel<ROWS><<<gemm_grid, blk256, ROWS * Fin * sizeof(float), stream>>>(
            x, W1, bufA, N, Fin, M1);
        alpha_kernel<<<(N * H * 64 + 255) / 256, blk256, 0, stream>>>(
            bufA, a1s, a1d, as_, ad_, N, H, C1);
        fused_attn_agg<256, 128><<<N, 256, 0, stream>>>(
            rowptr, csr_src, as_, ad_, bufA, b1, bufB, 1);
    }

    // ---- Layer 2: h1 (bufB) -> gemm(bufA) -> attn -> z (bufB) ----
    {
        int gemm_grid = (N + ROWS - 1) / ROWS;
        gemm_kernel<ROWS><<<gemm_grid, blk256, ROWS * M1 * sizeof(float), stream>>>(
            bufB, W2, bufA, N, M1, M2);
        alpha_kernel<<<(N * H * 64 + 255) / 256, blk256, 0, stream>>>(
            bufA, a2s, a2d, as_, ad_, N, H, C2);
        fused_attn_agg<128, 64><<<N, 128, 0, stream>>>(
            rowptr, csr_src, as_, ad_, bufA, b2, bufB, 0);
    }

    // ---- Decode ----
    decode_kernel<<<(Ep * 64 + 255) / 256, blk256, 0, stream>>>(
        pei, Ep, bufB, M2, out);
}

// Round 5
// 558.710 us; speedup vs baseline: 3.0625x; 1.1081x over previous
//
#include <hip/hip_runtime.h>

#define NEG_SLOPE 0.2f
#define EPS_F 1e-16f

// ---------------- GEMM v2: Y[N,MB] = X[N,K] @ W[K,MB], 8x8 register tiles ----------------
template<int MB>
__global__ __launch_bounds__(256) void gemm_tiled(const float* __restrict__ X,
                                                  const float* __restrict__ W,
                                                  float* __restrict__ Y, int N, int K) {
    constexpr int TM = 8, TN = 8;
    constexpr int CB = MB / TN;        // col-blocks: 32 (MB=256) or 16 (MB=128)
    constexpr int RB = 256 / CB;       // row-blocks: 8 or 16
    constexpr int BN = RB * TM;        // 64 or 128 rows per block
    constexpr int KT = 16;
    __shared__ float xs[BN][KT + 4];   // +4 pad: keeps float4 alignment, spreads banks
    __shared__ float ws[KT][MB];
    int tid = threadIdx.x;
    int cb = tid % CB, rb = tid / CB;
    int n0 = blockIdx.x * BN;
    int row0 = rb * TM;
    int col0 = cb * TN;
    float acc[TM][TN];
#pragma unroll
    for (int r = 0; r < TM; ++r)
#pragma unroll
        for (int c = 0; c < TN; ++c) acc[r][c] = 0.f;

    for (int k0 = 0; k0 < K; k0 += KT) {
        // stage X tile: BN*KT floats as float4
        constexpr int XL = BN * KT / (256 * 4);
#pragma unroll
        for (int i = 0; i < XL; ++i) {
            int fid = tid + i * 256;
            int r = fid / (KT / 4);
            int kq = fid % (KT / 4);
            int n = n0 + r;
            float4 v = make_float4(0.f, 0.f, 0.f, 0.f);
            if (n < N) v = *(const float4*)&X[(size_t)n * K + k0 + kq * 4];
            *(float4*)&xs[r][kq * 4] = v;
        }
        // stage W tile: KT*MB floats as float4
        constexpr int WL = KT * MB / (256 * 4);
#pragma unroll
        for (int i = 0; i < WL; ++i) {
            int fid = tid + i * 256;
            int kk = fid / (MB / 4);
            int mq = fid % (MB / 4);
            *(float4*)&ws[kk][mq * 4] = *(const float4*)&W[(size_t)(k0 + kk) * MB + mq * 4];
        }
        __syncthreads();
#pragma unroll
        for (int k = 0; k < KT; ++k) {
            float xv[TM], wv[TN];
#pragma unroll
            for (int r = 0; r < TM; ++r) xv[r] = xs[row0 + r][k];
            *(float4*)&wv[0] = *(float4*)&ws[k][col0];
            *(float4*)&wv[4] = *(float4*)&ws[k][col0 + 4];
#pragma unroll
            for (int r = 0; r < TM; ++r)
#pragma unroll
                for (int c = 0; c < TN; ++c) acc[r][c] += xv[r] * wv[c];
        }
        __syncthreads();
    }
#pragma unroll
    for (int r = 0; r < TM; ++r) {
        int n = n0 + row0 + r;
        if (n < N) {
            *(float4*)&Y[(size_t)n * MB + col0]     = *(float4*)&acc[r][0];
            *(float4*)&Y[(size_t)n * MB + col0 + 4] = *(float4*)&acc[r][4];
        }
    }
}

// ---------------- alpha: one wave per (n,h), float2 loads ----------------
__global__ void alpha_kernel(const float* __restrict__ h, const float* __restrict__ a_src,
                             const float* __restrict__ a_dst, float* __restrict__ as_out,
                             float* __restrict__ ad_out, int N, int H, int C) {
    int wid  = (blockIdx.x * blockDim.x + threadIdx.x) >> 6;
    int lane = threadIdx.x & 63;
    if (wid >= N * H) return;
    int n = wid / H, hh = wid - n * H;
    const float2* hp  = (const float2*)(h + (size_t)n * H * C + (size_t)hh * C);
    const float2* asv = (const float2*)(a_src + hh * C);
    const float2* adv = (const float2*)(a_dst + hh * C);
    float s1 = 0.f, s2 = 0.f;
    for (int i = lane; i < C / 2; i += 64) {
        float2 v = hp[i], a1 = asv[i], a2 = adv[i];
        s1 += v.x * a1.x + v.y * a1.y;
        s2 += v.x * a2.x + v.y * a2.y;
    }
    for (int off = 32; off; off >>= 1) {
        s1 += __shfl_down(s1, off);
        s2 += __shfl_down(s2, off);
    }
    if (lane == 0) { as_out[wid] = s1; ad_out[wid] = s2; }
}

// ---------------- CSR build ----------------
__global__ void hist_kernel(const int* __restrict__ ei, int E, int N, int* __restrict__ deg) {
    int e = blockIdx.x * blockDim.x + threadIdx.x;
    if (e >= E + N) return;
    int d = (e < E) ? ei[E + e] : e - E;
    atomicAdd(&deg[d], 1);
}

__global__ void scan_kernel(const int* __restrict__ deg, int* __restrict__ rowptr, int N) {
    __shared__ int wsum[16];
    __shared__ int carry_sh;
    int tid = threadIdx.x, lane = tid & 63, wid = tid >> 6;
    if (tid == 0) carry_sh = 0;
    __syncthreads();
    for (int base = 0; base < N; base += 1024) {
        int i = base + tid;
        int v = (i < N) ? deg[i] : 0;
        int x = v;
#pragma unroll
        for (int off = 1; off < 64; off <<= 1) {
            int y = __shfl_up(x, off);
            if (lane >= off) x += y;
        }
        if (lane == 63) wsum[wid] = x;
        __syncthreads();
        if (wid == 0 && lane < 16) {
            int w = wsum[lane];
            int xx = w;
#pragma unroll
            for (int off = 1; off < 16; off <<= 1) {
                int y = __shfl_up(xx, off);
                if (lane >= off) xx += y;
            }
            wsum[lane] = xx - w;
        }
        __syncthreads();
        int carry = carry_sh;
        if (i < N) rowptr[i] = carry + wsum[wid] + x - v;
        __syncthreads();
        if (tid == 1023) carry_sh = carry + wsum[15] + x;
        __syncthreads();
    }
    if (threadIdx.x == 0) rowptr[N] = carry_sh;
}

__global__ void fill_kernel(const int* __restrict__ ei, int E, int N,
                            const int* __restrict__ rowptr, int* __restrict__ cursor,
                            int* __restrict__ csr_src) {
    int e = blockIdx.x * blockDim.x + threadIdx.x;
    if (e >= E + N) return;
    int s, d;
    if (e < E) { s = ei[e]; d = ei[E + e]; } else { s = d = e - E; }
    int pos = atomicAdd(&cursor[d], 1);
    csr_src[rowptr[d] + pos] = s;
}

// ---------------- fused attn+agg v3: vectorized gather, per-wave edge split ----------------
// Block = 256 threads = 4 waves per dst node. Lane owns VEC=M/64 channels (same head).
// Wave w processes edges e ≡ w (mod 4) of each chunk; cross-wave reduce at the end.
template<int M, int C>
__global__ __launch_bounds__(256) void fused_attn_agg(
        const int* __restrict__ rowptr, const int* __restrict__ csr_src,
        const float* __restrict__ as_, const float* __restrict__ ad_,
        const float* __restrict__ hfeat, const float* __restrict__ bias,
        float* __restrict__ outp, int do_relu) {
    constexpr int VEC = M / 64;   // 4 (L1) or 2 (L2)
    constexpr int CH  = 256;
    __shared__ float sc[CH][2];
    __shared__ float px[CH][2];
    __shared__ int   ssrc[CH];
    __shared__ float partial[4][M];
    int n    = blockIdx.x;
    int tid  = threadIdx.x;
    int lane = tid & 63, w = tid >> 6;
    int cbase = lane * VEC;
    int hh    = cbase / C;        // uniform over the lane's VEC channels
    int r0 = rowptr[n], r1 = rowptr[n + 1];
    const float2* as2 = (const float2*)as_;
    float2 adv = ((const float2*)ad_)[n];
    float m0 = -INFINITY, m1 = -INFINITY;
    float s0 = 0.f, s1 = 0.f;
    float acc[VEC];
#pragma unroll
    for (int v = 0; v < VEC; ++v) acc[v] = 0.f;

    for (int base = r0; base < r1; base += CH) {
        int cnt = min(CH, r1 - base);
        if (tid < cnt) {
            int s = csr_src[base + tid];
            ssrc[tid] = s;
            float2 asv = as2[s];
            float e0 = asv.x + adv.x;
            float e1 = asv.y + adv.y;
            sc[tid][0] = (e0 > 0.f) ? e0 : NEG_SLOPE * e0;
            sc[tid][1] = (e1 > 0.f) ? e1 : NEG_SLOPE * e1;
        }
        __syncthreads();
        // chunk max, both heads (every wave -> uniform result)
        float pm0 = -INFINITY, pm1 = -INFINITY;
        for (int k = lane; k < cnt; k += 64) {
            pm0 = fmaxf(pm0, sc[k][0]);
            pm1 = fmaxf(pm1, sc[k][1]);
        }
#pragma unroll
        for (int off = 32; off; off >>= 1) {
            pm0 = fmaxf(pm0, __shfl_xor(pm0, off));
            pm1 = fmaxf(pm1, __shfl_xor(pm1, off));
        }
        float mn0 = fmaxf(m0, pm0), mn1 = fmaxf(m1, pm1);
        // rescale running state
        float f0 = expf(m0 - mn0), f1 = expf(m1 - mn1);
        s0 *= f0; s1 *= f1;
        float fa = (hh == 0) ? f0 : f1;
#pragma unroll
        for (int v = 0; v < VEC; ++v) acc[v] *= fa;
        m0 = mn0; m1 = mn1;
        // stage exp once per (edge, head)
        if (tid < cnt) {
            px[tid][0] = expf(sc[tid][0] - mn0);
            px[tid][1] = expf(sc[tid][1] - mn1);
        }
        __syncthreads();
        // chunk denominator (every wave -> uniform)
        float ps0 = 0.f, ps1 = 0.f;
        for (int k = lane; k < cnt; k += 64) {
            ps0 += px[k][0];
            ps1 += px[k][1];
        }
#pragma unroll
        for (int off = 32; off; off >>= 1) {
            ps0 += __shfl_xor(ps0, off);
            ps1 += __shfl_xor(ps1, off);
        }
        s0 += ps0; s1 += ps1;
        // gather-fma: wave w takes edges w, w+4, ...
        for (int e = w; e < cnt; e += 4) {
            float p = px[e][hh];
            const float* hp = hfeat + (size_t)ssrc[e] * M + cbase;
            if constexpr (VEC == 4) {
                float4 hv = *(const float4*)hp;
                acc[0] += p * hv.x; acc[1] += p * hv.y;
                acc[2] += p * hv.z; acc[3] += p * hv.w;
            } else {
                float2 hv = *(const float2*)hp;
                acc[0] += p * hv.x; acc[1] += p * hv.y;
            }
        }
        __syncthreads();
    }
    // cross-wave reduce
#pragma unroll
    for (int v = 0; v < VEC; ++v) partial[w][cbase + v] = acc[v];
    __syncthreads();
    if (tid < M) {
        float a = partial[0][tid] + partial[1][tid] + partial[2][tid] + partial[3][tid];
        int h2 = tid / C;
        float ssum = (h2 == 0) ? s0 : s1;
        float v = a / (ssum + EPS_F) + bias[tid];
        if (do_relu) v = fmaxf(v, 0.f);
        outp[(size_t)n * M + tid] = v;
    }
}

// ---------------- decode: one wave per positive edge, float2 ----------------
__global__ void decode_kernel(const int* __restrict__ pei, int Ep,
                              const float* __restrict__ z, int D,
                              float* __restrict__ out) {
    int wid  = (blockIdx.x * blockDim.x + threadIdx.x) >> 6;
    int lane = threadIdx.x & 63;
    if (wid >= Ep) return;
    int a = pei[wid], b = pei[Ep + wid];
    const float2* za = (const float2*)(z + (size_t)a * D);
    const float2* zb = (const float2*)(z + (size_t)b * D);
    float s = 0.f;
    for (int i = lane; i < D / 2; i += 64) {
        float2 xv = za[i], yv = zb[i];
        s += xv.x * yv.x + xv.y * yv.y;
    }
    for (int off = 32; off; off >>= 1) s += __shfl_down(s, off);
    if (lane == 0) out[wid] = s;
}

extern "C" void kernel_launch(void* const* d_in, const int* in_sizes, int n_in,
                              void* d_out, int out_size, void* d_ws, size_t ws_size,
                              hipStream_t stream) {
    const float* x   = (const float*)d_in[0];
    const int*   ei  = (const int*)d_in[1];
    const int*   pei = (const int*)d_in[2];
    const float* W1  = (const float*)d_in[3];
    const float* a1s = (const float*)d_in[4];
    const float* a1d = (const float*)d_in[5];
    const float* b1  = (const float*)d_in[6];
    const float* W2  = (const float*)d_in[7];
    const float* a2s = (const float*)d_in[8];
    const float* a2d = (const float*)d_in[9];
    const float* b2  = (const float*)d_in[10];
    float* out = (float*)d_out;

    const int M1  = in_sizes[6];            // 256
    const int Fin = in_sizes[3] / M1;       // 128
    const int N   = in_sizes[0] / Fin;      // 50000
    const int E   = in_sizes[1] / 2;        // 800000
    const int Ep  = in_sizes[2] / 2;        // 100000
    const int M2  = in_sizes[10];           // 128
    const int H   = 2;
    const int C1  = M1 / H, C2 = M2 / H;
    const int Etot = E + N;

    // workspace layout
    float* bufA    = (float*)d_ws;                      // N*M1
    float* bufB    = bufA + (size_t)N * M1;             // N*M1
    float* as_     = bufB + (size_t)N * M1;             // N*H
    float* ad_     = as_ + (size_t)N * H;               // N*H
    int*   deg     = (int*)(ad_ + (size_t)N * H);       // N
    int*   rowptr  = deg + N;                           // N+1
    int*   cursor  = rowptr + (N + 1);                  // N
    int*   csr_src = cursor + N;                        // Etot

    dim3 blk256(256);

    // ---- CSR build (shared by both layers) ----
    hipMemsetAsync(deg, 0, (size_t)N * sizeof(int), stream);
    hipMemsetAsync(cursor, 0, (size_t)N * sizeof(int), stream);
    hist_kernel<<<(Etot + 255) / 256, blk256, 0, stream>>>(ei, E, N, deg);
    scan_kernel<<<1, 1024, 0, stream>>>(deg, rowptr, N);
    fill_kernel<<<(Etot + 255) / 256, blk256, 0, stream>>>(ei, E, N, rowptr, cursor, csr_src);

    // ---- Layer 1 ----
    {
        constexpr int BN1 = 64;   // gemm_tiled<256> row tile
        gemm_tiled<256><<<(N + BN1 - 1) / BN1, blk256, 0, stream>>>(x, W1, bufA, N, Fin);
        alpha_kernel<<<(N * H * 64 + 255) / 256, blk256, 0, stream>>>(
            bufA, a1s, a1d, as_, ad_, N, H, C1);
        fused_attn_agg<256, 128><<<N, 256, 0, stream>>>(
            rowptr, csr_src, as_, ad_, bufA, b1, bufB, 1);
    }

    // ---- Layer 2 ----
    {
        constexpr int BN2 = 128;  // gemm_tiled<128> row tile
        gemm_tiled<128><<<(N + BN2 - 1) / BN2, blk256, 0, stream>>>(bufB, W2, bufA, N, M1);
        alpha_kernel<<<(N * H * 64 + 255) / 256, blk256, 0, stream>>>(
            bufA, a2s, a2d, as_, ad_, N, H, C2);
        fused_attn_agg<128, 64><<<N, 256, 0, stream>>>(
            rowptr, csr_src, as_, ad_, bufA, b2, bufB, 0);
    }

    // ---- Decode ----
    decode_kernel<<<(Ep * 64 + 255) / 256, blk256, 0, stream>>>(
        pei, Ep, bufB, M2, out);
}

// Round 6
// 537.459 us; speedup vs baseline: 3.1836x; 1.0395x over previous
//
#include <hip/hip_runtime.h>

#define NEG_SLOPE 0.2f
#define EPS_F 1e-16f

// ---------------- GEMM: Y[N,MB] = X[N,K] @ W[K,MB], 8x8 register tiles ----------------
template<int MB>
__global__ __launch_bounds__(256) void gemm_tiled(const float* __restrict__ X,
                                                  const float* __restrict__ W,
                                                  float* __restrict__ Y, int N, int K) {
    constexpr int TM = 8, TN = 8;
    constexpr int CB = MB / TN;
    constexpr int RB = 256 / CB;
    constexpr int BN = RB * TM;
    constexpr int KT = 16;
    __shared__ float xs[BN][KT + 4];
    __shared__ float ws[KT][MB];
    int tid = threadIdx.x;
    int cb = tid % CB, rb = tid / CB;
    int n0 = blockIdx.x * BN;
    int row0 = rb * TM;
    int col0 = cb * TN;
    float acc[TM][TN];
#pragma unroll
    for (int r = 0; r < TM; ++r)
#pragma unroll
        for (int c = 0; c < TN; ++c) acc[r][c] = 0.f;

    for (int k0 = 0; k0 < K; k0 += KT) {
        constexpr int XL = BN * KT / (256 * 4);
#pragma unroll
        for (int i = 0; i < XL; ++i) {
            int fid = tid + i * 256;
            int r = fid / (KT / 4);
            int kq = fid % (KT / 4);
            int n = n0 + r;
            float4 v = make_float4(0.f, 0.f, 0.f, 0.f);
            if (n < N) v = *(const float4*)&X[(size_t)n * K + k0 + kq * 4];
            *(float4*)&xs[r][kq * 4] = v;
        }
        constexpr int WL = KT * MB / (256 * 4);
#pragma unroll
        for (int i = 0; i < WL; ++i) {
            int fid = tid + i * 256;
            int kk = fid / (MB / 4);
            int mq = fid % (MB / 4);
            *(float4*)&ws[kk][mq * 4] = *(const float4*)&W[(size_t)(k0 + kk) * MB + mq * 4];
        }
        __syncthreads();
#pragma unroll
        for (int k = 0; k < KT; ++k) {
            float xv[TM], wv[TN];
#pragma unroll
            for (int r = 0; r < TM; ++r) xv[r] = xs[row0 + r][k];
            *(float4*)&wv[0] = *(float4*)&ws[k][col0];
            *(float4*)&wv[4] = *(float4*)&ws[k][col0 + 4];
#pragma unroll
            for (int r = 0; r < TM; ++r)
#pragma unroll
                for (int c = 0; c < TN; ++c) acc[r][c] += xv[r] * wv[c];
        }
        __syncthreads();
    }
#pragma unroll
    for (int r = 0; r < TM; ++r) {
        int n = n0 + row0 + r;
        if (n < N) {
            *(float4*)&Y[(size_t)n * MB + col0]     = *(float4*)&acc[r][0];
            *(float4*)&Y[(size_t)n * MB + col0 + 4] = *(float4*)&acc[r][4];
        }
    }
}

// ---------------- alpha: one wave per (n,h), float2 loads ----------------
__global__ void alpha_kernel(const float* __restrict__ h, const float* __restrict__ a_src,
                             const float* __restrict__ a_dst, float* __restrict__ as_out,
                             float* __restrict__ ad_out, int N, int H, int C) {
    int wid  = (blockIdx.x * blockDim.x + threadIdx.x) >> 6;
    int lane = threadIdx.x & 63;
    if (wid >= N * H) return;
    int n = wid / H, hh = wid - n * H;
    const float2* hp  = (const float2*)(h + (size_t)n * H * C + (size_t)hh * C);
    const float2* asv = (const float2*)(a_src + hh * C);
    const float2* adv = (const float2*)(a_dst + hh * C);
    float s1 = 0.f, s2 = 0.f;
    for (int i = lane; i < C / 2; i += 64) {
        float2 v = hp[i], a1 = asv[i], a2 = adv[i];
        s1 += v.x * a1.x + v.y * a1.y;
        s2 += v.x * a2.x + v.y * a2.y;
    }
    for (int off = 32; off; off >>= 1) {
        s1 += __shfl_down(s1, off);
        s2 += __shfl_down(s2, off);
    }
    if (lane == 0) { as_out[wid] = s1; ad_out[wid] = s2; }
}

// ---------------- CSR build ----------------
__global__ void hist_kernel(const int* __restrict__ ei, int E, int N, int* __restrict__ deg) {
    int e = blockIdx.x * blockDim.x + threadIdx.x;
    if (e >= E + N) return;
    int d = (e < E) ? ei[E + e] : e - E;
    atomicAdd(&deg[d], 1);
}

// single-block scan v2: thread t owns a contiguous span; one shuffle-scan of partials.
__global__ void scan_kernel(const int* __restrict__ deg, int* __restrict__ rowptr, int N) {
    __shared__ int wtot[16];
    int tid = threadIdx.x, lane = tid & 63, wid = tid >> 6;
    int span = (N + 1023) >> 10;
    int lo = min(tid * span, N), hi = min(lo + span, N);
    int sum = 0;
    for (int i = lo; i < hi; ++i) sum += deg[i];
    int x = sum;  // inclusive scan over 1024 threads
#pragma unroll
    for (int off = 1; off < 64; off <<= 1) {
        int y = __shfl_up(x, off);
        if (lane >= off) x += y;
    }
    if (lane == 63) wtot[wid] = x;
    __syncthreads();
    if (wid == 0 && lane < 16) {
        int w = wtot[lane], xx = w;
#pragma unroll
        for (int off = 1; off < 16; off <<= 1) {
            int y = __shfl_up(xx, off);
            if (lane >= off) xx += y;
        }
        wtot[lane] = xx - w;  // exclusive wave prefix
    }
    __syncthreads();
    int run = wtot[wid] + (x - sum);  // exclusive thread prefix
    for (int i = lo; i < hi; ++i) { rowptr[i] = run; run += deg[i]; }
    if (tid == 1023) rowptr[N] = wtot[15] + x;  // grand total
}

__global__ void fill_kernel(const int* __restrict__ ei, int E, int N,
                            const int* __restrict__ rowptr, int* __restrict__ cursor,
                            int* __restrict__ csr_src) {
    int e = blockIdx.x * blockDim.x + threadIdx.x;
    if (e >= E + N) return;
    int s, d;
    if (e < E) { s = ei[e]; d = ei[E + e]; } else { s = d = e - E; }
    int pos = atomicAdd(&cursor[d], 1);
    csr_src[rowptr[d] + pos] = s;
}

// ---------------- fused attn+agg v4: one WAVE per dst node, register softmax ----------------
// 4 independent waves per 256-block; no LDS, no __syncthreads. Lane e holds edge e's
// score/p in registers; chunk reductions via shfl_xor (once, not per-wave-redundant);
// per-edge p/src broadcast via shfl; full row gathered as lane-float4/float2.
template<int M, int C>
__global__ __launch_bounds__(256) void fused_attn_agg(
        const int* __restrict__ rowptr, const int* __restrict__ csr_src,
        const float* __restrict__ as_, const float* __restrict__ ad_,
        const float* __restrict__ hfeat, const float* __restrict__ bias,
        float* __restrict__ outp, int N, int do_relu) {
    constexpr int VEC = M / 64;   // 4 (L1) or 2 (L2)
    int n    = (blockIdx.x * blockDim.x + threadIdx.x) >> 6;
    int lane = threadIdx.x & 63;
    if (n >= N) return;
    int cbase = lane * VEC;
    int hh    = cbase / C;        // lanes 0-31: head 0, lanes 32-63: head 1
    int r0 = rowptr[n], r1 = rowptr[n + 1];
    const float2* as2 = (const float2*)as_;
    float2 adv = ((const float2*)ad_)[n];
    float m0 = -INFINITY, m1 = -INFINITY;
    float s0 = 0.f, s1 = 0.f;
    float acc[VEC];
#pragma unroll
    for (int v = 0; v < VEC; ++v) acc[v] = 0.f;

    for (int base = r0; base < r1; base += 64) {
        int cnt = min(64, r1 - base);
        int srcl = 0;
        float sc0 = -INFINITY, sc1 = -INFINITY;
        if (lane < cnt) {
            srcl = csr_src[base + lane];
            float2 asv = as2[srcl];
            float e0 = asv.x + adv.x;
            float e1 = asv.y + adv.y;
            sc0 = (e0 > 0.f) ? e0 : NEG_SLOPE * e0;
            sc1 = (e1 > 0.f) ? e1 : NEG_SLOPE * e1;
        }
        // chunk max (both heads), wave-wide
        float pm0 = sc0, pm1 = sc1;
#pragma unroll
        for (int off = 32; off; off >>= 1) {
            pm0 = fmaxf(pm0, __shfl_xor(pm0, off));
            pm1 = fmaxf(pm1, __shfl_xor(pm1, off));
        }
        float mn0 = fmaxf(m0, pm0), mn1 = fmaxf(m1, pm1);
        float f0 = expf(m0 - mn0), f1 = expf(m1 - mn1);   // 0 on first chunk
        float p0 = expf(sc0 - mn0), p1 = expf(sc1 - mn1); // 0 for lanes >= cnt
        // chunk denominator
        float ps0 = p0, ps1 = p1;
#pragma unroll
        for (int off = 32; off; off >>= 1) {
            ps0 += __shfl_xor(ps0, off);
            ps1 += __shfl_xor(ps1, off);
        }
        s0 = s0 * f0 + ps0;
        s1 = s1 * f1 + ps1;
        float fa = (hh == 0) ? f0 : f1;
#pragma unroll
        for (int v = 0; v < VEC; ++v) acc[v] *= fa;
        m0 = mn0; m1 = mn1;
        // gather-fma over this chunk's edges
        for (int e = 0; e < cnt; ++e) {
            float pe0 = __shfl(p0, e);
            float pe1 = __shfl(p1, e);
            int   se  = __shfl(srcl, e);
            float p = (hh == 0) ? pe0 : pe1;
            const float* hp = hfeat + se * M + cbase;   // < 2^31: 32-bit math
            if constexpr (VEC == 4) {
                float4 hv = *(const float4*)hp;
                acc[0] += p * hv.x; acc[1] += p * hv.y;
                acc[2] += p * hv.z; acc[3] += p * hv.w;
            } else {
                float2 hv = *(const float2*)hp;
                acc[0] += p * hv.x; acc[1] += p * hv.y;
            }
        }
    }
    float ssum = (hh == 0) ? s0 : s1;
    float inv = 1.f / (ssum + EPS_F);
    float o[VEC];
#pragma unroll
    for (int v = 0; v < VEC; ++v) {
        float val = acc[v] * inv + bias[cbase + v];
        o[v] = do_relu ? fmaxf(val, 0.f) : val;
    }
    float* op = outp + n * M + cbase;
    if constexpr (VEC == 4) *(float4*)op = make_float4(o[0], o[1], o[2], o[3]);
    else                    *(float2*)op = make_float2(o[0], o[1]);
}

// ---------------- decode: one wave per positive edge, float2 ----------------
__global__ void decode_kernel(const int* __restrict__ pei, int Ep,
                              const float* __restrict__ z, int D,
                              float* __restrict__ out) {
    int wid  = (blockIdx.x * blockDim.x + threadIdx.x) >> 6;
    int lane = threadIdx.x & 63;
    if (wid >= Ep) return;
    int a = pei[wid], b = pei[Ep + wid];
    const float2* za = (const float2*)(z + (size_t)a * D);
    const float2* zb = (const float2*)(z + (size_t)b * D);
    float s = 0.f;
    for (int i = lane; i < D / 2; i += 64) {
        float2 xv = za[i], yv = zb[i];
        s += xv.x * yv.x + xv.y * yv.y;
    }
    for (int off = 32; off; off >>= 1) s += __shfl_down(s, off);
    if (lane == 0) out[wid] = s;
}

extern "C" void kernel_launch(void* const* d_in, const int* in_sizes, int n_in,
                              void* d_out, int out_size, void* d_ws, size_t ws_size,
                              hipStream_t stream) {
    const float* x   = (const float*)d_in[0];
    const int*   ei  = (const int*)d_in[1];
    const int*   pei = (const int*)d_in[2];
    const float* W1  = (const float*)d_in[3];
    const float* a1s = (const float*)d_in[4];
    const float* a1d = (const float*)d_in[5];
    const float* b1  = (const float*)d_in[6];
    const float* W2  = (const float*)d_in[7];
    const float* a2s = (const float*)d_in[8];
    const float* a2d = (const float*)d_in[9];
    const float* b2  = (const float*)d_in[10];
    float* out = (float*)d_out;

    const int M1  = in_sizes[6];            // 256
    const int Fin = in_sizes[3] / M1;       // 128
    const int N   = in_sizes[0] / Fin;      // 50000
    const int E   = in_sizes[1] / 2;        // 800000
    const int Ep  = in_sizes[2] / 2;        // 100000
    const int M2  = in_sizes[10];           // 128
    const int H   = 2;
    const int C1  = M1 / H, C2 = M2 / H;
    const int Etot = E + N;

    // workspace layout
    float* bufA    = (float*)d_ws;                      // N*M1
    float* bufB    = bufA + (size_t)N * M1;             // N*M1
    float* as_     = bufB + (size_t)N * M1;             // N*H
    float* ad_     = as_ + (size_t)N * H;               // N*H
    int*   deg     = (int*)(ad_ + (size_t)N * H);       // N
    int*   rowptr  = deg + N;                           // N+1
    int*   cursor  = rowptr + (N + 1);                  // N
    int*   csr_src = cursor + N;                        // Etot

    dim3 blk256(256);

    // ---- CSR build (shared by both layers) ----
    hipMemsetAsync(deg, 0, (size_t)N * sizeof(int), stream);
    hipMemsetAsync(cursor, 0, (size_t)N * sizeof(int), stream);
    hist_kernel<<<(Etot + 255) / 256, blk256, 0, stream>>>(ei, E, N, deg);
    scan_kernel<<<1, 1024, 0, stream>>>(deg, rowptr, N);
    fill_kernel<<<(Etot + 255) / 256, blk256, 0, stream>>>(ei, E, N, rowptr, cursor, csr_src);

    // ---- Layer 1 ----
    {
        constexpr int BN1 = 64;
        gemm_tiled<256><<<(N + BN1 - 1) / BN1, blk256, 0, stream>>>(x, W1, bufA, N, Fin);
        alpha_kernel<<<(N * H * 64 + 255) / 256, blk256, 0, stream>>>(
            bufA, a1s, a1d, as_, ad_, N, H, C1);
        fused_attn_agg<256, 128><<<(N + 3) / 4, blk256, 0, stream>>>(
            rowptr, csr_src, as_, ad_, bufA, b1, bufB, N, 1);
    }

    // ---- Layer 2 ----
    {
        constexpr int BN2 = 128;
        gemm_tiled<128><<<(N + BN2 - 1) / BN2, blk256, 0, stream>>>(bufB, W2, bufA, N, M1);
        alpha_kernel<<<(N * H * 64 + 255) / 256, blk256, 0, stream>>>(
            bufA, a2s, a2d, as_, ad_, N, H, C2);
        fused_attn_agg<128, 64><<<(N + 3) / 4, blk256, 0, stream>>>(
            rowptr, csr_src, as_, ad_, bufA, b2, bufB, N, 0);
    }

    // ---- Decode ----
    decode_kernel<<<(Ep * 64 + 255) / 256, blk256, 0, stream>>>(
        pei, Ep, bufB, M2, out);
}

// Round 7
// 495.957 us; speedup vs baseline: 3.4500x; 1.0837x over previous
//
#include <hip/hip_runtime.h>

#define NEG_SLOPE 0.2f
#define EPS_F 1e-16f

// ---------------- GEMM + fused alpha: Y[N,MB] = X[N,K] @ W[K,MB] ----------------
// 8x8 register tiles; epilogue computes alpha_src/dst[n,h] = sum_c h[n,h,c]*a[h,c]
// via per-thread partial dot + shfl_xor reduce over the head's column-thread group.
template<int MB>
__global__ __launch_bounds__(256) void gemm_tiled(const float* __restrict__ X,
                                                  const float* __restrict__ W,
                                                  float* __restrict__ Y,
                                                  float* __restrict__ as_out,
                                                  float* __restrict__ ad_out,
                                                  const float* __restrict__ a_srcf,
                                                  const float* __restrict__ a_dstf,
                                                  int N, int K) {
    constexpr int TM = 8, TN = 8;
    constexpr int CB = MB / TN;        // col-thread-groups per row: 32 (<256>) / 16 (<128>)
    constexpr int RB = 256 / CB;
    constexpr int BN = RB * TM;
    constexpr int KT = 16;
    constexpr int C  = MB / 2;         // per-head channels
    constexpr int REDW = C / TN;       // threads per head group: 16 (<256>) / 8 (<128>)
    __shared__ float xs[BN][KT + 4];
    __shared__ float ws[KT][MB];
    int tid = threadIdx.x;
    int cb = tid % CB, rb = tid / CB;
    int n0 = blockIdx.x * BN;
    int row0 = rb * TM;
    int col0 = cb * TN;
    float acc[TM][TN];
#pragma unroll
    for (int r = 0; r < TM; ++r)
#pragma unroll
        for (int c = 0; c < TN; ++c) acc[r][c] = 0.f;

    for (int k0 = 0; k0 < K; k0 += KT) {
        constexpr int XL = BN * KT / (256 * 4);
#pragma unroll
        for (int i = 0; i < XL; ++i) {
            int fid = tid + i * 256;
            int r = fid / (KT / 4);
            int kq = fid % (KT / 4);
            int n = n0 + r;
            float4 v = make_float4(0.f, 0.f, 0.f, 0.f);
            if (n < N) v = *(const float4*)&X[(size_t)n * K + k0 + kq * 4];
            *(float4*)&xs[r][kq * 4] = v;
        }
        constexpr int WL = KT * MB / (256 * 4);
#pragma unroll
        for (int i = 0; i < WL; ++i) {
            int fid = tid + i * 256;
            int kk = fid / (MB / 4);
            int mq = fid % (MB / 4);
            *(float4*)&ws[kk][mq * 4] = *(const float4*)&W[(size_t)(k0 + kk) * MB + mq * 4];
        }
        __syncthreads();
#pragma unroll
        for (int k = 0; k < KT; ++k) {
            float xv[TM], wv[TN];
#pragma unroll
            for (int r = 0; r < TM; ++r) xv[r] = xs[row0 + r][k];
            *(float4*)&wv[0] = *(float4*)&ws[k][col0];
            *(float4*)&wv[4] = *(float4*)&ws[k][col0 + 4];
#pragma unroll
            for (int r = 0; r < TM; ++r)
#pragma unroll
                for (int c = 0; c < TN; ++c) acc[r][c] += xv[r] * wv[c];
        }
        __syncthreads();
    }
    // store Y
#pragma unroll
    for (int r = 0; r < TM; ++r) {
        int n = n0 + row0 + r;
        if (n < N) {
            *(float4*)&Y[(size_t)n * MB + col0]     = *(float4*)&acc[r][0];
            *(float4*)&Y[(size_t)n * MB + col0 + 4] = *(float4*)&acc[r][4];
        }
    }
    // fused alpha epilogue
    float av[TN], dv[TN];
    *(float4*)&av[0] = *(const float4*)&a_srcf[col0];
    *(float4*)&av[4] = *(const float4*)&a_srcf[col0 + 4];
    *(float4*)&dv[0] = *(const float4*)&a_dstf[col0];
    *(float4*)&dv[4] = *(const float4*)&a_dstf[col0 + 4];
    int head = cb / REDW;
#pragma unroll
    for (int r = 0; r < TM; ++r) {
        float vs = 0.f, vd = 0.f;
#pragma unroll
        for (int c = 0; c < TN; ++c) { vs += acc[r][c] * av[c]; vd += acc[r][c] * dv[c]; }
#pragma unroll
        for (int off = REDW / 2; off; off >>= 1) {
            vs += __shfl_xor(vs, off);
            vd += __shfl_xor(vd, off);
        }
        if ((cb & (REDW - 1)) == 0) {
            int n = n0 + row0 + r;
            if (n < N) { as_out[n * 2 + head] = vs; ad_out[n * 2 + head] = vd; }
        }
    }
}

// ---------------- CSR build ----------------
__global__ void hist_kernel(const int* __restrict__ ei, int E, int N, int* __restrict__ deg) {
    int e = blockIdx.x * blockDim.x + threadIdx.x;
    if (e >= E + N) return;
    int d = (e < E) ? ei[E + e] : e - E;
    atomicAdd(&deg[d], 1);
}

// single-block scan: thread t owns a contiguous span; one shuffle-scan of partials.
__global__ void scan_kernel(const int* __restrict__ deg, int* __restrict__ rowptr, int N) {
    __shared__ int wtot[16];
    int tid = threadIdx.x, lane = tid & 63, wid = tid >> 6;
    int span = (N + 1023) >> 10;
    int lo = min(tid * span, N), hi = min(lo + span, N);
    int sum = 0;
    for (int i = lo; i < hi; ++i) sum += deg[i];
    int x = sum;
#pragma unroll
    for (int off = 1; off < 64; off <<= 1) {
        int y = __shfl_up(x, off);
        if (lane >= off) x += y;
    }
    if (lane == 63) wtot[wid] = x;
    __syncthreads();
    if (wid == 0 && lane < 16) {
        int w = wtot[lane], xx = w;
#pragma unroll
        for (int off = 1; off < 16; off <<= 1) {
            int y = __shfl_up(xx, off);
            if (lane >= off) xx += y;
        }
        wtot[lane] = xx - w;
    }
    __syncthreads();
    int run = wtot[wid] + (x - sum);
    for (int i = lo; i < hi; ++i) { rowptr[i] = run; run += deg[i]; }
    if (tid == 1023) rowptr[N] = wtot[15] + x;
}

__global__ void fill_kernel(const int* __restrict__ ei, int E, int N,
                            const int* __restrict__ rowptr, int* __restrict__ cursor,
                            int* __restrict__ csr_src) {
    int e = blockIdx.x * blockDim.x + threadIdx.x;
    if (e >= E + N) return;
    int s, d;
    if (e < E) { s = ei[e]; d = ei[E + e]; } else { s = d = e - E; }
    int pos = atomicAdd(&cursor[d], 1);
    csr_src[rowptr[d] + pos] = s;
}

// ---------------- fused attn+agg v5: wave per node, unroll-4 gather ----------------
template<int M, int C>
__global__ __launch_bounds__(256) void fused_attn_agg(
        const int* __restrict__ rowptr, const int* __restrict__ csr_src,
        const float* __restrict__ as_, const float* __restrict__ ad_,
        const float* __restrict__ hfeat, const float* __restrict__ bias,
        float* __restrict__ outp, int N, int do_relu) {
    constexpr int VEC = M / 64;   // 4 (L1) or 2 (L2)
    int n    = (blockIdx.x * blockDim.x + threadIdx.x) >> 6;
    int lane = threadIdx.x & 63;
    if (n >= N) return;
    int cbase = lane * VEC;
    int hh    = cbase / C;
    int r0 = rowptr[n], r1 = rowptr[n + 1];
    const float2* as2 = (const float2*)as_;
    float2 adv = ((const float2*)ad_)[n];
    float m0 = -INFINITY, m1 = -INFINITY;
    float s0 = 0.f, s1 = 0.f;
    float acc[VEC];
#pragma unroll
    for (int v = 0; v < VEC; ++v) acc[v] = 0.f;

    for (int base = r0; base < r1; base += 64) {
        int cnt = min(64, r1 - base);
        int srcl = 0;
        float sc0 = -INFINITY, sc1 = -INFINITY;
        if (lane < cnt) {
            srcl = csr_src[base + lane];
            float2 asv = as2[srcl];
            float e0 = asv.x + adv.x;
            float e1 = asv.y + adv.y;
            sc0 = (e0 > 0.f) ? e0 : NEG_SLOPE * e0;
            sc1 = (e1 > 0.f) ? e1 : NEG_SLOPE * e1;
        }
        float pm0 = sc0, pm1 = sc1;
#pragma unroll
        for (int off = 32; off; off >>= 1) {
            pm0 = fmaxf(pm0, __shfl_xor(pm0, off));
            pm1 = fmaxf(pm1, __shfl_xor(pm1, off));
        }
        float mn0 = fmaxf(m0, pm0), mn1 = fmaxf(m1, pm1);
        float f0 = expf(m0 - mn0), f1 = expf(m1 - mn1);
        float p0 = expf(sc0 - mn0), p1 = expf(sc1 - mn1);
        float ps0 = p0, ps1 = p1;
#pragma unroll
        for (int off = 32; off; off >>= 1) {
            ps0 += __shfl_xor(ps0, off);
            ps1 += __shfl_xor(ps1, off);
        }
        s0 = s0 * f0 + ps0;
        s1 = s1 * f1 + ps1;
        float fa = (hh == 0) ? f0 : f1;
#pragma unroll
        for (int v = 0; v < VEC; ++v) acc[v] *= fa;
        m0 = mn0; m1 = mn1;
        // gather-fma, unrolled x4 for memory-level parallelism
        for (int e = 0; e < cnt; e += 4) {
            float pj[4]; int sj[4];
#pragma unroll
            for (int j = 0; j < 4; ++j) {
                int idx = e + j;
                float pe0 = __shfl(p0, idx & 63);
                float pe1 = __shfl(p1, idx & 63);
                int   se  = __shfl(srcl, idx & 63);
                pj[j] = (idx < cnt) ? ((hh == 0) ? pe0 : pe1) : 0.f;
                sj[j] = se;   // stale-but-valid row for idx>=cnt (p=0)
            }
            if constexpr (VEC == 4) {
                float4 h0 = *(const float4*)(hfeat + sj[0] * M + cbase);
                float4 h1 = *(const float4*)(hfeat + sj[1] * M + cbase);
                float4 h2 = *(const float4*)(hfeat + sj[2] * M + cbase);
                float4 h3 = *(const float4*)(hfeat + sj[3] * M + cbase);
                acc[0] += pj[0] * h0.x; acc[1] += pj[0] * h0.y;
                acc[2] += pj[0] * h0.z; acc[3] += pj[0] * h0.w;
                acc[0] += pj[1] * h1.x; acc[1] += pj[1] * h1.y;
                acc[2] += pj[1] * h1.z; acc[3] += pj[1] * h1.w;
                acc[0] += pj[2] * h2.x; acc[1] += pj[2] * h2.y;
                acc[2] += pj[2] * h2.z; acc[3] += pj[2] * h2.w;
                acc[0] += pj[3] * h3.x; acc[1] += pj[3] * h3.y;
                acc[2] += pj[3] * h3.z; acc[3] += pj[3] * h3.w;
            } else {
                float2 h0 = *(const float2*)(hfeat + sj[0] * M + cbase);
                float2 h1 = *(const float2*)(hfeat + sj[1] * M + cbase);
                float2 h2 = *(const float2*)(hfeat + sj[2] * M + cbase);
                float2 h3 = *(const float2*)(hfeat + sj[3] * M + cbase);
                acc[0] += pj[0] * h0.x; acc[1] += pj[0] * h0.y;
                acc[0] += pj[1] * h1.x; acc[1] += pj[1] * h1.y;
                acc[0] += pj[2] * h2.x; acc[1] += pj[2] * h2.y;
                acc[0] += pj[3] * h3.x; acc[1] += pj[3] * h3.y;
            }
        }
    }
    float ssum = (hh == 0) ? s0 : s1;
    float inv = 1.f / (ssum + EPS_F);
    float o[VEC];
#pragma unroll
    for (int v = 0; v < VEC; ++v) {
        float val = acc[v] * inv + bias[cbase + v];
        o[v] = do_relu ? fmaxf(val, 0.f) : val;
    }
    float* op = outp + n * M + cbase;
    if constexpr (VEC == 4) *(float4*)op = make_float4(o[0], o[1], o[2], o[3]);
    else                    *(float2*)op = make_float2(o[0], o[1]);
}

// ---------------- decode: one wave per positive edge, float2 ----------------
__global__ void decode_kernel(const int* __restrict__ pei, int Ep,
                              const float* __restrict__ z, int D,
                              float* __restrict__ out) {
    int wid  = (blockIdx.x * blockDim.x + threadIdx.x) >> 6;
    int lane = threadIdx.x & 63;
    if (wid >= Ep) return;
    int a = pei[wid], b = pei[Ep + wid];
    const float2* za = (const float2*)(z + (size_t)a * D);
    const float2* zb = (const float2*)(z + (size_t)b * D);
    float s = 0.f;
    for (int i = lane; i < D / 2; i += 64) {
        float2 xv = za[i], yv = zb[i];
        s += xv.x * yv.x + xv.y * yv.y;
    }
    for (int off = 32; off; off >>= 1) s += __shfl_down(s, off);
    if (lane == 0) out[wid] = s;
}

extern "C" void kernel_launch(void* const* d_in, const int* in_sizes, int n_in,
                              void* d_out, int out_size, void* d_ws, size_t ws_size,
                              hipStream_t stream) {
    const float* x   = (const float*)d_in[0];
    const int*   ei  = (const int*)d_in[1];
    const int*   pei = (const int*)d_in[2];
    const float* W1  = (const float*)d_in[3];
    const float* a1s = (const float*)d_in[4];
    const float* a1d = (const float*)d_in[5];
    const float* b1  = (const float*)d_in[6];
    const float* W2  = (const float*)d_in[7];
    const float* a2s = (const float*)d_in[8];
    const float* a2d = (const float*)d_in[9];
    const float* b2  = (const float*)d_in[10];
    float* out = (float*)d_out;

    const int M1  = in_sizes[6];            // 256
    const int Fin = in_sizes[3] / M1;       // 128
    const int N   = in_sizes[0] / Fin;      // 50000
    const int E   = in_sizes[1] / 2;        // 800000
    const int Ep  = in_sizes[2] / 2;        // 100000
    const int M2  = in_sizes[10];           // 128
    const int Etot = E + N;

    // workspace layout
    float* bufA    = (float*)d_ws;                      // N*M1
    float* bufB    = bufA + (size_t)N * M1;             // N*M1
    float* as_     = bufB + (size_t)N * M1;             // N*2
    float* ad_     = as_ + (size_t)N * 2;               // N*2
    int*   deg     = (int*)(ad_ + (size_t)N * 2);       // N
    int*   rowptr  = deg + N;                           // N+1
    int*   cursor  = rowptr + (N + 1);                  // N
    int*   csr_src = cursor + N;                        // Etot

    dim3 blk256(256);

    // ---- CSR build (shared by both layers) ----
    hipMemsetAsync(deg, 0, (size_t)N * sizeof(int), stream);
    hipMemsetAsync(cursor, 0, (size_t)N * sizeof(int), stream);
    hist_kernel<<<(Etot + 255) / 256, blk256, 0, stream>>>(ei, E, N, deg);
    scan_kernel<<<1, 1024, 0, stream>>>(deg, rowptr, N);
    fill_kernel<<<(Etot + 255) / 256, blk256, 0, stream>>>(ei, E, N, rowptr, cursor, csr_src);

    // ---- Layer 1 ----
    {
        constexpr int BN1 = 64;
        gemm_tiled<256><<<(N + BN1 - 1) / BN1, blk256, 0, stream>>>(
            x, W1, bufA, as_, ad_, a1s, a1d, N, Fin);
        fused_attn_agg<256, 128><<<(N + 3) / 4, blk256, 0, stream>>>(
            rowptr, csr_src, as_, ad_, bufA, b1, bufB, N, 1);
    }

    // ---- Layer 2 ----
    {
        constexpr int BN2 = 128;
        gemm_tiled<128><<<(N + BN2 - 1) / BN2, blk256, 0, stream>>>(
            bufB, W2, bufA, as_, ad_, a2s, a2d, N, M1);
        fused_attn_agg<128, 64><<<(N + 3) / 4, blk256, 0, stream>>>(
            rowptr, csr_src, as_, ad_, bufA, b2, bufB, N, 0);
    }

    // ---- Decode ----
    decode_kernel<<<(Ep * 64 + 255) / 256, blk256, 0, stream>>>(
        pei, Ep, bufB, M2, out);
}

// Round 8
// 429.889 us; speedup vs baseline: 3.9802x; 1.1537x over previous
//
#include <hip/hip_runtime.h>

#define NEG_SLOPE 0.2f
#define EPS_F 1e-16f

// round-to-nearest-even f32 -> bf16 (finite inputs)
__device__ __forceinline__ unsigned short f2bf(float x) {
    unsigned u = __float_as_uint(x);
    return (unsigned short)((u + 0x7FFFu + ((u >> 16) & 1u)) >> 16);
}
__device__ __forceinline__ float bflo(unsigned q) { return __uint_as_float(q << 16); }
__device__ __forceinline__ float bfhi(unsigned q) { return __uint_as_float(q & 0xFFFF0000u); }

// ---------------- GEMM + fused alpha, bf16 output table ----------------
// Y_bf16[N,MB] = X[N,K] @ W[K,MB]; epilogue computes alpha_src/dst from f32 acc.
template<int MB>
__global__ __launch_bounds__(256) void gemm_tiled(const float* __restrict__ X,
                                                  const float* __restrict__ W,
                                                  unsigned short* __restrict__ Y,
                                                  float* __restrict__ as_out,
                                                  float* __restrict__ ad_out,
                                                  const float* __restrict__ a_srcf,
                                                  const float* __restrict__ a_dstf,
                                                  int N, int K) {
    constexpr int TM = 8, TN = 8;
    constexpr int CB = MB / TN;
    constexpr int RB = 256 / CB;
    constexpr int BN = RB * TM;
    constexpr int KT = 16;
    constexpr int C  = MB / 2;
    constexpr int REDW = C / TN;       // threads per head group: 16 (<256>) / 8 (<128>)
    __shared__ float xs[BN][KT + 4];
    __shared__ float ws[KT][MB];
    int tid = threadIdx.x;
    int cb = tid % CB, rb = tid / CB;
    int n0 = blockIdx.x * BN;
    int row0 = rb * TM;
    int col0 = cb * TN;
    float acc[TM][TN];
#pragma unroll
    for (int r = 0; r < TM; ++r)
#pragma unroll
        for (int c = 0; c < TN; ++c) acc[r][c] = 0.f;

    for (int k0 = 0; k0 < K; k0 += KT) {
        constexpr int XL = BN * KT / (256 * 4);
#pragma unroll
        for (int i = 0; i < XL; ++i) {
            int fid = tid + i * 256;
            int r = fid / (KT / 4);
            int kq = fid % (KT / 4);
            int n = n0 + r;
            float4 v = make_float4(0.f, 0.f, 0.f, 0.f);
            if (n < N) v = *(const float4*)&X[(size_t)n * K + k0 + kq * 4];
            *(float4*)&xs[r][kq * 4] = v;
        }
        constexpr int WL = KT * MB / (256 * 4);
#pragma unroll
        for (int i = 0; i < WL; ++i) {
            int fid = tid + i * 256;
            int kk = fid / (MB / 4);
            int mq = fid % (MB / 4);
            *(float4*)&ws[kk][mq * 4] = *(const float4*)&W[(size_t)(k0 + kk) * MB + mq * 4];
        }
        __syncthreads();
#pragma unroll
        for (int k = 0; k < KT; ++k) {
            float xv[TM], wv[TN];
#pragma unroll
            for (int r = 0; r < TM; ++r) xv[r] = xs[row0 + r][k];
            *(float4*)&wv[0] = *(float4*)&ws[k][col0];
            *(float4*)&wv[4] = *(float4*)&ws[k][col0 + 4];
#pragma unroll
            for (int r = 0; r < TM; ++r)
#pragma unroll
                for (int c = 0; c < TN; ++c) acc[r][c] += xv[r] * wv[c];
        }
        __syncthreads();
    }
    // store Y as bf16 (8 values -> 16 bytes)
#pragma unroll
    for (int r = 0; r < TM; ++r) {
        int n = n0 + row0 + r;
        if (n < N) {
            uint4 pk;
            pk.x = (unsigned)f2bf(acc[r][0]) | ((unsigned)f2bf(acc[r][1]) << 16);
            pk.y = (unsigned)f2bf(acc[r][2]) | ((unsigned)f2bf(acc[r][3]) << 16);
            pk.z = (unsigned)f2bf(acc[r][4]) | ((unsigned)f2bf(acc[r][5]) << 16);
            pk.w = (unsigned)f2bf(acc[r][6]) | ((unsigned)f2bf(acc[r][7]) << 16);
            *(uint4*)&Y[(size_t)n * MB + col0] = pk;
        }
    }
    // fused alpha epilogue (f32 precision)
    float av[TN], dv[TN];
    *(float4*)&av[0] = *(const float4*)&a_srcf[col0];
    *(float4*)&av[4] = *(const float4*)&a_srcf[col0 + 4];
    *(float4*)&dv[0] = *(const float4*)&a_dstf[col0];
    *(float4*)&dv[4] = *(const float4*)&a_dstf[col0 + 4];
    int head = cb / REDW;
#pragma unroll
    for (int r = 0; r < TM; ++r) {
        float vs = 0.f, vd = 0.f;
#pragma unroll
        for (int c = 0; c < TN; ++c) { vs += acc[r][c] * av[c]; vd += acc[r][c] * dv[c]; }
#pragma unroll
        for (int off = REDW / 2; off; off >>= 1) {
            vs += __shfl_xor(vs, off);
            vd += __shfl_xor(vd, off);
        }
        if ((cb & (REDW - 1)) == 0) {
            int n = n0 + row0 + r;
            if (n < N) { as_out[n * 2 + head] = vs; ad_out[n * 2 + head] = vd; }
        }
    }
}

// ---------------- CSR build ----------------
__global__ void hist_kernel(const int* __restrict__ ei, int E, int N, int* __restrict__ deg) {
    int e = blockIdx.x * blockDim.x + threadIdx.x;
    if (e >= E + N) return;
    int d = (e < E) ? ei[E + e] : e - E;
    atomicAdd(&deg[d], 1);
}

__global__ void scan_kernel(const int* __restrict__ deg, int* __restrict__ rowptr, int N) {
    __shared__ int wtot[16];
    int tid = threadIdx.x, lane = tid & 63, wid = tid >> 6;
    int span = (N + 1023) >> 10;
    int lo = min(tid * span, N), hi = min(lo + span, N);
    int sum = 0;
    for (int i = lo; i < hi; ++i) sum += deg[i];
    int x = sum;
#pragma unroll
    for (int off = 1; off < 64; off <<= 1) {
        int y = __shfl_up(x, off);
        if (lane >= off) x += y;
    }
    if (lane == 63) wtot[wid] = x;
    __syncthreads();
    if (wid == 0 && lane < 16) {
        int w = wtot[lane], xx = w;
#pragma unroll
        for (int off = 1; off < 16; off <<= 1) {
            int y = __shfl_up(xx, off);
            if (lane >= off) xx += y;
        }
        wtot[lane] = xx - w;
    }
    __syncthreads();
    int run = wtot[wid] + (x - sum);
    for (int i = lo; i < hi; ++i) { rowptr[i] = run; run += deg[i]; }
    if (tid == 1023) rowptr[N] = wtot[15] + x;
}

__global__ void fill_kernel(const int* __restrict__ ei, int E, int N,
                            const int* __restrict__ rowptr, int* __restrict__ cursor,
                            int* __restrict__ csr_src) {
    int e = blockIdx.x * blockDim.x + threadIdx.x;
    if (e >= E + N) return;
    int s, d;
    if (e < E) { s = ei[e]; d = ei[E + e]; } else { s = d = e - E; }
    int pos = atomicAdd(&cursor[d], 1);
    csr_src[rowptr[d] + pos] = s;
}

// ---------------- fused attn+agg v6: wave per node, bf16 gather ----------------
template<int M, int C>
__global__ __launch_bounds__(256) void fused_attn_agg(
        const int* __restrict__ rowptr, const int* __restrict__ csr_src,
        const float* __restrict__ as_, const float* __restrict__ ad_,
        const unsigned short* __restrict__ hfeat, const float* __restrict__ bias,
        float* __restrict__ outp, int N, int do_relu) {
    constexpr int VEC = M / 64;   // 4 (L1) or 2 (L2)
    int n    = (blockIdx.x * blockDim.x + threadIdx.x) >> 6;
    int lane = threadIdx.x & 63;
    if (n >= N) return;
    int cbase = lane * VEC;
    int hh    = cbase / C;
    int r0 = rowptr[n], r1 = rowptr[n + 1];
    const float2* as2 = (const float2*)as_;
    float2 adv = ((const float2*)ad_)[n];
    float m0 = -INFINITY, m1 = -INFINITY;
    float s0 = 0.f, s1 = 0.f;
    float acc[VEC];
#pragma unroll
    for (int v = 0; v < VEC; ++v) acc[v] = 0.f;

    for (int base = r0; base < r1; base += 64) {
        int cnt = min(64, r1 - base);
        int srcl = 0;
        float sc0 = -INFINITY, sc1 = -INFINITY;
        if (lane < cnt) {
            srcl = csr_src[base + lane];
            float2 asv = as2[srcl];
            float e0 = asv.x + adv.x;
            float e1 = asv.y + adv.y;
            sc0 = (e0 > 0.f) ? e0 : NEG_SLOPE * e0;
            sc1 = (e1 > 0.f) ? e1 : NEG_SLOPE * e1;
        }
        float pm0 = sc0, pm1 = sc1;
#pragma unroll
        for (int off = 32; off; off >>= 1) {
            pm0 = fmaxf(pm0, __shfl_xor(pm0, off));
            pm1 = fmaxf(pm1, __shfl_xor(pm1, off));
        }
        float mn0 = fmaxf(m0, pm0), mn1 = fmaxf(m1, pm1);
        float f0 = expf(m0 - mn0), f1 = expf(m1 - mn1);
        float p0 = expf(sc0 - mn0), p1 = expf(sc1 - mn1);
        float ps0 = p0, ps1 = p1;
#pragma unroll
        for (int off = 32; off; off >>= 1) {
            ps0 += __shfl_xor(ps0, off);
            ps1 += __shfl_xor(ps1, off);
        }
        s0 = s0 * f0 + ps0;
        s1 = s1 * f1 + ps1;
        float fa = (hh == 0) ? f0 : f1;
#pragma unroll
        for (int v = 0; v < VEC; ++v) acc[v] *= fa;
        m0 = mn0; m1 = mn1;
        // bf16 gather-fma, unrolled x2 (half the bytes of f32)
        for (int e = 0; e < cnt; e += 2) {
            float pj[2]; int sj[2];
#pragma unroll
            for (int j = 0; j < 2; ++j) {
                int idx = e + j;
                float pe0 = __shfl(p0, idx & 63);
                float pe1 = __shfl(p1, idx & 63);
                int   se  = __shfl(srcl, idx & 63);
                pj[j] = (idx < cnt) ? ((hh == 0) ? pe0 : pe1) : 0.f;
                sj[j] = se;
            }
            if constexpr (VEC == 4) {
                uint2 q0 = *(const uint2*)(hfeat + sj[0] * M + cbase);
                uint2 q1 = *(const uint2*)(hfeat + sj[1] * M + cbase);
                acc[0] += pj[0] * bflo(q0.x); acc[1] += pj[0] * bfhi(q0.x);
                acc[2] += pj[0] * bflo(q0.y); acc[3] += pj[0] * bfhi(q0.y);
                acc[0] += pj[1] * bflo(q1.x); acc[1] += pj[1] * bfhi(q1.x);
                acc[2] += pj[1] * bflo(q1.y); acc[3] += pj[1] * bfhi(q1.y);
            } else {
                unsigned q0 = *(const unsigned*)(hfeat + sj[0] * M + cbase);
                unsigned q1 = *(const unsigned*)(hfeat + sj[1] * M + cbase);
                acc[0] += pj[0] * bflo(q0); acc[1] += pj[0] * bfhi(q0);
                acc[0] += pj[1] * bflo(q1); acc[1] += pj[1] * bfhi(q1);
            }
        }
    }
    float ssum = (hh == 0) ? s0 : s1;
    float inv = 1.f / (ssum + EPS_F);
    float o[VEC];
#pragma unroll
    for (int v = 0; v < VEC; ++v) {
        float val = acc[v] * inv + bias[cbase + v];
        o[v] = do_relu ? fmaxf(val, 0.f) : val;
    }
    float* op = outp + n * M + cbase;
    if constexpr (VEC == 4) *(float4*)op = make_float4(o[0], o[1], o[2], o[3]);
    else                    *(float2*)op = make_float2(o[0], o[1]);
}

// ---------------- decode: one wave per positive edge, float2 ----------------
__global__ void decode_kernel(const int* __restrict__ pei, int Ep,
                              const float* __restrict__ z, int D,
                              float* __restrict__ out) {
    int wid  = (blockIdx.x * blockDim.x + threadIdx.x) >> 6;
    int lane = threadIdx.x & 63;
    if (wid >= Ep) return;
    int a = pei[wid], b = pei[Ep + wid];
    const float2* za = (const float2*)(z + (size_t)a * D);
    const float2* zb = (const float2*)(z + (size_t)b * D);
    float s = 0.f;
    for (int i = lane; i < D / 2; i += 64) {
        float2 xv = za[i], yv = zb[i];
        s += xv.x * yv.x + xv.y * yv.y;
    }
    for (int off = 32; off; off >>= 1) s += __shfl_down(s, off);
    if (lane == 0) out[wid] = s;
}

extern "C" void kernel_launch(void* const* d_in, const int* in_sizes, int n_in,
                              void* d_out, int out_size, void* d_ws, size_t ws_size,
                              hipStream_t stream) {
    const float* x   = (const float*)d_in[0];
    const int*   ei  = (const int*)d_in[1];
    const int*   pei = (const int*)d_in[2];
    const float* W1  = (const float*)d_in[3];
    const float* a1s = (const float*)d_in[4];
    const float* a1d = (const float*)d_in[5];
    const float* b1  = (const float*)d_in[6];
    const float* W2  = (const float*)d_in[7];
    const float* a2s = (const float*)d_in[8];
    const float* a2d = (const float*)d_in[9];
    const float* b2  = (const float*)d_in[10];
    float* out = (float*)d_out;

    const int M1  = in_sizes[6];            // 256
    const int Fin = in_sizes[3] / M1;       // 128
    const int N   = in_sizes[0] / Fin;      // 50000
    const int E   = in_sizes[1] / 2;        // 800000
    const int Ep  = in_sizes[2] / 2;        // 100000
    const int M2  = in_sizes[10];           // 128
    const int Etot = E + N;

    // workspace layout
    unsigned short* hbf = (unsigned short*)d_ws;        // N*M1 bf16 (gather table, both layers)
    float* bufB    = (float*)(hbf + (size_t)N * M1);    // N*M1 f32 (h1, then z)
    float* as_     = bufB + (size_t)N * M1;             // N*2
    float* ad_     = as_ + (size_t)N * 2;               // N*2
    int*   deg     = (int*)(ad_ + (size_t)N * 2);       // N
    int*   rowptr  = deg + N;                           // N+1
    int*   cursor  = rowptr + (N + 1);                  // N
    int*   csr_src = cursor + N;                        // Etot

    dim3 blk256(256);

    // ---- CSR build (shared by both layers) ----
    hipMemsetAsync(deg, 0, (size_t)N * sizeof(int), stream);
    hipMemsetAsync(cursor, 0, (size_t)N * sizeof(int), stream);
    hist_kernel<<<(Etot + 255) / 256, blk256, 0, stream>>>(ei, E, N, deg);
    scan_kernel<<<1, 1024, 0, stream>>>(deg, rowptr, N);
    fill_kernel<<<(Etot + 255) / 256, blk256, 0, stream>>>(ei, E, N, rowptr, cursor, csr_src);

    // ---- Layer 1: gemm -> bf16 table + alpha; attn -> h1 (f32 bufB) ----
    {
        constexpr int BN1 = 64;
        gemm_tiled<256><<<(N + BN1 - 1) / BN1, blk256, 0, stream>>>(
            x, W1, hbf, as_, ad_, a1s, a1d, N, Fin);
        fused_attn_agg<256, 128><<<(N + 3) / 4, blk256, 0, stream>>>(
            rowptr, csr_src, as_, ad_, hbf, b1, bufB, N, 1);
    }

    // ---- Layer 2: gemm(h1) -> bf16 table + alpha; attn -> z (f32 bufB) ----
    {
        constexpr int BN2 = 128;
        gemm_tiled<128><<<(N + BN2 - 1) / BN2, blk256, 0, stream>>>(
            bufB, W2, hbf, as_, ad_, a2s, a2d, N, M1);
        fused_attn_agg<128, 64><<<(N + 3) / 4, blk256, 0, stream>>>(
            rowptr, csr_src, as_, ad_, hbf, b2, bufB, N, 0);
    }

    // ---- Decode ----
    decode_kernel<<<(Ep * 64 + 255) / 256, blk256, 0, stream>>>(
        pei, Ep, bufB, M2, out);
}

// Round 9
// 351.904 us; speedup vs baseline: 4.8622x; 1.2216x over previous
//
#include <hip/hip_runtime.h>

#define NEG_SLOPE 0.2f
#define EPS_F 1e-16f
#define STILE 4096

// round-to-nearest-even f32 -> bf16 (finite inputs)
__device__ __forceinline__ unsigned short f2bf(float x) {
    unsigned u = __float_as_uint(x);
    return (unsigned short)((u + 0x7FFFu + ((u >> 16) & 1u)) >> 16);
}
__device__ __forceinline__ float bflo(unsigned q) { return __uint_as_float(q << 16); }
__device__ __forceinline__ float bfhi(unsigned q) { return __uint_as_float(q & 0xFFFF0000u); }

// ---------------- GEMM + fused alpha, bf16 output table ----------------
// Y_bf16[N,MB] = X[N,K] @ W[K,MB]; TIN = float or bf16(ushort).
template<int MB, typename TIN>
__global__ __launch_bounds__(256) void gemm_tiled(const TIN* __restrict__ X,
                                                  const float* __restrict__ W,
                                                  unsigned short* __restrict__ Y,
                                                  float* __restrict__ as_out,
                                                  float* __restrict__ ad_out,
                                                  const float* __restrict__ a_srcf,
                                                  const float* __restrict__ a_dstf,
                                                  int N, int K) {
    constexpr int TM = 8, TN = 8;
    constexpr int CB = MB / TN;
    constexpr int RB = 256 / CB;
    constexpr int BN = RB * TM;
    constexpr int KT = 16;
    constexpr int C  = MB / 2;
    constexpr int REDW = C / TN;       // threads per head group: 16 (<256>) / 8 (<128>)
    __shared__ float xs[BN][KT + 4];
    __shared__ float ws[KT][MB];
    int tid = threadIdx.x;
    int cb = tid % CB, rb = tid / CB;
    int n0 = blockIdx.x * BN;
    int row0 = rb * TM;
    int col0 = cb * TN;
    float acc[TM][TN];
#pragma unroll
    for (int r = 0; r < TM; ++r)
#pragma unroll
        for (int c = 0; c < TN; ++c) acc[r][c] = 0.f;

    for (int k0 = 0; k0 < K; k0 += KT) {
        constexpr int XL = BN * KT / (256 * 4);
#pragma unroll
        for (int i = 0; i < XL; ++i) {
            int fid = tid + i * 256;
            int r = fid / (KT / 4);
            int kq = fid % (KT / 4);
            int n = n0 + r;
            float4 v = make_float4(0.f, 0.f, 0.f, 0.f);
            if (n < N) {
                if constexpr (sizeof(TIN) == 4) {
                    v = *(const float4*)&X[(size_t)n * K + k0 + kq * 4];
                } else {
                    uint2 q = *(const uint2*)&X[(size_t)n * K + k0 + kq * 4];
                    v = make_float4(bflo(q.x), bfhi(q.x), bflo(q.y), bfhi(q.y));
                }
            }
            *(float4*)&xs[r][kq * 4] = v;
        }
        constexpr int WL = KT * MB / (256 * 4);
#pragma unroll
        for (int i = 0; i < WL; ++i) {
            int fid = tid + i * 256;
            int kk = fid / (MB / 4);
            int mq = fid % (MB / 4);
            *(float4*)&ws[kk][mq * 4] = *(const float4*)&W[(size_t)(k0 + kk) * MB + mq * 4];
        }
        __syncthreads();
#pragma unroll
        for (int k = 0; k < KT; ++k) {
            float xv[TM], wv[TN];
#pragma unroll
            for (int r = 0; r < TM; ++r) xv[r] = xs[row0 + r][k];
            *(float4*)&wv[0] = *(float4*)&ws[k][col0];
            *(float4*)&wv[4] = *(float4*)&ws[k][col0 + 4];
#pragma unroll
            for (int r = 0; r < TM; ++r)
#pragma unroll
                for (int c = 0; c < TN; ++c) acc[r][c] += xv[r] * wv[c];
        }
        __syncthreads();
    }
    // store Y as bf16 (8 values -> 16 bytes)
#pragma unroll
    for (int r = 0; r < TM; ++r) {
        int n = n0 + row0 + r;
        if (n < N) {
            uint4 pk;
            pk.x = (unsigned)f2bf(acc[r][0]) | ((unsigned)f2bf(acc[r][1]) << 16);
            pk.y = (unsigned)f2bf(acc[r][2]) | ((unsigned)f2bf(acc[r][3]) << 16);
            pk.z = (unsigned)f2bf(acc[r][4]) | ((unsigned)f2bf(acc[r][5]) << 16);
            pk.w = (unsigned)f2bf(acc[r][6]) | ((unsigned)f2bf(acc[r][7]) << 16);
            *(uint4*)&Y[(size_t)n * MB + col0] = pk;
        }
    }
    // fused alpha epilogue (f32 precision)
    float av[TN], dv[TN];
    *(float4*)&av[0] = *(const float4*)&a_srcf[col0];
    *(float4*)&av[4] = *(const float4*)&a_srcf[col0 + 4];
    *(float4*)&dv[0] = *(const float4*)&a_dstf[col0];
    *(float4*)&dv[4] = *(const float4*)&a_dstf[col0 + 4];
    int head = cb / REDW;
#pragma unroll
    for (int r = 0; r < TM; ++r) {
        float vs = 0.f, vd = 0.f;
#pragma unroll
        for (int c = 0; c < TN; ++c) { vs += acc[r][c] * av[c]; vd += acc[r][c] * dv[c]; }
#pragma unroll
        for (int off = REDW / 2; off; off >>= 1) {
            vs += __shfl_xor(vs, off);
            vd += __shfl_xor(vd, off);
        }
        if ((cb & (REDW - 1)) == 0) {
            int n = n0 + row0 + r;
            if (n < N) { as_out[n * 2 + head] = vs; ad_out[n * 2 + head] = vd; }
        }
    }
}

// ---------------- CSR build ----------------
__global__ void hist_kernel(const int* __restrict__ ei, int E, int N, int* __restrict__ deg) {
    int e = blockIdx.x * blockDim.x + threadIdx.x;
    if (e >= E + N) return;
    int d = (e < E) ? ei[E + e] : e - E;
    atomicAdd(&deg[d], 1);
}

// hierarchical scan, step 1: per-tile sums (deg padded with zeros to NT*STILE)
__global__ __launch_bounds__(256) void scan_part(const int* __restrict__ deg,
                                                 int* __restrict__ tsum) {
    int b = blockIdx.x, t = threadIdx.x;
    int base = b * STILE + t * 16;
    int sum = 0;
#pragma unroll
    for (int j = 0; j < 16; j += 4) {
        int4 q = *(const int4*)&deg[base + j];
        sum += q.x + q.y + q.z + q.w;
    }
#pragma unroll
    for (int off = 32; off; off >>= 1) sum += __shfl_down(sum, off);
    __shared__ int wsh[4];
    if ((t & 63) == 0) wsh[t >> 6] = sum;
    __syncthreads();
    if (t == 0) tsum[b] = wsh[0] + wsh[1] + wsh[2] + wsh[3];
}

// step 2: exclusive scan of tile sums (ntiles <= 64), single wave
__global__ void scan_tiles(int* __restrict__ tsum, int ntiles) {
    int lane = threadIdx.x;
    int v = (lane < ntiles) ? tsum[lane] : 0;
    int x = v;
#pragma unroll
    for (int off = 1; off < 64; off <<= 1) {
        int y = __shfl_up(x, off);
        if (lane >= off) x += y;
    }
    if (lane < ntiles) tsum[lane] = x - v;
}

// step 3: downsweep — block per tile, thread owns 16 contiguous elems (rowptr padded)
__global__ __launch_bounds__(256) void scan_final(const int* __restrict__ deg,
                                                  const int* __restrict__ tsum,
                                                  int* __restrict__ rowptr) {
    int b = blockIdx.x, t = threadIdx.x, lane = t & 63, wid = t >> 6;
    int base = b * STILE + t * 16;
    int v[16];
    int sum = 0;
#pragma unroll
    for (int j = 0; j < 16; j += 4) {
        int4 q = *(const int4*)&deg[base + j];
        v[j] = q.x; v[j + 1] = q.y; v[j + 2] = q.z; v[j + 3] = q.w;
        sum += q.x + q.y + q.z + q.w;
    }
    int x = sum;  // inclusive wave scan of per-thread sums
#pragma unroll
    for (int off = 1; off < 64; off <<= 1) {
        int y = __shfl_up(x, off);
        if (lane >= off) x += y;
    }
    __shared__ int wtot[4];
    if (lane == 63) wtot[wid] = x;
    __syncthreads();
    int woff = 0;
    for (int wi = 0; wi < wid; ++wi) woff += wtot[wi];
    int run = tsum[b] + woff + (x - sum);
    int outv[16];
#pragma unroll
    for (int j = 0; j < 16; ++j) { outv[j] = run; run += v[j]; }
#pragma unroll
    for (int j = 0; j < 16; j += 4)
        *(int4*)&rowptr[base + j] = make_int4(outv[j], outv[j+1], outv[j+2], outv[j+3]);
}

__global__ void fill_kernel(const int* __restrict__ ei, int E, int N,
                            const int* __restrict__ rowptr, int* __restrict__ cursor,
                            int* __restrict__ csr_src) {
    int e = blockIdx.x * blockDim.x + threadIdx.x;
    if (e >= E + N) return;
    int s, d;
    if (e < E) { s = ei[e]; d = ei[E + e]; } else { s = d = e - E; }
    int pos = atomicAdd(&cursor[d], 1);
    csr_src[rowptr[d] + pos] = s;
}

// ---------------- fused attn+agg: wave per node, bf16 gather, TOUT = bf16 or f32 ----------------
template<int M, int C, typename TOUT>
__global__ __launch_bounds__(256) void fused_attn_agg(
        const int* __restrict__ rowptr, const int* __restrict__ csr_src,
        const float* __restrict__ as_, const float* __restrict__ ad_,
        const unsigned short* __restrict__ hfeat, const float* __restrict__ bias,
        TOUT* __restrict__ outp, int N, int do_relu) {
    constexpr int VEC = M / 64;   // 4 (L1) or 2 (L2)
    int n    = (blockIdx.x * blockDim.x + threadIdx.x) >> 6;
    int lane = threadIdx.x & 63;
    if (n >= N) return;
    int cbase = lane * VEC;
    int hh    = cbase / C;
    int r0 = rowptr[n], r1 = rowptr[n + 1];
    const float2* as2 = (const float2*)as_;
    float2 adv = ((const float2*)ad_)[n];
    float m0 = -INFINITY, m1 = -INFINITY;
    float s0 = 0.f, s1 = 0.f;
    float acc[VEC];
#pragma unroll
    for (int v = 0; v < VEC; ++v) acc[v] = 0.f;

    for (int base = r0; base < r1; base += 64) {
        int cnt = min(64, r1 - base);
        int srcl = 0;
        float sc0 = -INFINITY, sc1 = -INFINITY;
        if (lane < cnt) {
            srcl = csr_src[base + lane];
            float2 asv = as2[srcl];
            float e0 = asv.x + adv.x;
            float e1 = asv.y + adv.y;
            sc0 = (e0 > 0.f) ? e0 : NEG_SLOPE * e0;
            sc1 = (e1 > 0.f) ? e1 : NEG_SLOPE * e1;
        }
        float pm0 = sc0, pm1 = sc1;
#pragma unroll
        for (int off = 32; off; off >>= 1) {
            pm0 = fmaxf(pm0, __shfl_xor(pm0, off));
            pm1 = fmaxf(pm1, __shfl_xor(pm1, off));
        }
        float mn0 = fmaxf(m0, pm0), mn1 = fmaxf(m1, pm1);
        float f0 = expf(m0 - mn0), f1 = expf(m1 - mn1);
        float p0 = expf(sc0 - mn0), p1 = expf(sc1 - mn1);
        float ps0 = p0, ps1 = p1;
#pragma unroll
        for (int off = 32; off; off >>= 1) {
            ps0 += __shfl_xor(ps0, off);
            ps1 += __shfl_xor(ps1, off);
        }
        s0 = s0 * f0 + ps0;
        s1 = s1 * f1 + ps1;
        float fa = (hh == 0) ? f0 : f1;
#pragma unroll
        for (int v = 0; v < VEC; ++v) acc[v] *= fa;
        m0 = mn0; m1 = mn1;
        // bf16 gather-fma, unrolled x2
        for (int e = 0; e < cnt; e += 2) {
            float pj[2]; int sj[2];
#pragma unroll
            for (int j = 0; j < 2; ++j) {
                int idx = e + j;
                float pe0 = __shfl(p0, idx & 63);
                float pe1 = __shfl(p1, idx & 63);
                int   se  = __shfl(srcl, idx & 63);
                pj[j] = (idx < cnt) ? ((hh == 0) ? pe0 : pe1) : 0.f;
                sj[j] = se;
            }
            if constexpr (VEC == 4) {
                uint2 q0 = *(const uint2*)(hfeat + sj[0] * M + cbase);
                uint2 q1 = *(const uint2*)(hfeat + sj[1] * M + cbase);
                acc[0] += pj[0] * bflo(q0.x); acc[1] += pj[0] * bfhi(q0.x);
                acc[2] += pj[0] * bflo(q0.y); acc[3] += pj[0] * bfhi(q0.y);
                acc[0] += pj[1] * bflo(q1.x); acc[1] += pj[1] * bfhi(q1.x);
                acc[2] += pj[1] * bflo(q1.y); acc[3] += pj[1] * bfhi(q1.y);
            } else {
                unsigned q0 = *(const unsigned*)(hfeat + sj[0] * M + cbase);
                unsigned q1 = *(const unsigned*)(hfeat + sj[1] * M + cbase);
                acc[0] += pj[0] * bflo(q0); acc[1] += pj[0] * bfhi(q0);
                acc[0] += pj[1] * bflo(q1); acc[1] += pj[1] * bfhi(q1);
            }
        }
    }
    float ssum = (hh == 0) ? s0 : s1;
    float inv = 1.f / (ssum + EPS_F);
    float o[VEC];
#pragma unroll
    for (int v = 0; v < VEC; ++v) {
        float val = acc[v] * inv + bias[cbase + v];
        o[v] = do_relu ? fmaxf(val, 0.f) : val;
    }
    if constexpr (sizeof(TOUT) == 2) {
        unsigned short* op = (unsigned short*)outp + (size_t)n * M + cbase;
        if constexpr (VEC == 4) {
            uint2 pk;
            pk.x = (unsigned)f2bf(o[0]) | ((unsigned)f2bf(o[1]) << 16);
            pk.y = (unsigned)f2bf(o[2]) | ((unsigned)f2bf(o[3]) << 16);
            *(uint2*)op = pk;
        } else {
            *(unsigned*)op = (unsigned)f2bf(o[0]) | ((unsigned)f2bf(o[1]) << 16);
        }
    } else {
        float* op = (float*)outp + (size_t)n * M + cbase;
        if constexpr (VEC == 4) *(float4*)op = make_float4(o[0], o[1], o[2], o[3]);
        else                    *(float2*)op = make_float2(o[0], o[1]);
    }
}

// ---------------- decode: one wave per positive edge, float2 ----------------
__global__ void decode_kernel(const int* __restrict__ pei, int Ep,
                              const float* __restrict__ z, int D,
                              float* __restrict__ out) {
    int wid  = (blockIdx.x * blockDim.x + threadIdx.x) >> 6;
    int lane = threadIdx.x & 63;
    if (wid >= Ep) return;
    int a = pei[wid], b = pei[Ep + wid];
    const float2* za = (const float2*)(z + (size_t)a * D);
    const float2* zb = (const float2*)(z + (size_t)b * D);
    float s = 0.f;
    for (int i = lane; i < D / 2; i += 64) {
        float2 xv = za[i], yv = zb[i];
        s += xv.x * yv.x + xv.y * yv.y;
    }
    for (int off = 32; off; off >>= 1) s += __shfl_down(s, off);
    if (lane == 0) out[wid] = s;
}

extern "C" void kernel_launch(void* const* d_in, const int* in_sizes, int n_in,
                              void* d_out, int out_size, void* d_ws, size_t ws_size,
                              hipStream_t stream) {
    const float* x   = (const float*)d_in[0];
    const int*   ei  = (const int*)d_in[1];
    const int*   pei = (const int*)d_in[2];
    const float* W1  = (const float*)d_in[3];
    const float* a1s = (const float*)d_in[4];
    const float* a1d = (const float*)d_in[5];
    const float* b1  = (const float*)d_in[6];
    const float* W2  = (const float*)d_in[7];
    const float* a2s = (const float*)d_in[8];
    const float* a2d = (const float*)d_in[9];
    const float* b2  = (const float*)d_in[10];
    float* out = (float*)d_out;

    const int M1  = in_sizes[6];            // 256
    const int Fin = in_sizes[3] / M1;       // 128
    const int N   = in_sizes[0] / Fin;      // 50000
    const int E   = in_sizes[1] / 2;        // 800000
    const int Ep  = in_sizes[2] / 2;        // 100000
    const int M2  = in_sizes[10];           // 128
    const int Etot = E + N;
    const int NT  = (N + STILE - 1) / STILE;   // scan tiles (13)

    // workspace layout (16B-aligned sections)
    unsigned short* hbf  = (unsigned short*)d_ws;         // N*M1 bf16 gather table
    unsigned short* h1bf = hbf + (size_t)N * M1;          // N*M1 bf16 h1
    float* zbuf    = (float*)(h1bf + (size_t)N * M1);     // N*M2 f32 z
    float* as_     = zbuf + (size_t)N * M2;               // N*2
    float* ad_     = as_ + (size_t)N * 2;                 // N*2
    int*   deg     = (int*)(ad_ + (size_t)N * 2);         // NT*STILE (padded)
    int*   rowptr  = deg + (size_t)NT * STILE;            // NT*STILE (padded; rowptr[N] valid)
    int*   tsum    = rowptr + (size_t)NT * STILE;         // 64
    int*   cursor  = tsum + 64;                           // N
    int*   csr_src = cursor + N;                          // Etot

    dim3 blk256(256);

    // ---- CSR build (shared by both layers) ----
    hipMemsetAsync(deg, 0, (size_t)NT * STILE * sizeof(int), stream);
    hipMemsetAsync(cursor, 0, (size_t)N * sizeof(int), stream);
    hist_kernel<<<(Etot + 255) / 256, blk256, 0, stream>>>(ei, E, N, deg);
    scan_part<<<NT, blk256, 0, stream>>>(deg, tsum);
    scan_tiles<<<1, 64, 0, stream>>>(tsum, NT);
    scan_final<<<NT, blk256, 0, stream>>>(deg, tsum, rowptr);
    fill_kernel<<<(Etot + 255) / 256, blk256, 0, stream>>>(ei, E, N, rowptr, cursor, csr_src);

    // ---- Layer 1: gemm(f32 x) -> bf16 table + alpha; attn -> bf16 h1 ----
    {
        constexpr int BN1 = 64;
        gemm_tiled<256, float><<<(N + BN1 - 1) / BN1, blk256, 0, stream>>>(
            x, W1, hbf, as_, ad_, a1s, a1d, N, Fin);
        fused_attn_agg<256, 128, unsigned short><<<(N + 3) / 4, blk256, 0, stream>>>(
            rowptr, csr_src, as_, ad_, hbf, b1, h1bf, N, 1);
    }

    // ---- Layer 2: gemm(bf16 h1) -> bf16 table + alpha; attn -> f32 z ----
    {
        constexpr int BN2 = 128;
        gemm_tiled<128, unsigned short><<<(N + BN2 - 1) / BN2, blk256, 0, stream>>>(
            h1bf, W2, hbf, as_, ad_, a2s, a2d, N, M1);
        fused_attn_agg<128, 64, float><<<(N + 3) / 4, blk256, 0, stream>>>(
            rowptr, csr_src, as_, ad_, hbf, b2, zbuf, N, 0);
    }

    // ---- Decode ----
    decode_kernel<<<(Ep * 64 + 255) / 256, blk256, 0, stream>>>(
        pei, Ep, zbuf, M2, out);
}

// Round 10
// 320.699 us; speedup vs baseline: 5.3353x; 1.0973x over previous
//
#include <hip/hip_runtime.h>

#define NEG_SLOPE 0.2f
#define EPS_F 1e-16f
#define STILE 4096

typedef short short8 __attribute__((ext_vector_type(8)));
typedef float f32x4 __attribute__((ext_vector_type(4)));

// round-to-nearest-even f32 -> bf16 (finite inputs)
__device__ __forceinline__ unsigned short f2bf(float x) {
    unsigned u = __float_as_uint(x);
    return (unsigned short)((u + 0x7FFFu + ((u >> 16) & 1u)) >> 16);
}
__device__ __forceinline__ float bflo(unsigned q) { return __uint_as_float(q << 16); }
__device__ __forceinline__ float bfhi(unsigned q) { return __uint_as_float(q & 0xFFFF0000u); }

// ---------------- W prep: Wt_bf16[MB][K] = bf16(W[K][MB]^T) ----------------
__global__ void prep_w(const float* __restrict__ W, unsigned short* __restrict__ Wt,
                       int K, int MB) {
    int i = blockIdx.x * blockDim.x + threadIdx.x;
    if (i >= MB * K) return;
    int m = i / K, k = i - m * K;
    Wt[i] = f2bf(W[(size_t)k * MB + m]);
}

// ---------------- MFMA GEMM + fused alpha ----------------
// Y_bf16[N,MB] = X[N,K] @ W[K,MB]; wave owns 16 rows x MB cols; no LDS.
// mfma_f32_16x16x32_bf16: A row=lane%16, k=8*(lane/16)+j; B col=lane%16, same k;
// D col=lane&15, row=(lane>>4)*4+reg.
template<int MB, typename TIN>
__global__ __launch_bounds__(256) void mfma_gemm(
        const TIN* __restrict__ X, const unsigned short* __restrict__ Wt,
        unsigned short* __restrict__ Y, float* __restrict__ as_out,
        float* __restrict__ ad_out, const float* __restrict__ a_srcf,
        const float* __restrict__ a_dstf, int N, int K) {
    constexpr int NT_ = MB / 16;
    constexpr int C   = MB / 2;
    int tid  = threadIdx.x;
    int w    = tid >> 6, lane = tid & 63;
    int li   = lane & 15, kc = lane >> 4;
    int n0   = blockIdx.x * 64 + w * 16;
    int arow = min(n0 + li, N - 1);

    f32x4 acc[NT_];
#pragma unroll
    for (int ct = 0; ct < NT_; ++ct) acc[ct] = (f32x4){0.f, 0.f, 0.f, 0.f};

    for (int k0 = 0; k0 < K; k0 += 32) {
        short8 a;
        if constexpr (sizeof(TIN) == 4) {
            const float* xp = (const float*)X + (size_t)arow * K + k0 + kc * 8;
            float4 xa = *(const float4*)xp;
            float4 xb = *(const float4*)(xp + 4);
            a[0] = (short)f2bf(xa.x); a[1] = (short)f2bf(xa.y);
            a[2] = (short)f2bf(xa.z); a[3] = (short)f2bf(xa.w);
            a[4] = (short)f2bf(xb.x); a[5] = (short)f2bf(xb.y);
            a[6] = (short)f2bf(xb.z); a[7] = (short)f2bf(xb.w);
        } else {
            a = *(const short8*)((const unsigned short*)X + (size_t)arow * K + k0 + kc * 8);
        }
        const unsigned short* wp = Wt + (size_t)li * K + k0 + kc * 8;
#pragma unroll
        for (int ct = 0; ct < NT_; ++ct) {
            short8 b = *(const short8*)(wp + (size_t)ct * 16 * K);
            acc[ct] = __builtin_amdgcn_mfma_f32_16x16x32_bf16(a, b, acc[ct], 0, 0, 0);
        }
    }

    // preload alpha vectors for this lane's column slot
    float av[NT_], dv[NT_];
#pragma unroll
    for (int ct = 0; ct < NT_; ++ct) {
        av[ct] = a_srcf[ct * 16 + li];
        dv[ct] = a_dstf[ct * 16 + li];
    }
    int row_base = n0 + kc * 4;
#pragma unroll
    for (int r = 0; r < 4; ++r) {
        int n = row_base + r;
        float vs0 = 0.f, vs1 = 0.f, vd0 = 0.f, vd1 = 0.f;
#pragma unroll
        for (int ct = 0; ct < NT_; ++ct) {
            float v = acc[ct][r];
            if (ct * 16 < C) { vs0 = fmaf(v, av[ct], vs0); vd0 = fmaf(v, dv[ct], vd0); }
            else             { vs1 = fmaf(v, av[ct], vs1); vd1 = fmaf(v, dv[ct], vd1); }
        }
#pragma unroll
        for (int off = 1; off < 16; off <<= 1) {
            vs0 += __shfl_xor(vs0, off);
            vs1 += __shfl_xor(vs1, off);
            vd0 += __shfl_xor(vd0, off);
            vd1 += __shfl_xor(vd1, off);
        }
        if (n < N) {
            if (li == 0) {
                as_out[n * 2] = vs0; as_out[n * 2 + 1] = vs1;
                ad_out[n * 2] = vd0; ad_out[n * 2 + 1] = vd1;
            }
#pragma unroll
            for (int ct = 0; ct < NT_; ++ct)
                Y[(size_t)n * MB + ct * 16 + li] = f2bf(acc[ct][r]);
        }
    }
}

// ---------------- CSR build ----------------
__global__ void hist_kernel(const int* __restrict__ ei, int E, int N, int* __restrict__ deg) {
    int e = blockIdx.x * blockDim.x + threadIdx.x;
    if (e >= E + N) return;
    int d = (e < E) ? ei[E + e] : e - E;
    atomicAdd(&deg[d], 1);
}

__global__ __launch_bounds__(256) void scan_part(const int* __restrict__ deg,
                                                 int* __restrict__ tsum) {
    int b = blockIdx.x, t = threadIdx.x;
    int base = b * STILE + t * 16;
    int sum = 0;
#pragma unroll
    for (int j = 0; j < 16; j += 4) {
        int4 q = *(const int4*)&deg[base + j];
        sum += q.x + q.y + q.z + q.w;
    }
#pragma unroll
    for (int off = 32; off; off >>= 1) sum += __shfl_down(sum, off);
    __shared__ int wsh[4];
    if ((t & 63) == 0) wsh[t >> 6] = sum;
    __syncthreads();
    if (t == 0) tsum[b] = wsh[0] + wsh[1] + wsh[2] + wsh[3];
}

__global__ void scan_tiles(int* __restrict__ tsum, int ntiles) {
    int lane = threadIdx.x;
    int v = (lane < ntiles) ? tsum[lane] : 0;
    int x = v;
#pragma unroll
    for (int off = 1; off < 64; off <<= 1) {
        int y = __shfl_up(x, off);
        if (lane >= off) x += y;
    }
    if (lane < ntiles) tsum[lane] = x - v;
}

__global__ __launch_bounds__(256) void scan_final(const int* __restrict__ deg,
                                                  const int* __restrict__ tsum,
                                                  int* __restrict__ rowptr) {
    int b = blockIdx.x, t = threadIdx.x, lane = t & 63, wid = t >> 6;
    int base = b * STILE + t * 16;
    int v[16];
    int sum = 0;
#pragma unroll
    for (int j = 0; j < 16; j += 4) {
        int4 q = *(const int4*)&deg[base + j];
        v[j] = q.x; v[j + 1] = q.y; v[j + 2] = q.z; v[j + 3] = q.w;
        sum += q.x + q.y + q.z + q.w;
    }
    int x = sum;
#pragma unroll
    for (int off = 1; off < 64; off <<= 1) {
        int y = __shfl_up(x, off);
        if (lane >= off) x += y;
    }
    __shared__ int wtot[4];
    if (lane == 63) wtot[wid] = x;
    __syncthreads();
    int woff = 0;
    for (int wi = 0; wi < wid; ++wi) woff += wtot[wi];
    int run = tsum[b] + woff + (x - sum);
    int outv[16];
#pragma unroll
    for (int j = 0; j < 16; ++j) { outv[j] = run; run += v[j]; }
#pragma unroll
    for (int j = 0; j < 16; j += 4)
        *(int4*)&rowptr[base + j] = make_int4(outv[j], outv[j+1], outv[j+2], outv[j+3]);
}

__global__ void fill_kernel(const int* __restrict__ ei, int E, int N,
                            const int* __restrict__ rowptr, int* __restrict__ cursor,
                            int* __restrict__ csr_src) {
    int e = blockIdx.x * blockDim.x + threadIdx.x;
    if (e >= E + N) return;
    int s, d;
    if (e < E) { s = ei[e]; d = ei[E + e]; } else { s = d = e - E; }
    int pos = atomicAdd(&cursor[d], 1);
    csr_src[rowptr[d] + pos] = s;
}

// ---------------- fused attn+agg: wave per node, bf16 gather, TOUT = bf16 or f32 ----------------
template<int M, int C, typename TOUT>
__global__ __launch_bounds__(256) void fused_attn_agg(
        const int* __restrict__ rowptr, const int* __restrict__ csr_src,
        const float* __restrict__ as_, const float* __restrict__ ad_,
        const unsigned short* __restrict__ hfeat, const float* __restrict__ bias,
        TOUT* __restrict__ outp, int N, int do_relu) {
    constexpr int VEC = M / 64;   // 4 (L1) or 2 (L2)
    int n    = (blockIdx.x * blockDim.x + threadIdx.x) >> 6;
    int lane = threadIdx.x & 63;
    if (n >= N) return;
    int cbase = lane * VEC;
    int hh    = cbase / C;
    int r0 = rowptr[n], r1 = rowptr[n + 1];
    const float2* as2 = (const float2*)as_;
    float2 adv = ((const float2*)ad_)[n];
    float m0 = -INFINITY, m1 = -INFINITY;
    float s0 = 0.f, s1 = 0.f;
    float acc[VEC];
#pragma unroll
    for (int v = 0; v < VEC; ++v) acc[v] = 0.f;

    for (int base = r0; base < r1; base += 64) {
        int cnt = min(64, r1 - base);
        int srcl = 0;
        float sc0 = -INFINITY, sc1 = -INFINITY;
        if (lane < cnt) {
            srcl = csr_src[base + lane];
            float2 asv = as2[srcl];
            float e0 = asv.x + adv.x;
            float e1 = asv.y + adv.y;
            sc0 = (e0 > 0.f) ? e0 : NEG_SLOPE * e0;
            sc1 = (e1 > 0.f) ? e1 : NEG_SLOPE * e1;
        }
        float pm0 = sc0, pm1 = sc1;
#pragma unroll
        for (int off = 32; off; off >>= 1) {
            pm0 = fmaxf(pm0, __shfl_xor(pm0, off));
            pm1 = fmaxf(pm1, __shfl_xor(pm1, off));
        }
        float mn0 = fmaxf(m0, pm0), mn1 = fmaxf(m1, pm1);
        float f0 = expf(m0 - mn0), f1 = expf(m1 - mn1);
        float p0 = expf(sc0 - mn0), p1 = expf(sc1 - mn1);
        float ps0 = p0, ps1 = p1;
#pragma unroll
        for (int off = 32; off; off >>= 1) {
            ps0 += __shfl_xor(ps0, off);
            ps1 += __shfl_xor(ps1, off);
        }
        s0 = s0 * f0 + ps0;
        s1 = s1 * f1 + ps1;
        float fa = (hh == 0) ? f0 : f1;
#pragma unroll
        for (int v = 0; v < VEC; ++v) acc[v] *= fa;
        m0 = mn0; m1 = mn1;
        // bf16 gather-fma, unrolled x2
        for (int e = 0; e < cnt; e += 2) {
            float pj[2]; int sj[2];
#pragma unroll
            for (int j = 0; j < 2; ++j) {
                int idx = e + j;
                float pe0 = __shfl(p0, idx & 63);
                float pe1 = __shfl(p1, idx & 63);
                int   se  = __shfl(srcl, idx & 63);
                pj[j] = (idx < cnt) ? ((hh == 0) ? pe0 : pe1) : 0.f;
                sj[j] = se;
            }
            if constexpr (VEC == 4) {
                uint2 q0 = *(const uint2*)(hfeat + sj[0] * M + cbase);
                uint2 q1 = *(const uint2*)(hfeat + sj[1] * M + cbase);
                acc[0] += pj[0] * bflo(q0.x); acc[1] += pj[0] * bfhi(q0.x);
                acc[2] += pj[0] * bflo(q0.y); acc[3] += pj[0] * bfhi(q0.y);
                acc[0] += pj[1] * bflo(q1.x); acc[1] += pj[1] * bfhi(q1.x);
                acc[2] += pj[1] * bflo(q1.y); acc[3] += pj[1] * bfhi(q1.y);
            } else {
                unsigned q0 = *(const unsigned*)(hfeat + sj[0] * M + cbase);
                unsigned q1 = *(const unsigned*)(hfeat + sj[1] * M + cbase);
                acc[0] += pj[0] * bflo(q0); acc[1] += pj[0] * bfhi(q0);
                acc[0] += pj[1] * bflo(q1); acc[1] += pj[1] * bfhi(q1);
            }
        }
    }
    float ssum = (hh == 0) ? s0 : s1;
    float inv = 1.f / (ssum + EPS_F);
    float o[VEC];
#pragma unroll
    for (int v = 0; v < VEC; ++v) {
        float val = acc[v] * inv + bias[cbase + v];
        o[v] = do_relu ? fmaxf(val, 0.f) : val;
    }
    if constexpr (sizeof(TOUT) == 2) {
        unsigned short* op = (unsigned short*)outp + (size_t)n * M + cbase;
        if constexpr (VEC == 4) {
            uint2 pk;
            pk.x = (unsigned)f2bf(o[0]) | ((unsigned)f2bf(o[1]) << 16);
            pk.y = (unsigned)f2bf(o[2]) | ((unsigned)f2bf(o[3]) << 16);
            *(uint2*)op = pk;
        } else {
            *(unsigned*)op = (unsigned)f2bf(o[0]) | ((unsigned)f2bf(o[1]) << 16);
        }
    } else {
        float* op = (float*)outp + (size_t)n * M + cbase;
        if constexpr (VEC == 4) *(float4*)op = make_float4(o[0], o[1], o[2], o[3]);
        else                    *(float2*)op = make_float2(o[0], o[1]);
    }
}

// ---------------- decode: one wave per positive edge, float2 ----------------
__global__ void decode_kernel(const int* __restrict__ pei, int Ep,
                              const float* __restrict__ z, int D,
                              float* __restrict__ out) {
    int wid  = (blockIdx.x * blockDim.x + threadIdx.x) >> 6;
    int lane = threadIdx.x & 63;
    if (wid >= Ep) return;
    int a = pei[wid], b = pei[Ep + wid];
    const float2* za = (const float2*)(z + (size_t)a * D);
    const float2* zb = (const float2*)(z + (size_t)b * D);
    float s = 0.f;
    for (int i = lane; i < D / 2; i += 64) {
        float2 xv = za[i], yv = zb[i];
        s += xv.x * yv.x + xv.y * yv.y;
    }
    for (int off = 32; off; off >>= 1) s += __shfl_down(s, off);
    if (lane == 0) out[wid] = s;
}

extern "C" void kernel_launch(void* const* d_in, const int* in_sizes, int n_in,
                              void* d_out, int out_size, void* d_ws, size_t ws_size,
                              hipStream_t stream) {
    const float* x   = (const float*)d_in[0];
    const int*   ei  = (const int*)d_in[1];
    const int*   pei = (const int*)d_in[2];
    const float* W1  = (const float*)d_in[3];
    const float* a1s = (const float*)d_in[4];
    const float* a1d = (const float*)d_in[5];
    const float* b1  = (const float*)d_in[6];
    const float* W2  = (const float*)d_in[7];
    const float* a2s = (const float*)d_in[8];
    const float* a2d = (const float*)d_in[9];
    const float* b2  = (const float*)d_in[10];
    float* out = (float*)d_out;

    const int M1  = in_sizes[6];            // 256
    const int Fin = in_sizes[3] / M1;       // 128
    const int N   = in_sizes[0] / Fin;      // 50000
    const int E   = in_sizes[1] / 2;        // 800000
    const int Ep  = in_sizes[2] / 2;        // 100000
    const int M2  = in_sizes[10];           // 128
    const int Etot = E + N;
    const int NT  = (N + STILE - 1) / STILE;   // scan tiles (13)

    // workspace layout (16B-aligned sections)
    unsigned short* hbf  = (unsigned short*)d_ws;         // N*M1 bf16 gather table
    unsigned short* h1bf = hbf + (size_t)N * M1;          // N*M1 bf16 h1
    float* zbuf    = (float*)(h1bf + (size_t)N * M1);     // N*M2 f32 z
    float* as_     = zbuf + (size_t)N * M2;               // N*2
    float* ad_     = as_ + (size_t)N * 2;                 // N*2
    int*   deg     = (int*)(ad_ + (size_t)N * 2);         // NT*STILE (padded)
    int*   rowptr  = deg + (size_t)NT * STILE;            // NT*STILE (padded; rowptr[N] valid)
    int*   tsum    = rowptr + (size_t)NT * STILE;         // 64
    int*   cursor  = tsum + 64;                           // N
    int*   csr_src = cursor + N;                          // Etot
    unsigned short* wt1 = (unsigned short*)(csr_src + Etot);   // M1*Fin bf16 (W1^T)
    unsigned short* wt2 = wt1 + (size_t)M1 * Fin;              // M2*M1 bf16 (W2^T)

    dim3 blk256(256);

    // ---- W prep (independent) ----
    prep_w<<<(M1 * Fin + 255) / 256, blk256, 0, stream>>>(W1, wt1, Fin, M1);
    prep_w<<<(M2 * M1 + 255) / 256, blk256, 0, stream>>>(W2, wt2, M1, M2);

    // ---- CSR build (shared by both layers) ----
    hipMemsetAsync(deg, 0, (size_t)NT * STILE * sizeof(int), stream);
    hipMemsetAsync(cursor, 0, (size_t)N * sizeof(int), stream);
    hist_kernel<<<(Etot + 255) / 256, blk256, 0, stream>>>(ei, E, N, deg);
    scan_part<<<NT, blk256, 0, stream>>>(deg, tsum);
    scan_tiles<<<1, 64, 0, stream>>>(tsum, NT);
    scan_final<<<NT, blk256, 0, stream>>>(deg, tsum, rowptr);
    fill_kernel<<<(Etot + 255) / 256, blk256, 0, stream>>>(ei, E, N, rowptr, cursor, csr_src);

    // ---- Layer 1: MFMA gemm(f32 x) -> bf16 table + alpha; attn -> bf16 h1 ----
    mfma_gemm<256, float><<<(N + 63) / 64, blk256, 0, stream>>>(
        x, wt1, hbf, as_, ad_, a1s, a1d, N, Fin);
    fused_attn_agg<256, 128, unsigned short><<<(N + 3) / 4, blk256, 0, stream>>>(
        rowptr, csr_src, as_, ad_, hbf, b1, h1bf, N, 1);

    // ---- Layer 2: MFMA gemm(bf16 h1) -> bf16 table + alpha; attn -> f32 z ----
    mfma_gemm<128, unsigned short><<<(N + 63) / 64, blk256, 0, stream>>>(
        h1bf, wt2, hbf, as_, ad_, a2s, a2d, N, M1);
    fused_attn_agg<128, 64, float><<<(N + 3) / 4, blk256, 0, stream>>>(
        rowptr, csr_src, as_, ad_, hbf, b2, zbuf, N, 0);

    // ---- Decode ----
    decode_kernel<<<(Ep * 64 + 255) / 256, blk256, 0, stream>>>(
        pei, Ep, zbuf, M2, out);
}

// Round 11
// 306.293 us; speedup vs baseline: 5.5863x; 1.0470x over previous
//
#include <hip/hip_runtime.h>

#define NEG_SLOPE 0.2f
#define EPS_F 1e-16f
#define STILE 4096

typedef short short8 __attribute__((ext_vector_type(8)));
typedef float f32x4 __attribute__((ext_vector_type(4)));

// round-to-nearest-even f32 -> bf16 (finite inputs)
__device__ __forceinline__ unsigned short f2bf(float x) {
    unsigned u = __float_as_uint(x);
    return (unsigned short)((u + 0x7FFFu + ((u >> 16) & 1u)) >> 16);
}
__device__ __forceinline__ float bflo(unsigned q) { return __uint_as_float(q << 16); }
__device__ __forceinline__ float bfhi(unsigned q) { return __uint_as_float(q & 0xFFFF0000u); }

// ---------------- W prep: Wt_bf16[MB][K] = bf16(W[K][MB]^T) ----------------
__global__ void prep_w(const float* __restrict__ W, unsigned short* __restrict__ Wt,
                       int K, int MB) {
    int i = blockIdx.x * blockDim.x + threadIdx.x;
    if (i >= MB * K) return;
    int m = i / K, k = i - m * K;
    Wt[i] = f2bf(W[(size_t)k * MB + m]);
}

// ---------------- MFMA GEMM + fused alpha ----------------
template<int MB, typename TIN>
__global__ __launch_bounds__(256) void mfma_gemm(
        const TIN* __restrict__ X, const unsigned short* __restrict__ Wt,
        unsigned short* __restrict__ Y, float* __restrict__ as_out,
        float* __restrict__ ad_out, const float* __restrict__ a_srcf,
        const float* __restrict__ a_dstf, int N, int K) {
    constexpr int NT_ = MB / 16;
    constexpr int C   = MB / 2;
    int tid  = threadIdx.x;
    int w    = tid >> 6, lane = tid & 63;
    int li   = lane & 15, kc = lane >> 4;
    int n0   = blockIdx.x * 64 + w * 16;
    int arow = min(n0 + li, N - 1);

    f32x4 acc[NT_];
#pragma unroll
    for (int ct = 0; ct < NT_; ++ct) acc[ct] = (f32x4){0.f, 0.f, 0.f, 0.f};

    for (int k0 = 0; k0 < K; k0 += 32) {
        short8 a;
        if constexpr (sizeof(TIN) == 4) {
            const float* xp = (const float*)X + (size_t)arow * K + k0 + kc * 8;
            float4 xa = *(const float4*)xp;
            float4 xb = *(const float4*)(xp + 4);
            a[0] = (short)f2bf(xa.x); a[1] = (short)f2bf(xa.y);
            a[2] = (short)f2bf(xa.z); a[3] = (short)f2bf(xa.w);
            a[4] = (short)f2bf(xb.x); a[5] = (short)f2bf(xb.y);
            a[6] = (short)f2bf(xb.z); a[7] = (short)f2bf(xb.w);
        } else {
            a = *(const short8*)((const unsigned short*)X + (size_t)arow * K + k0 + kc * 8);
        }
        const unsigned short* wp = Wt + (size_t)li * K + k0 + kc * 8;
#pragma unroll
        for (int ct = 0; ct < NT_; ++ct) {
            short8 b = *(const short8*)(wp + (size_t)ct * 16 * K);
            acc[ct] = __builtin_amdgcn_mfma_f32_16x16x32_bf16(a, b, acc[ct], 0, 0, 0);
        }
    }

    float av[NT_], dv[NT_];
#pragma unroll
    for (int ct = 0; ct < NT_; ++ct) {
        av[ct] = a_srcf[ct * 16 + li];
        dv[ct] = a_dstf[ct * 16 + li];
    }
    int row_base = n0 + kc * 4;
#pragma unroll
    for (int r = 0; r < 4; ++r) {
        int n = row_base + r;
        float vs0 = 0.f, vs1 = 0.f, vd0 = 0.f, vd1 = 0.f;
#pragma unroll
        for (int ct = 0; ct < NT_; ++ct) {
            float v = acc[ct][r];
            if (ct * 16 < C) { vs0 = fmaf(v, av[ct], vs0); vd0 = fmaf(v, dv[ct], vd0); }
            else             { vs1 = fmaf(v, av[ct], vs1); vd1 = fmaf(v, dv[ct], vd1); }
        }
#pragma unroll
        for (int off = 1; off < 16; off <<= 1) {
            vs0 += __shfl_xor(vs0, off);
            vs1 += __shfl_xor(vs1, off);
            vd0 += __shfl_xor(vd0, off);
            vd1 += __shfl_xor(vd1, off);
        }
        if (n < N) {
            if (li == 0) {
                as_out[n * 2] = vs0; as_out[n * 2 + 1] = vs1;
                ad_out[n * 2] = vd0; ad_out[n * 2 + 1] = vd1;
            }
#pragma unroll
            for (int ct = 0; ct < NT_; ++ct)
                Y[(size_t)n * MB + ct * 16 + li] = f2bf(acc[ct][r]);
        }
    }
}

// ---------------- CSR build ----------------
__global__ void hist_kernel(const int* __restrict__ ei, int E, int N, int* __restrict__ deg) {
    int e = blockIdx.x * blockDim.x + threadIdx.x;
    if (e >= E + N) return;
    int d = (e < E) ? ei[E + e] : e - E;
    atomicAdd(&deg[d], 1);
}

__global__ __launch_bounds__(256) void scan_part(const int* __restrict__ deg,
                                                 int* __restrict__ tsum) {
    int b = blockIdx.x, t = threadIdx.x;
    int base = b * STILE + t * 16;
    int sum = 0;
#pragma unroll
    for (int j = 0; j < 16; j += 4) {
        int4 q = *(const int4*)&deg[base + j];
        sum += q.x + q.y + q.z + q.w;
    }
#pragma unroll
    for (int off = 32; off; off >>= 1) sum += __shfl_down(sum, off);
    __shared__ int wsh[4];
    if ((t & 63) == 0) wsh[t >> 6] = sum;
    __syncthreads();
    if (t == 0) tsum[b] = wsh[0] + wsh[1] + wsh[2] + wsh[3];
}

__global__ void scan_tiles(int* __restrict__ tsum, int ntiles) {
    int lane = threadIdx.x;
    int v = (lane < ntiles) ? tsum[lane] : 0;
    int x = v;
#pragma unroll
    for (int off = 1; off < 64; off <<= 1) {
        int y = __shfl_up(x, off);
        if (lane >= off) x += y;
    }
    if (lane < ntiles) tsum[lane] = x - v;
}

__global__ __launch_bounds__(256) void scan_final(const int* __restrict__ deg,
                                                  const int* __restrict__ tsum,
                                                  int* __restrict__ rowptr) {
    int b = blockIdx.x, t = threadIdx.x, lane = t & 63, wid = t >> 6;
    int base = b * STILE + t * 16;
    int v[16];
    int sum = 0;
#pragma unroll
    for (int j = 0; j < 16; j += 4) {
        int4 q = *(const int4*)&deg[base + j];
        v[j] = q.x; v[j + 1] = q.y; v[j + 2] = q.z; v[j + 3] = q.w;
        sum += q.x + q.y + q.z + q.w;
    }
    int x = sum;
#pragma unroll
    for (int off = 1; off < 64; off <<= 1) {
        int y = __shfl_up(x, off);
        if (lane >= off) x += y;
    }
    __shared__ int wtot[4];
    if (lane == 63) wtot[wid] = x;
    __syncthreads();
    int woff = 0;
    for (int wi = 0; wi < wid; ++wi) woff += wtot[wi];
    int run = tsum[b] + woff + (x - sum);
    int outv[16];
#pragma unroll
    for (int j = 0; j < 16; ++j) { outv[j] = run; run += v[j]; }
#pragma unroll
    for (int j = 0; j < 16; j += 4)
        *(int4*)&rowptr[base + j] = make_int4(outv[j], outv[j+1], outv[j+2], outv[j+3]);
}

__global__ void fill_kernel(const int* __restrict__ ei, int E, int N,
                            const int* __restrict__ rowptr, int* __restrict__ cursor,
                            int* __restrict__ csr_src) {
    int e = blockIdx.x * blockDim.x + threadIdx.x;
    if (e >= E + N) return;
    int s, d;
    if (e < E) { s = ei[e]; d = ei[E + e]; } else { s = d = e - E; }
    int pos = atomicAdd(&cursor[d], 1);
    csr_src[rowptr[d] + pos] = s;
}

// ---------------- fused attn+agg v7: wave per node, no-max softmax, LDS broadcast ----------------
// p = exp(sc) directly (scores are O(10); f32 exp overflows at 88 — safe).
// Per chunk each lane writes {byte_off, p} per head to per-wave LDS; inner loop
// does ONE ds_read_b64 broadcast per edge (replaces 3 ds_bpermute). Denominator
// accumulated lane-locally; single wave reduce at the end.
template<int M, int C, typename TOUT>
__global__ __launch_bounds__(256) void fused_attn_agg(
        const int* __restrict__ rowptr, const int* __restrict__ csr_src,
        const float* __restrict__ as_, const float* __restrict__ ad_,
        const unsigned short* __restrict__ hfeat, const float* __restrict__ bias,
        TOUT* __restrict__ outp, int N, int do_relu) {
    constexpr int VEC = M / 64;   // 4 (L1) or 2 (L2)
    __shared__ uint2 pb0[4][64];  // {byte_off, p_head0}
    __shared__ uint2 pb1[4][64];  // {byte_off, p_head1}
    int n    = (blockIdx.x * blockDim.x + threadIdx.x) >> 6;
    int lane = threadIdx.x & 63;
    int w    = (threadIdx.x >> 6) & 3;
    if (n >= N) return;
    int cbase = lane * VEC;
    int hh    = cbase / C;
    int r0 = rowptr[n], r1 = rowptr[n + 1];
    const float2* as2 = (const float2*)as_;
    float2 adv = ((const float2*)ad_)[n];
    float sa0 = 0.f, sa1 = 0.f;    // lane-local denominator partials
    float acc[VEC];
#pragma unroll
    for (int v = 0; v < VEC; ++v) acc[v] = 0.f;
    const uint2* a0 = pb0[w];
    const uint2* a1 = pb1[w];

    for (int base = r0; base < r1; base += 64) {
        int cnt = min(64, r1 - base);
        int srcl = 0;
        float sc0 = -INFINITY, sc1 = -INFINITY;
        if (lane < cnt) {
            srcl = csr_src[base + lane];
            float2 asv = as2[srcl];
            float e0 = asv.x + adv.x;
            float e1 = asv.y + adv.y;
            sc0 = (e0 > 0.f) ? e0 : NEG_SLOPE * e0;
            sc1 = (e1 > 0.f) ? e1 : NEG_SLOPE * e1;
        }
        float p0 = expf(sc0), p1 = expf(sc1);   // 0 for tail lanes
        sa0 += p0; sa1 += p1;
        unsigned off = (unsigned)srcl * (M * 2);
        pb0[w][lane] = make_uint2(off, __float_as_uint(p0));
        pb1[w][lane] = make_uint2(off, __float_as_uint(p1));
        // gather-fma: 1 ds_read_b64 broadcast per edge
        for (int e = 0; e < cnt; e += 2) {
            uint2 q0 = (hh == 0) ? a0[e] : a1[e];
            uint2 q1 = (hh == 0) ? a0[e + 1] : a1[e + 1];  // entry e+1<=63; p=0 beyond cnt
            float pa = __uint_as_float(q0.y);
            float pc = __uint_as_float(q1.y);
            const unsigned short* hp0 = (const unsigned short*)((const char*)hfeat + q0.x) + cbase;
            const unsigned short* hp1 = (const unsigned short*)((const char*)hfeat + q1.x) + cbase;
            if constexpr (VEC == 4) {
                uint2 g0 = *(const uint2*)hp0;
                uint2 g1 = *(const uint2*)hp1;
                acc[0] += pa * bflo(g0.x); acc[1] += pa * bfhi(g0.x);
                acc[2] += pa * bflo(g0.y); acc[3] += pa * bfhi(g0.y);
                acc[0] += pc * bflo(g1.x); acc[1] += pc * bfhi(g1.x);
                acc[2] += pc * bflo(g1.y); acc[3] += pc * bfhi(g1.y);
            } else {
                unsigned g0 = *(const unsigned*)hp0;
                unsigned g1 = *(const unsigned*)hp1;
                acc[0] += pa * bflo(g0); acc[1] += pa * bfhi(g0);
                acc[0] += pc * bflo(g1); acc[1] += pc * bfhi(g1);
            }
        }
    }
    // single denominator reduce
#pragma unroll
    for (int off = 32; off; off >>= 1) {
        sa0 += __shfl_xor(sa0, off);
        sa1 += __shfl_xor(sa1, off);
    }
    float ssum = (hh == 0) ? sa0 : sa1;
    float inv = 1.f / (ssum + EPS_F);
    float o[VEC];
#pragma unroll
    for (int v = 0; v < VEC; ++v) {
        float val = acc[v] * inv + bias[cbase + v];
        o[v] = do_relu ? fmaxf(val, 0.f) : val;
    }
    if constexpr (sizeof(TOUT) == 2) {
        unsigned short* op = (unsigned short*)outp + (size_t)n * M + cbase;
        if constexpr (VEC == 4) {
            uint2 pk;
            pk.x = (unsigned)f2bf(o[0]) | ((unsigned)f2bf(o[1]) << 16);
            pk.y = (unsigned)f2bf(o[2]) | ((unsigned)f2bf(o[3]) << 16);
            *(uint2*)op = pk;
        } else {
            *(unsigned*)op = (unsigned)f2bf(o[0]) | ((unsigned)f2bf(o[1]) << 16);
        }
    } else {
        float* op = (float*)outp + (size_t)n * M + cbase;
        if constexpr (VEC == 4) *(float4*)op = make_float4(o[0], o[1], o[2], o[3]);
        else                    *(float2*)op = make_float2(o[0], o[1]);
    }
}

// ---------------- decode: one wave per positive edge, float2 ----------------
__global__ void decode_kernel(const int* __restrict__ pei, int Ep,
                              const float* __restrict__ z, int D,
                              float* __restrict__ out) {
    int wid  = (blockIdx.x * blockDim.x + threadIdx.x) >> 6;
    int lane = threadIdx.x & 63;
    if (wid >= Ep) return;
    int a = pei[wid], b = pei[Ep + wid];
    const float2* za = (const float2*)(z + (size_t)a * D);
    const float2* zb = (const float2*)(z + (size_t)b * D);
    float s = 0.f;
    for (int i = lane; i < D / 2; i += 64) {
        float2 xv = za[i], yv = zb[i];
        s += xv.x * yv.x + xv.y * yv.y;
    }
    for (int off = 32; off; off >>= 1) s += __shfl_down(s, off);
    if (lane == 0) out[wid] = s;
}

extern "C" void kernel_launch(void* const* d_in, const int* in_sizes, int n_in,
                              void* d_out, int out_size, void* d_ws, size_t ws_size,
                              hipStream_t stream) {
    const float* x   = (const float*)d_in[0];
    const int*   ei  = (const int*)d_in[1];
    const int*   pei = (const int*)d_in[2];
    const float* W1  = (const float*)d_in[3];
    const float* a1s = (const float*)d_in[4];
    const float* a1d = (const float*)d_in[5];
    const float* b1  = (const float*)d_in[6];
    const float* W2  = (const float*)d_in[7];
    const float* a2s = (const float*)d_in[8];
    const float* a2d = (const float*)d_in[9];
    const float* b2  = (const float*)d_in[10];
    float* out = (float*)d_out;

    const int M1  = in_sizes[6];            // 256
    const int Fin = in_sizes[3] / M1;       // 128
    const int N   = in_sizes[0] / Fin;      // 50000
    const int E   = in_sizes[1] / 2;        // 800000
    const int Ep  = in_sizes[2] / 2;        // 100000
    const int M2  = in_sizes[10];           // 128
    const int Etot = E + N;
    const int NT  = (N + STILE - 1) / STILE;   // scan tiles (13)

    // workspace layout (16B-aligned sections)
    unsigned short* hbf  = (unsigned short*)d_ws;         // N*M1 bf16 gather table
    unsigned short* h1bf = hbf + (size_t)N * M1;          // N*M1 bf16 h1
    float* zbuf    = (float*)(h1bf + (size_t)N * M1);     // N*M2 f32 z
    float* as_     = zbuf + (size_t)N * M2;               // N*2
    float* ad_     = as_ + (size_t)N * 2;                 // N*2
    int*   deg     = (int*)(ad_ + (size_t)N * 2);         // NT*STILE (padded)
    int*   rowptr  = deg + (size_t)NT * STILE;            // NT*STILE (padded; rowptr[N] valid)
    int*   tsum    = rowptr + (size_t)NT * STILE;         // 64
    int*   cursor  = tsum + 64;                           // N
    int*   csr_src = cursor + N;                          // Etot
    unsigned short* wt1 = (unsigned short*)(csr_src + Etot);   // M1*Fin bf16 (W1^T)
    unsigned short* wt2 = wt1 + (size_t)M1 * Fin;              // M2*M1 bf16 (W2^T)

    dim3 blk256(256);

    // ---- W prep (independent) ----
    prep_w<<<(M1 * Fin + 255) / 256, blk256, 0, stream>>>(W1, wt1, Fin, M1);
    prep_w<<<(M2 * M1 + 255) / 256, blk256, 0, stream>>>(W2, wt2, M1, M2);

    // ---- CSR build (shared by both layers) ----
    hipMemsetAsync(deg, 0, (size_t)NT * STILE * sizeof(int), stream);
    hipMemsetAsync(cursor, 0, (size_t)N * sizeof(int), stream);
    hist_kernel<<<(Etot + 255) / 256, blk256, 0, stream>>>(ei, E, N, deg);
    scan_part<<<NT, blk256, 0, stream>>>(deg, tsum);
    scan_tiles<<<1, 64, 0, stream>>>(tsum, NT);
    scan_final<<<NT, blk256, 0, stream>>>(deg, tsum, rowptr);
    fill_kernel<<<(Etot + 255) / 256, blk256, 0, stream>>>(ei, E, N, rowptr, cursor, csr_src);

    // ---- Layer 1: MFMA gemm(f32 x) -> bf16 table + alpha; attn -> bf16 h1 ----
    mfma_gemm<256, float><<<(N + 63) / 64, blk256, 0, stream>>>(
        x, wt1, hbf, as_, ad_, a1s, a1d, N, Fin);
    fused_attn_agg<256, 128, unsigned short><<<(N + 3) / 4, blk256, 0, stream>>>(
        rowptr, csr_src, as_, ad_, hbf, b1, h1bf, N, 1);

    // ---- Layer 2: MFMA gemm(bf16 h1) -> bf16 table + alpha; attn -> f32 z ----
    mfma_gemm<128, unsigned short><<<(N + 63) / 64, blk256, 0, stream>>>(
        h1bf, wt2, hbf, as_, ad_, a2s, a2d, N, M1);
    fused_attn_agg<128, 64, float><<<(N + 3) / 4, blk256, 0, stream>>>(
        rowptr, csr_src, as_, ad_, hbf, b2, zbuf, N, 0);

    // ---- Decode ----
    decode_kernel<<<(Ep * 64 + 255) / 256, blk256, 0, stream>>>(
        pei, Ep, zbuf, M2, out);
}

// Round 12
// 301.361 us; speedup vs baseline: 5.6777x; 1.0164x over previous
//
#include <hip/hip_runtime.h>

#define NEG_SLOPE 0.2f
#define EPS_F 1e-16f
#define STILE 4096

typedef short short8 __attribute__((ext_vector_type(8)));
typedef float f32x4 __attribute__((ext_vector_type(4)));

// round-to-nearest-even f32 -> bf16 (finite inputs)
__device__ __forceinline__ unsigned short f2bf(float x) {
    unsigned u = __float_as_uint(x);
    return (unsigned short)((u + 0x7FFFu + ((u >> 16) & 1u)) >> 16);
}
__device__ __forceinline__ float bflo(unsigned q) { return __uint_as_float(q << 16); }
__device__ __forceinline__ float bfhi(unsigned q) { return __uint_as_float(q & 0xFFFF0000u); }

// ---------------- W prep (both weights in one launch): Wt_bf16[MB][K] = bf16(W^T) ----------------
__global__ void prep_w_all(const float* __restrict__ W1, unsigned short* __restrict__ Wt1,
                           int K1, int M1,
                           const float* __restrict__ W2, unsigned short* __restrict__ Wt2,
                           int K2, int M2) {
    int i = blockIdx.x * blockDim.x + threadIdx.x;
    int n1 = M1 * K1;
    if (i < n1) {
        int m = i / K1, k = i - m * K1;
        Wt1[i] = f2bf(W1[(size_t)k * M1 + m]);
    } else {
        int j = i - n1;
        if (j < M2 * K2) {
            int m = j / K2, k = j - m * K2;
            Wt2[j] = f2bf(W2[(size_t)k * M2 + m]);
        }
    }
}

// ---------------- MFMA GEMM + fused alpha ----------------
template<int MB, typename TIN>
__global__ __launch_bounds__(256) void mfma_gemm(
        const TIN* __restrict__ X, const unsigned short* __restrict__ Wt,
        unsigned short* __restrict__ Y, float* __restrict__ as_out,
        float* __restrict__ ad_out, const float* __restrict__ a_srcf,
        const float* __restrict__ a_dstf, int N, int K) {
    constexpr int NT_ = MB / 16;
    constexpr int C   = MB / 2;
    int tid  = threadIdx.x;
    int w    = tid >> 6, lane = tid & 63;
    int li   = lane & 15, kc = lane >> 4;
    int n0   = blockIdx.x * 64 + w * 16;
    int arow = min(n0 + li, N - 1);

    f32x4 acc[NT_];
#pragma unroll
    for (int ct = 0; ct < NT_; ++ct) acc[ct] = (f32x4){0.f, 0.f, 0.f, 0.f};

    for (int k0 = 0; k0 < K; k0 += 32) {
        short8 a;
        if constexpr (sizeof(TIN) == 4) {
            const float* xp = (const float*)X + (size_t)arow * K + k0 + kc * 8;
            float4 xa = *(const float4*)xp;
            float4 xb = *(const float4*)(xp + 4);
            a[0] = (short)f2bf(xa.x); a[1] = (short)f2bf(xa.y);
            a[2] = (short)f2bf(xa.z); a[3] = (short)f2bf(xa.w);
            a[4] = (short)f2bf(xb.x); a[5] = (short)f2bf(xb.y);
            a[6] = (short)f2bf(xb.z); a[7] = (short)f2bf(xb.w);
        } else {
            a = *(const short8*)((const unsigned short*)X + (size_t)arow * K + k0 + kc * 8);
        }
        const unsigned short* wp = Wt + (size_t)li * K + k0 + kc * 8;
#pragma unroll
        for (int ct = 0; ct < NT_; ++ct) {
            short8 b = *(const short8*)(wp + (size_t)ct * 16 * K);
            acc[ct] = __builtin_amdgcn_mfma_f32_16x16x32_bf16(a, b, acc[ct], 0, 0, 0);
        }
    }

    float av[NT_], dv[NT_];
#pragma unroll
    for (int ct = 0; ct < NT_; ++ct) {
        av[ct] = a_srcf[ct * 16 + li];
        dv[ct] = a_dstf[ct * 16 + li];
    }
    int row_base = n0 + kc * 4;
#pragma unroll
    for (int r = 0; r < 4; ++r) {
        int n = row_base + r;
        float vs0 = 0.f, vs1 = 0.f, vd0 = 0.f, vd1 = 0.f;
#pragma unroll
        for (int ct = 0; ct < NT_; ++ct) {
            float v = acc[ct][r];
            if (ct * 16 < C) { vs0 = fmaf(v, av[ct], vs0); vd0 = fmaf(v, dv[ct], vd0); }
            else             { vs1 = fmaf(v, av[ct], vs1); vd1 = fmaf(v, dv[ct], vd1); }
        }
#pragma unroll
        for (int off = 1; off < 16; off <<= 1) {
            vs0 += __shfl_xor(vs0, off);
            vs1 += __shfl_xor(vs1, off);
            vd0 += __shfl_xor(vd0, off);
            vd1 += __shfl_xor(vd1, off);
        }
        if (n < N) {
            if (li == 0) {
                as_out[n * 2] = vs0; as_out[n * 2 + 1] = vs1;
                ad_out[n * 2] = vd0; ad_out[n * 2 + 1] = vd1;
            }
#pragma unroll
            for (int ct = 0; ct < NT_; ++ct)
                Y[(size_t)n * MB + ct * 16 + li] = f2bf(acc[ct][r]);
        }
    }
}

// ---------------- CSR build ----------------
__global__ void hist_kernel(const int* __restrict__ ei, int E, int N, int* __restrict__ deg) {
    int e = blockIdx.x * blockDim.x + threadIdx.x;
    if (e >= E + N) return;
    int d = (e < E) ? ei[E + e] : e - E;
    atomicAdd(&deg[d], 1);
}

__global__ __launch_bounds__(256) void scan_part(const int* __restrict__ deg,
                                                 int* __restrict__ tsum) {
    int b = blockIdx.x, t = threadIdx.x;
    int base = b * STILE + t * 16;
    int sum = 0;
#pragma unroll
    for (int j = 0; j < 16; j += 4) {
        int4 q = *(const int4*)&deg[base + j];
        sum += q.x + q.y + q.z + q.w;
    }
#pragma unroll
    for (int off = 32; off; off >>= 1) sum += __shfl_down(sum, off);
    __shared__ int wsh[4];
    if ((t & 63) == 0) wsh[t >> 6] = sum;
    __syncthreads();
    if (t == 0) tsum[b] = wsh[0] + wsh[1] + wsh[2] + wsh[3];
}

// downsweep: block per tile; computes tile prefix from raw tsum (NT<=16) itself;
// also zeroes cursor[] over the same padded index space.
__global__ __launch_bounds__(256) void scan_final(const int* __restrict__ deg,
                                                  const int* __restrict__ tsum,
                                                  int* __restrict__ rowptr,
                                                  int* __restrict__ cursor) {
    int b = blockIdx.x, t = threadIdx.x, lane = t & 63, wid = t >> 6;
    int base = b * STILE + t * 16;
    int tpre = 0;
    for (int j = 0; j < b; ++j) tpre += tsum[j];
    int v[16];
    int sum = 0;
#pragma unroll
    for (int j = 0; j < 16; j += 4) {
        int4 q = *(const int4*)&deg[base + j];
        v[j] = q.x; v[j + 1] = q.y; v[j + 2] = q.z; v[j + 3] = q.w;
        sum += q.x + q.y + q.z + q.w;
    }
    int x = sum;
#pragma unroll
    for (int off = 1; off < 64; off <<= 1) {
        int y = __shfl_up(x, off);
        if (lane >= off) x += y;
    }
    __shared__ int wtot[4];
    if (lane == 63) wtot[wid] = x;
    __syncthreads();
    int woff = 0;
    for (int wi = 0; wi < wid; ++wi) woff += wtot[wi];
    int run = tpre + woff + (x - sum);
    int outv[16];
#pragma unroll
    for (int j = 0; j < 16; ++j) { outv[j] = run; run += v[j]; }
#pragma unroll
    for (int j = 0; j < 16; j += 4) {
        *(int4*)&rowptr[base + j] = make_int4(outv[j], outv[j+1], outv[j+2], outv[j+3]);
        *(int4*)&cursor[base + j] = make_int4(0, 0, 0, 0);
    }
}

__global__ void fill_kernel(const int* __restrict__ ei, int E, int N,
                            const int* __restrict__ rowptr, int* __restrict__ cursor,
                            int* __restrict__ csr_src) {
    int e = blockIdx.x * blockDim.x + threadIdx.x;
    if (e >= E + N) return;
    int s, d;
    if (e < E) { s = ei[e]; d = ei[E + e]; } else { s = d = e - E; }
    int pos = atomicAdd(&cursor[d], 1);
    csr_src[rowptr[d] + pos] = s;
}

// ---------------- fused attn+agg: wave per node, no-max softmax, LDS b128 broadcast ----------------
template<int M, int C, typename TOUT>
__global__ __launch_bounds__(256) void fused_attn_agg(
        const int* __restrict__ rowptr, const int* __restrict__ csr_src,
        const float* __restrict__ as_, const float* __restrict__ ad_,
        const unsigned short* __restrict__ hfeat, const float* __restrict__ bias,
        TOUT* __restrict__ outp, int N, int do_relu) {
    constexpr int VEC = M / 64;   // 4 (L1) or 2 (L2)
    __shared__ __align__(16) uint2 pb0[4][64];  // {byte_off, p_head0}
    __shared__ __align__(16) uint2 pb1[4][64];  // {byte_off, p_head1}
    int n    = (blockIdx.x * blockDim.x + threadIdx.x) >> 6;
    int lane = threadIdx.x & 63;
    int w    = (threadIdx.x >> 6) & 3;
    if (n >= N) return;
    int cbase = lane * VEC;
    int hh    = cbase / C;
    int r0 = rowptr[n], r1 = rowptr[n + 1];
    const float2* as2 = (const float2*)as_;
    float2 adv = ((const float2*)ad_)[n];
    float sa0 = 0.f, sa1 = 0.f;
    float acc[VEC];
#pragma unroll
    for (int v = 0; v < VEC; ++v) acc[v] = 0.f;
    const uint2* ap = (hh == 0) ? pb0[w] : pb1[w];

    for (int base = r0; base < r1; base += 64) {
        int cnt = min(64, r1 - base);
        int srcl = 0;
        float sc0 = -INFINITY, sc1 = -INFINITY;
        if (lane < cnt) {
            srcl = csr_src[base + lane];
            float2 asv = as2[srcl];
            float e0 = asv.x + adv.x;
            float e1 = asv.y + adv.y;
            sc0 = (e0 > 0.f) ? e0 : NEG_SLOPE * e0;
            sc1 = (e1 > 0.f) ? e1 : NEG_SLOPE * e1;
        }
        float p0 = expf(sc0), p1 = expf(sc1);   // 0 for tail lanes
        sa0 += p0; sa1 += p1;
        unsigned off = (unsigned)srcl * (M * 2);
        pb0[w][lane] = make_uint2(off, __float_as_uint(p0));
        pb1[w][lane] = make_uint2(off, __float_as_uint(p1));
        // gather-fma: one ds_read_b128 per 2 edges
        for (int e = 0; e < cnt; e += 2) {
            uint4 qq = *(const uint4*)&ap[e];
            float pa = __uint_as_float(qq.y);
            float pc = __uint_as_float(qq.w);
            const unsigned short* hp0 = (const unsigned short*)((const char*)hfeat + qq.x) + cbase;
            const unsigned short* hp1 = (const unsigned short*)((const char*)hfeat + qq.z) + cbase;
            if constexpr (VEC == 4) {
                uint2 g0 = *(const uint2*)hp0;
                uint2 g1 = *(const uint2*)hp1;
                acc[0] += pa * bflo(g0.x); acc[1] += pa * bfhi(g0.x);
                acc[2] += pa * bflo(g0.y); acc[3] += pa * bfhi(g0.y);
                acc[0] += pc * bflo(g1.x); acc[1] += pc * bfhi(g1.x);
                acc[2] += pc * bflo(g1.y); acc[3] += pc * bfhi(g1.y);
            } else {
                unsigned g0 = *(const unsigned*)hp0;
                unsigned g1 = *(const unsigned*)hp1;
                acc[0] += pa * bflo(g0); acc[1] += pa * bfhi(g0);
                acc[0] += pc * bflo(g1); acc[1] += pc * bfhi(g1);
            }
        }
    }
#pragma unroll
    for (int off = 32; off; off >>= 1) {
        sa0 += __shfl_xor(sa0, off);
        sa1 += __shfl_xor(sa1, off);
    }
    float ssum = (hh == 0) ? sa0 : sa1;
    float inv = 1.f / (ssum + EPS_F);
    float o[VEC];
#pragma unroll
    for (int v = 0; v < VEC; ++v) {
        float val = acc[v] * inv + bias[cbase + v];
        o[v] = do_relu ? fmaxf(val, 0.f) : val;
    }
    if constexpr (sizeof(TOUT) == 2) {
        unsigned short* op = (unsigned short*)outp + (size_t)n * M + cbase;
        if constexpr (VEC == 4) {
            uint2 pk;
            pk.x = (unsigned)f2bf(o[0]) | ((unsigned)f2bf(o[1]) << 16);
            pk.y = (unsigned)f2bf(o[2]) | ((unsigned)f2bf(o[3]) << 16);
            *(uint2*)op = pk;
        } else {
            *(unsigned*)op = (unsigned)f2bf(o[0]) | ((unsigned)f2bf(o[1]) << 16);
        }
    } else {
        float* op = (float*)outp + (size_t)n * M + cbase;
        if constexpr (VEC == 4) *(float4*)op = make_float4(o[0], o[1], o[2], o[3]);
        else                    *(float2*)op = make_float2(o[0], o[1]);
    }
}

// ---------------- decode: one wave per positive edge, float2 ----------------
__global__ void decode_kernel(const int* __restrict__ pei, int Ep,
                              const float* __restrict__ z, int D,
                              float* __restrict__ out) {
    int wid  = (blockIdx.x * blockDim.x + threadIdx.x) >> 6;
    int lane = threadIdx.x & 63;
    if (wid >= Ep) return;
    int a = pei[wid], b = pei[Ep + wid];
    const float2* za = (const float2*)(z + (size_t)a * D);
    const float2* zb = (const float2*)(z + (size_t)b * D);
    float s = 0.f;
    for (int i = lane; i < D / 2; i += 64) {
        float2 xv = za[i], yv = zb[i];
        s += xv.x * yv.x + xv.y * yv.y;
    }
    for (int off = 32; off; off >>= 1) s += __shfl_down(s, off);
    if (lane == 0) out[wid] = s;
}

extern "C" void kernel_launch(void* const* d_in, const int* in_sizes, int n_in,
                              void* d_out, int out_size, void* d_ws, size_t ws_size,
                              hipStream_t stream) {
    const float* x   = (const float*)d_in[0];
    const int*   ei  = (const int*)d_in[1];
    const int*   pei = (const int*)d_in[2];
    const float* W1  = (const float*)d_in[3];
    const float* a1s = (const float*)d_in[4];
    const float* a1d = (const float*)d_in[5];
    const float* b1  = (const float*)d_in[6];
    const float* W2  = (const float*)d_in[7];
    const float* a2s = (const float*)d_in[8];
    const float* a2d = (const float*)d_in[9];
    const float* b2  = (const float*)d_in[10];
    float* out = (float*)d_out;

    const int M1  = in_sizes[6];            // 256
    const int Fin = in_sizes[3] / M1;       // 128
    const int N   = in_sizes[0] / Fin;      // 50000
    const int E   = in_sizes[1] / 2;        // 800000
    const int Ep  = in_sizes[2] / 2;        // 100000
    const int M2  = in_sizes[10];           // 128
    const int Etot = E + N;
    const int NT  = (N + STILE - 1) / STILE;   // scan tiles (13)

    // workspace layout (16B-aligned sections)
    unsigned short* hbf  = (unsigned short*)d_ws;         // N*M1 bf16 gather table
    unsigned short* h1bf = hbf + (size_t)N * M1;          // N*M1 bf16 h1
    float* zbuf    = (float*)(h1bf + (size_t)N * M1);     // N*M2 f32 z
    float* as_     = zbuf + (size_t)N * M2;               // N*2
    float* ad_     = as_ + (size_t)N * 2;                 // N*2
    int*   deg     = (int*)(ad_ + (size_t)N * 2);         // NT*STILE (padded)
    int*   rowptr  = deg + (size_t)NT * STILE;            // NT*STILE (padded; rowptr[N] valid)
    int*   cursor  = rowptr + (size_t)NT * STILE;         // NT*STILE (padded)
    int*   tsum    = cursor + (size_t)NT * STILE;         // 64
    int*   csr_src = tsum + 64;                           // Etot
    unsigned short* wt1 = (unsigned short*)(csr_src + Etot);   // M1*Fin bf16 (W1^T)
    unsigned short* wt2 = wt1 + (size_t)M1 * Fin;              // M2*M1 bf16 (W2^T)

    dim3 blk256(256);

    // ---- W prep (one launch for both) ----
    {
        int tot = M1 * Fin + M2 * M1;
        prep_w_all<<<(tot + 255) / 256, blk256, 0, stream>>>(
            W1, wt1, Fin, M1, W2, wt2, M1, M2);
    }

    // ---- CSR build (shared by both layers) ----
    hipMemsetAsync(deg, 0, (size_t)NT * STILE * sizeof(int), stream);
    hist_kernel<<<(Etot + 255) / 256, blk256, 0, stream>>>(ei, E, N, deg);
    scan_part<<<NT, blk256, 0, stream>>>(deg, tsum);
    scan_final<<<NT, blk256, 0, stream>>>(deg, tsum, rowptr, cursor);
    fill_kernel<<<(Etot + 255) / 256, blk256, 0, stream>>>(ei, E, N, rowptr, cursor, csr_src);

    // ---- Layer 1: MFMA gemm(f32 x) -> bf16 table + alpha; attn -> bf16 h1 ----
    mfma_gemm<256, float><<<(N + 63) / 64, blk256, 0, stream>>>(
        x, wt1, hbf, as_, ad_, a1s, a1d, N, Fin);
    fused_attn_agg<256, 128, unsigned short><<<(N + 3) / 4, blk256, 0, stream>>>(
        rowptr, csr_src, as_, ad_, hbf, b1, h1bf, N, 1);

    // ---- Layer 2: MFMA gemm(bf16 h1) -> bf16 table + alpha; attn -> f32 z ----
    mfma_gemm<128, unsigned short><<<(N + 63) / 64, blk256, 0, stream>>>(
        h1bf, wt2, hbf, as_, ad_, a2s, a2d, N, M1);
    fused_attn_agg<128, 64, float><<<(N + 3) / 4, blk256, 0, stream>>>(
        rowptr, csr_src, as_, ad_, hbf, b2, zbuf, N, 0);

    // ---- Decode ----
    decode_kernel<<<(Ep * 64 + 255) / 256, blk256, 0, stream>>>(
        pei, Ep, zbuf, M2, out);
}

// Round 13
// 254.453 us; speedup vs baseline: 6.7244x; 1.1843x over previous
//
#include <hip/hip_runtime.h>

#define NEG_SLOPE 0.2f
#define EPS_F 1e-16f
#define STILE 4096

typedef short short8 __attribute__((ext_vector_type(8)));
typedef float f32x4 __attribute__((ext_vector_type(4)));

// round-to-nearest-even f32 -> bf16 (finite inputs)
__device__ __forceinline__ unsigned short f2bf(float x) {
    unsigned u = __float_as_uint(x);
    return (unsigned short)((u + 0x7FFFu + ((u >> 16) & 1u)) >> 16);
}
__device__ __forceinline__ float bflo(unsigned q) { return __uint_as_float(q << 16); }
__device__ __forceinline__ float bfhi(unsigned q) { return __uint_as_float(q & 0xFFFF0000u); }

// ================= device bodies =================

// GEMM body: Y_bf16[N,MB] = X[N,K] @ Wt^T; Wt[MB][K] staged in LDS (row pad +8 shorts).
// Wave owns 16 rows; A prefetched to regs; inner loop = ds_read_b128 + MFMA only.
template<int MB, int K, typename TIN>
__device__ __forceinline__ void gemm_body(
        const TIN* __restrict__ X, const unsigned short* __restrict__ Wt,
        unsigned short* __restrict__ Y, float* __restrict__ as_out,
        float* __restrict__ ad_out, const float* __restrict__ a_srcf,
        const float* __restrict__ a_dstf, int N, int bid,
        unsigned short* lds) {
    constexpr int NT_ = MB / 16;
    constexpr int C   = MB / 2;
    constexpr int KS  = K / 32;
    constexpr int KP  = K + 8;
    int tid  = threadIdx.x;
    int w    = tid >> 6, lane = tid & 63;
    int li   = lane & 15, kc = lane >> 4;
    int n0   = bid * 64 + w * 16;
    int arow = min(n0 + li, N - 1);

    // stage Wt -> LDS (padded rows)
    constexpr int CHUNKS = MB * K / 8;
#pragma unroll
    for (int c = 0; c < CHUNKS / 256; ++c) {
        int id = tid + c * 256;
        int m = id / (K / 8), k8 = id % (K / 8);
        *(uint4*)&lds[m * KP + k8 * 8] = *(const uint4*)&Wt[m * K + k8 * 8];
    }
    // prefetch A slice into regs
    short8 a[KS];
#pragma unroll
    for (int ks = 0; ks < KS; ++ks) {
        if constexpr (sizeof(TIN) == 4) {
            const float* xp = (const float*)X + (size_t)arow * K + ks * 32 + kc * 8;
            float4 xa = *(const float4*)xp;
            float4 xb = *(const float4*)(xp + 4);
            a[ks][0] = (short)f2bf(xa.x); a[ks][1] = (short)f2bf(xa.y);
            a[ks][2] = (short)f2bf(xa.z); a[ks][3] = (short)f2bf(xa.w);
            a[ks][4] = (short)f2bf(xb.x); a[ks][5] = (short)f2bf(xb.y);
            a[ks][6] = (short)f2bf(xb.z); a[ks][7] = (short)f2bf(xb.w);
        } else {
            a[ks] = *(const short8*)((const unsigned short*)X + (size_t)arow * K + ks * 32 + kc * 8);
        }
    }
    __syncthreads();

    f32x4 acc[NT_];
#pragma unroll
    for (int ct = 0; ct < NT_; ++ct) acc[ct] = (f32x4){0.f, 0.f, 0.f, 0.f};
#pragma unroll
    for (int ct = 0; ct < NT_; ++ct) {
        const unsigned short* wb = lds + (ct * 16 + li) * KP + kc * 8;
#pragma unroll
        for (int ks = 0; ks < KS; ++ks) {
            short8 b = *(const short8*)(wb + ks * 32);
            acc[ct] = __builtin_amdgcn_mfma_f32_16x16x32_bf16(a[ks], b, acc[ct], 0, 0, 0);
        }
    }

    float av[NT_], dv[NT_];
#pragma unroll
    for (int ct = 0; ct < NT_; ++ct) {
        av[ct] = a_srcf[ct * 16 + li];
        dv[ct] = a_dstf[ct * 16 + li];
    }
    int row_base = n0 + kc * 4;
#pragma unroll
    for (int r = 0; r < 4; ++r) {
        int n = row_base + r;
        float vs0 = 0.f, vs1 = 0.f, vd0 = 0.f, vd1 = 0.f;
#pragma unroll
        for (int ct = 0; ct < NT_; ++ct) {
            float v = acc[ct][r];
            if (ct * 16 < C) { vs0 = fmaf(v, av[ct], vs0); vd0 = fmaf(v, dv[ct], vd0); }
            else             { vs1 = fmaf(v, av[ct], vs1); vd1 = fmaf(v, dv[ct], vd1); }
        }
#pragma unroll
        for (int off = 1; off < 16; off <<= 1) {
            vs0 += __shfl_xor(vs0, off);
            vs1 += __shfl_xor(vs1, off);
            vd0 += __shfl_xor(vd0, off);
            vd1 += __shfl_xor(vd1, off);
        }
        if (n < N) {
            if (li == 0) {
                as_out[n * 2] = vs0; as_out[n * 2 + 1] = vs1;
                ad_out[n * 2] = vd0; ad_out[n * 2 + 1] = vd1;
            }
#pragma unroll
            for (int ct = 0; ct < NT_; ++ct)
                Y[(size_t)n * MB + ct * 16 + li] = f2bf(acc[ct][r]);
        }
    }
}

// scan_part body: per-tile sum
__device__ __forceinline__ void scan_part_body(const int* __restrict__ deg,
                                               int* __restrict__ tsum, int b) {
    __shared__ int wsh[4];
    int t = threadIdx.x;
    int base = b * STILE + t * 16;
    int sum = 0;
#pragma unroll
    for (int j = 0; j < 16; j += 4) {
        int4 q = *(const int4*)&deg[base + j];
        sum += q.x + q.y + q.z + q.w;
    }
#pragma unroll
    for (int off = 32; off; off >>= 1) sum += __shfl_down(sum, off);
    if ((t & 63) == 0) wsh[t >> 6] = sum;
    __syncthreads();
    if (t == 0) tsum[b] = wsh[0] + wsh[1] + wsh[2] + wsh[3];
}

// ================= kernels =================

// {W prep || histogram} — independent work, one launch
__global__ void k_prep_hist(const float* __restrict__ W1, unsigned short* __restrict__ Wt1,
                            int K1, int M1,
                            const float* __restrict__ W2, unsigned short* __restrict__ Wt2,
                            int K2, int M2, int nPrepBlk,
                            const int* __restrict__ ei, int E, int N,
                            int* __restrict__ deg) {
    if ((int)blockIdx.x < nPrepBlk) {
        int i = blockIdx.x * 256 + threadIdx.x;
        int n1 = M1 * K1;
        if (i < n1) {
            int m = i / K1, k = i - m * K1;
            Wt1[i] = f2bf(W1[(size_t)k * M1 + m]);
        } else {
            int j = i - n1;
            if (j < M2 * K2) {
                int m = j / K2, k = j - m * K2;
                Wt2[j] = f2bf(W2[(size_t)k * M2 + m]);
            }
        }
    } else {
        int e = (blockIdx.x - nPrepBlk) * 256 + threadIdx.x;
        if (e >= E + N) return;
        int d = (e < E) ? ei[E + e] : e - E;
        atomicAdd(&deg[d], 1);
    }
}

// {GEMM layer1 || scan_part} — gemm needs Wt1 (done), scan needs deg (done)
__global__ __launch_bounds__(256) void k_gemm1_scan(
        const float* __restrict__ X, const unsigned short* __restrict__ Wt,
        unsigned short* __restrict__ Y, float* __restrict__ as_out,
        float* __restrict__ ad_out, const float* __restrict__ a_srcf,
        const float* __restrict__ a_dstf, int N, int GB,
        const int* __restrict__ deg, int* __restrict__ tsum) {
    __shared__ __align__(16) unsigned short lds[256 * (128 + 8)];
    if ((int)blockIdx.x < GB)
        gemm_body<256, 128, float>(X, Wt, Y, as_out, ad_out, a_srcf, a_dstf, N,
                                   blockIdx.x, lds);
    else
        scan_part_body(deg, tsum, blockIdx.x - GB);
}

// GEMM layer2 standalone
__global__ __launch_bounds__(256) void k_gemm2(
        const unsigned short* __restrict__ X, const unsigned short* __restrict__ Wt,
        unsigned short* __restrict__ Y, float* __restrict__ as_out,
        float* __restrict__ ad_out, const float* __restrict__ a_srcf,
        const float* __restrict__ a_dstf, int N) {
    __shared__ __align__(16) unsigned short lds[128 * (256 + 8)];
    gemm_body<128, 256, unsigned short>(X, Wt, Y, as_out, ad_out, a_srcf, a_dstf, N,
                                        blockIdx.x, lds);
}

// downsweep: block per tile; serial prefix of tsum (NT<=16); zeroes cursor too.
__global__ __launch_bounds__(256) void scan_final(const int* __restrict__ deg,
                                                  const int* __restrict__ tsum,
                                                  int* __restrict__ rowptr,
                                                  int* __restrict__ cursor) {
    int b = blockIdx.x, t = threadIdx.x, lane = t & 63, wid = t >> 6;
    int base = b * STILE + t * 16;
    int tpre = 0;
    for (int j = 0; j < b; ++j) tpre += tsum[j];
    int v[16];
    int sum = 0;
#pragma unroll
    for (int j = 0; j < 16; j += 4) {
        int4 q = *(const int4*)&deg[base + j];
        v[j] = q.x; v[j + 1] = q.y; v[j + 2] = q.z; v[j + 3] = q.w;
        sum += q.x + q.y + q.z + q.w;
    }
    int x = sum;
#pragma unroll
    for (int off = 1; off < 64; off <<= 1) {
        int y = __shfl_up(x, off);
        if (lane >= off) x += y;
    }
    __shared__ int wtot[4];
    if (lane == 63) wtot[wid] = x;
    __syncthreads();
    int woff = 0;
    for (int wi = 0; wi < wid; ++wi) woff += wtot[wi];
    int run = tpre + woff + (x - sum);
    int outv[16];
#pragma unroll
    for (int j = 0; j < 16; ++j) { outv[j] = run; run += v[j]; }
#pragma unroll
    for (int j = 0; j < 16; j += 4) {
        *(int4*)&rowptr[base + j] = make_int4(outv[j], outv[j+1], outv[j+2], outv[j+3]);
        *(int4*)&cursor[base + j] = make_int4(0, 0, 0, 0);
    }
}

__global__ void fill_kernel(const int* __restrict__ ei, int E, int N,
                            const int* __restrict__ rowptr, int* __restrict__ cursor,
                            int* __restrict__ csr_src) {
    int e = blockIdx.x * blockDim.x + threadIdx.x;
    if (e >= E + N) return;
    int s, d;
    if (e < E) { s = ei[e]; d = ei[E + e]; } else { s = d = e - E; }
    int pos = atomicAdd(&cursor[d], 1);
    csr_src[rowptr[d] + pos] = s;
}

// ---------------- fused attn+agg: wave per node, no-max softmax, LDS b128 broadcast ----------------
template<int M, int C, typename TOUT>
__global__ __launch_bounds__(256) void fused_attn_agg(
        const int* __restrict__ rowptr, const int* __restrict__ csr_src,
        const float* __restrict__ as_, const float* __restrict__ ad_,
        const unsigned short* __restrict__ hfeat, const float* __restrict__ bias,
        TOUT* __restrict__ outp, int N, int do_relu) {
    constexpr int VEC = M / 64;   // 4 (L1) or 2 (L2)
    __shared__ __align__(16) uint2 pb0[4][64];  // {byte_off, p_head0}
    __shared__ __align__(16) uint2 pb1[4][64];  // {byte_off, p_head1}
    int n    = (blockIdx.x * blockDim.x + threadIdx.x) >> 6;
    int lane = threadIdx.x & 63;
    int w    = (threadIdx.x >> 6) & 3;
    if (n >= N) return;
    int cbase = lane * VEC;
    int hh    = cbase / C;
    int r0 = rowptr[n], r1 = rowptr[n + 1];
    const float2* as2 = (const float2*)as_;
    float2 adv = ((const float2*)ad_)[n];
    float sa0 = 0.f, sa1 = 0.f;
    float acc[VEC];
#pragma unroll
    for (int v = 0; v < VEC; ++v) acc[v] = 0.f;
    const uint2* ap = (hh == 0) ? pb0[w] : pb1[w];

    for (int base = r0; base < r1; base += 64) {
        int cnt = min(64, r1 - base);
        int srcl = 0;
        float sc0 = -INFINITY, sc1 = -INFINITY;
        if (lane < cnt) {
            srcl = csr_src[base + lane];
            float2 asv = as2[srcl];
            float e0 = asv.x + adv.x;
            float e1 = asv.y + adv.y;
            sc0 = (e0 > 0.f) ? e0 : NEG_SLOPE * e0;
            sc1 = (e1 > 0.f) ? e1 : NEG_SLOPE * e1;
        }
        float p0 = expf(sc0), p1 = expf(sc1);   // 0 for tail lanes
        sa0 += p0; sa1 += p1;
        unsigned off = (unsigned)srcl * (M * 2);
        pb0[w][lane] = make_uint2(off, __float_as_uint(p0));
        pb1[w][lane] = make_uint2(off, __float_as_uint(p1));
        // gather-fma: one ds_read_b128 per 2 edges
        for (int e = 0; e < cnt; e += 2) {
            uint4 qq = *(const uint4*)&ap[e];
            float pa = __uint_as_float(qq.y);
            float pc = __uint_as_float(qq.w);
            const unsigned short* hp0 = (const unsigned short*)((const char*)hfeat + qq.x) + cbase;
            const unsigned short* hp1 = (const unsigned short*)((const char*)hfeat + qq.z) + cbase;
            if constexpr (VEC == 4) {
                uint2 g0 = *(const uint2*)hp0;
                uint2 g1 = *(const uint2*)hp1;
                acc[0] += pa * bflo(g0.x); acc[1] += pa * bfhi(g0.x);
                acc[2] += pa * bflo(g0.y); acc[3] += pa * bfhi(g0.y);
                acc[0] += pc * bflo(g1.x); acc[1] += pc * bfhi(g1.x);
                acc[2] += pc * bflo(g1.y); acc[3] += pc * bfhi(g1.y);
            } else {
                unsigned g0 = *(const unsigned*)hp0;
                unsigned g1 = *(const unsigned*)hp1;
                acc[0] += pa * bflo(g0); acc[1] += pa * bfhi(g0);
                acc[0] += pc * bflo(g1); acc[1] += pc * bfhi(g1);
            }
        }
    }
#pragma unroll
    for (int off = 32; off; off >>= 1) {
        sa0 += __shfl_xor(sa0, off);
        sa1 += __shfl_xor(sa1, off);
    }
    float ssum = (hh == 0) ? sa0 : sa1;
    float inv = 1.f / (ssum + EPS_F);
    float o[VEC];
#pragma unroll
    for (int v = 0; v < VEC; ++v) {
        float val = acc[v] * inv + bias[cbase + v];
        o[v] = do_relu ? fmaxf(val, 0.f) : val;
    }
    if constexpr (sizeof(TOUT) == 2) {
        unsigned short* op = (unsigned short*)outp + (size_t)n * M + cbase;
        if constexpr (VEC == 4) {
            uint2 pk;
            pk.x = (unsigned)f2bf(o[0]) | ((unsigned)f2bf(o[1]) << 16);
            pk.y = (unsigned)f2bf(o[2]) | ((unsigned)f2bf(o[3]) << 16);
            *(uint2*)op = pk;
        } else {
            *(unsigned*)op = (unsigned)f2bf(o[0]) | ((unsigned)f2bf(o[1]) << 16);
        }
    } else {
        float* op = (float*)outp + (size_t)n * M + cbase;
        if constexpr (VEC == 4) *(float4*)op = make_float4(o[0], o[1], o[2], o[3]);
        else                    *(float2*)op = make_float2(o[0], o[1]);
    }
}

// ---------------- decode: one wave per positive edge, float2 ----------------
__global__ void decode_kernel(const int* __restrict__ pei, int Ep,
                              const float* __restrict__ z, int D,
                              float* __restrict__ out) {
    int wid  = (blockIdx.x * blockDim.x + threadIdx.x) >> 6;
    int lane = threadIdx.x & 63;
    if (wid >= Ep) return;
    int a = pei[wid], b = pei[Ep + wid];
    const float2* za = (const float2*)(z + (size_t)a * D);
    const float2* zb = (const float2*)(z + (size_t)b * D);
    float s = 0.f;
    for (int i = lane; i < D / 2; i += 64) {
        float2 xv = za[i], yv = zb[i];
        s += xv.x * yv.x + xv.y * yv.y;
    }
    for (int off = 32; off; off >>= 1) s += __shfl_down(s, off);
    if (lane == 0) out[wid] = s;
}

extern "C" void kernel_launch(void* const* d_in, const int* in_sizes, int n_in,
                              void* d_out, int out_size, void* d_ws, size_t ws_size,
                              hipStream_t stream) {
    const float* x   = (const float*)d_in[0];
    const int*   ei  = (const int*)d_in[1];
    const int*   pei = (const int*)d_in[2];
    const float* W1  = (const float*)d_in[3];
    const float* a1s = (const float*)d_in[4];
    const float* a1d = (const float*)d_in[5];
    const float* b1  = (const float*)d_in[6];
    const float* W2  = (const float*)d_in[7];
    const float* a2s = (const float*)d_in[8];
    const float* a2d = (const float*)d_in[9];
    const float* b2  = (const float*)d_in[10];
    float* out = (float*)d_out;

    const int M1  = in_sizes[6];            // 256
    const int Fin = in_sizes[3] / M1;       // 128
    const int N   = in_sizes[0] / Fin;      // 50000
    const int E   = in_sizes[1] / 2;        // 800000
    const int Ep  = in_sizes[2] / 2;        // 100000
    const int M2  = in_sizes[10];           // 128
    const int Etot = E + N;
    const int NT  = (N + STILE - 1) / STILE;   // scan tiles (13)

    // workspace layout (16B-aligned sections)
    unsigned short* hbf  = (unsigned short*)d_ws;         // N*M1 bf16 gather table
    unsigned short* h1bf = hbf + (size_t)N * M1;          // N*M1 bf16 h1
    float* zbuf    = (float*)(h1bf + (size_t)N * M1);     // N*M2 f32 z
    float* as_     = zbuf + (size_t)N * M2;               // N*2
    float* ad_     = as_ + (size_t)N * 2;                 // N*2
    int*   deg     = (int*)(ad_ + (size_t)N * 2);         // NT*STILE (padded)
    int*   rowptr  = deg + (size_t)NT * STILE;            // NT*STILE (padded; rowptr[N] valid)
    int*   cursor  = rowptr + (size_t)NT * STILE;         // NT*STILE (padded)
    int*   tsum    = cursor + (size_t)NT * STILE;         // 64
    int*   csr_src = tsum + 64;                           // Etot
    unsigned short* wt1 = (unsigned short*)(csr_src + Etot);   // M1*Fin bf16 (W1^T)
    unsigned short* wt2 = wt1 + (size_t)M1 * Fin;              // M2*M1 bf16 (W2^T)

    dim3 blk256(256);

    // ---- node 1: zero deg ----
    hipMemsetAsync(deg, 0, (size_t)NT * STILE * sizeof(int), stream);

    // ---- node 2: {W prep || histogram} ----
    int nPrepBlk = (M1 * Fin + M2 * M1 + 255) / 256;
    int nHistBlk = (Etot + 255) / 256;
    k_prep_hist<<<nPrepBlk + nHistBlk, blk256, 0, stream>>>(
        W1, wt1, Fin, M1, W2, wt2, M1, M2, nPrepBlk, ei, E, N, deg);

    // ---- node 3: {GEMM L1 || scan_part} ----
    int GB = (N + 63) / 64;
    k_gemm1_scan<<<GB + NT, blk256, 0, stream>>>(
        x, wt1, hbf, as_, ad_, a1s, a1d, N, GB, deg, tsum);

    // ---- node 4-5: scan_final, fill ----
    scan_final<<<NT, blk256, 0, stream>>>(deg, tsum, rowptr, cursor);
    fill_kernel<<<nHistBlk, blk256, 0, stream>>>(ei, E, N, rowptr, cursor, csr_src);

    // ---- node 6: attn L1 -> bf16 h1 ----
    fused_attn_agg<256, 128, unsigned short><<<(N + 3) / 4, blk256, 0, stream>>>(
        rowptr, csr_src, as_, ad_, hbf, b1, h1bf, N, 1);

    // ---- node 7: GEMM L2 ----
    k_gemm2<<<(N + 63) / 64, blk256, 0, stream>>>(
        h1bf, wt2, hbf, as_, ad_, a2s, a2d, N);

    // ---- node 8: attn L2 -> f32 z ----
    fused_attn_agg<128, 64, float><<<(N + 3) / 4, blk256, 0, stream>>>(
        rowptr, csr_src, as_, ad_, hbf, b2, zbuf, N, 0);

    // ---- node 9: decode ----
    decode_kernel<<<(Ep * 64 + 255) / 256, blk256, 0, stream>>>(
        pei, Ep, zbuf, M2, out);
}

// Round 14
// 242.871 us; speedup vs baseline: 7.0451x; 1.0477x over previous
//
#include <hip/hip_runtime.h>

#define NEG_SLOPE 0.2f
#define EPS_F 1e-16f
#define STILE 4096

typedef short short8 __attribute__((ext_vector_type(8)));
typedef float f32x4 __attribute__((ext_vector_type(4)));

// round-to-nearest-even f32 -> bf16 (finite inputs)
__device__ __forceinline__ unsigned short f2bf(float x) {
    unsigned u = __float_as_uint(x);
    return (unsigned short)((u + 0x7FFFu + ((u >> 16) & 1u)) >> 16);
}
__device__ __forceinline__ float bflo(unsigned q) { return __uint_as_float(q << 16); }
__device__ __forceinline__ float bfhi(unsigned q) { return __uint_as_float(q & 0xFFFF0000u); }

// ================= device bodies =================

// GEMM body: Y_bf16[N,MB] = X[N,K] @ Wt^T; Wt[MB][K] staged in LDS (row pad +8 shorts).
template<int MB, int K, typename TIN>
__device__ __forceinline__ void gemm_body(
        const TIN* __restrict__ X, const unsigned short* __restrict__ Wt,
        unsigned short* __restrict__ Y, float* __restrict__ as_out,
        float* __restrict__ ad_out, const float* __restrict__ a_srcf,
        const float* __restrict__ a_dstf, int N, int bid,
        unsigned short* lds) {
    constexpr int NT_ = MB / 16;
    constexpr int C   = MB / 2;
    constexpr int KS  = K / 32;
    constexpr int KP  = K + 8;
    int tid  = threadIdx.x;
    int w    = tid >> 6, lane = tid & 63;
    int li   = lane & 15, kc = lane >> 4;
    int n0   = bid * 64 + w * 16;
    int arow = min(n0 + li, N - 1);

    constexpr int CHUNKS = MB * K / 8;
#pragma unroll
    for (int c = 0; c < CHUNKS / 256; ++c) {
        int id = tid + c * 256;
        int m = id / (K / 8), k8 = id % (K / 8);
        *(uint4*)&lds[m * KP + k8 * 8] = *(const uint4*)&Wt[m * K + k8 * 8];
    }
    short8 a[KS];
#pragma unroll
    for (int ks = 0; ks < KS; ++ks) {
        if constexpr (sizeof(TIN) == 4) {
            const float* xp = (const float*)X + (size_t)arow * K + ks * 32 + kc * 8;
            float4 xa = *(const float4*)xp;
            float4 xb = *(const float4*)(xp + 4);
            a[ks][0] = (short)f2bf(xa.x); a[ks][1] = (short)f2bf(xa.y);
            a[ks][2] = (short)f2bf(xa.z); a[ks][3] = (short)f2bf(xa.w);
            a[ks][4] = (short)f2bf(xb.x); a[ks][5] = (short)f2bf(xb.y);
            a[ks][6] = (short)f2bf(xb.z); a[ks][7] = (short)f2bf(xb.w);
        } else {
            a[ks] = *(const short8*)((const unsigned short*)X + (size_t)arow * K + ks * 32 + kc * 8);
        }
    }
    __syncthreads();

    f32x4 acc[NT_];
#pragma unroll
    for (int ct = 0; ct < NT_; ++ct) acc[ct] = (f32x4){0.f, 0.f, 0.f, 0.f};
#pragma unroll
    for (int ct = 0; ct < NT_; ++ct) {
        const unsigned short* wb = lds + (ct * 16 + li) * KP + kc * 8;
#pragma unroll
        for (int ks = 0; ks < KS; ++ks) {
            short8 b = *(const short8*)(wb + ks * 32);
            acc[ct] = __builtin_amdgcn_mfma_f32_16x16x32_bf16(a[ks], b, acc[ct], 0, 0, 0);
        }
    }

    float av[NT_], dv[NT_];
#pragma unroll
    for (int ct = 0; ct < NT_; ++ct) {
        av[ct] = a_srcf[ct * 16 + li];
        dv[ct] = a_dstf[ct * 16 + li];
    }
    int row_base = n0 + kc * 4;
#pragma unroll
    for (int r = 0; r < 4; ++r) {
        int n = row_base + r;
        float vs0 = 0.f, vs1 = 0.f, vd0 = 0.f, vd1 = 0.f;
#pragma unroll
        for (int ct = 0; ct < NT_; ++ct) {
            float v = acc[ct][r];
            if (ct * 16 < C) { vs0 = fmaf(v, av[ct], vs0); vd0 = fmaf(v, dv[ct], vd0); }
            else             { vs1 = fmaf(v, av[ct], vs1); vd1 = fmaf(v, dv[ct], vd1); }
        }
#pragma unroll
        for (int off = 1; off < 16; off <<= 1) {
            vs0 += __shfl_xor(vs0, off);
            vs1 += __shfl_xor(vs1, off);
            vd0 += __shfl_xor(vd0, off);
            vd1 += __shfl_xor(vd1, off);
        }
        if (n < N) {
            if (li == 0) {
                as_out[n * 2] = vs0; as_out[n * 2 + 1] = vs1;
                ad_out[n * 2] = vd0; ad_out[n * 2 + 1] = vd1;
            }
#pragma unroll
            for (int ct = 0; ct < NT_; ++ct)
                Y[(size_t)n * MB + ct * 16 + li] = f2bf(acc[ct][r]);
        }
    }
}

__device__ __forceinline__ void scan_part_body(const int* __restrict__ deg,
                                               int* __restrict__ tsum, int b) {
    __shared__ int wsh[4];
    int t = threadIdx.x;
    int base = b * STILE + t * 16;
    int sum = 0;
#pragma unroll
    for (int j = 0; j < 16; j += 4) {
        int4 q = *(const int4*)&deg[base + j];
        sum += q.x + q.y + q.z + q.w;
    }
#pragma unroll
    for (int off = 32; off; off >>= 1) sum += __shfl_down(sum, off);
    if ((t & 63) == 0) wsh[t >> 6] = sum;
    __syncthreads();
    if (t == 0) tsum[b] = wsh[0] + wsh[1] + wsh[2] + wsh[3];
}

// ================= kernels =================

__global__ void k_prep_hist(const float* __restrict__ W1, unsigned short* __restrict__ Wt1,
                            int K1, int M1,
                            const float* __restrict__ W2, unsigned short* __restrict__ Wt2,
                            int K2, int M2, int nPrepBlk,
                            const int* __restrict__ ei, int E, int N,
                            int* __restrict__ deg) {
    if ((int)blockIdx.x < nPrepBlk) {
        int i = blockIdx.x * 256 + threadIdx.x;
        int n1 = M1 * K1;
        if (i < n1) {
            int m = i / K1, k = i - m * K1;
            Wt1[i] = f2bf(W1[(size_t)k * M1 + m]);
        } else {
            int j = i - n1;
            if (j < M2 * K2) {
                int m = j / K2, k = j - m * K2;
                Wt2[j] = f2bf(W2[(size_t)k * M2 + m]);
            }
        }
    } else {
        int e = (blockIdx.x - nPrepBlk) * 256 + threadIdx.x;
        if (e >= E + N) return;
        int d = (e < E) ? ei[E + e] : e - E;
        atomicAdd(&deg[d], 1);
    }
}

__global__ __launch_bounds__(256) void k_gemm1_scan(
        const float* __restrict__ X, const unsigned short* __restrict__ Wt,
        unsigned short* __restrict__ Y, float* __restrict__ as_out,
        float* __restrict__ ad_out, const float* __restrict__ a_srcf,
        const float* __restrict__ a_dstf, int N, int GB,
        const int* __restrict__ deg, int* __restrict__ tsum) {
    __shared__ __align__(16) unsigned short lds[256 * (128 + 8)];
    if ((int)blockIdx.x < GB)
        gemm_body<256, 128, float>(X, Wt, Y, as_out, ad_out, a_srcf, a_dstf, N,
                                   blockIdx.x, lds);
    else
        scan_part_body(deg, tsum, blockIdx.x - GB);
}

__global__ __launch_bounds__(256) void k_gemm2(
        const unsigned short* __restrict__ X, const unsigned short* __restrict__ Wt,
        unsigned short* __restrict__ Y, float* __restrict__ as_out,
        float* __restrict__ ad_out, const float* __restrict__ a_srcf,
        const float* __restrict__ a_dstf, int N) {
    __shared__ __align__(16) unsigned short lds[128 * (256 + 8)];
    gemm_body<128, 256, unsigned short>(X, Wt, Y, as_out, ad_out, a_srcf, a_dstf, N,
                                        blockIdx.x, lds);
}

__global__ __launch_bounds__(256) void scan_final(const int* __restrict__ deg,
                                                  const int* __restrict__ tsum,
                                                  int* __restrict__ rowptr,
                                                  int* __restrict__ cursor) {
    int b = blockIdx.x, t = threadIdx.x, lane = t & 63, wid = t >> 6;
    int base = b * STILE + t * 16;
    int tpre = 0;
    for (int j = 0; j < b; ++j) tpre += tsum[j];
    int v[16];
    int sum = 0;
#pragma unroll
    for (int j = 0; j < 16; j += 4) {
        int4 q = *(const int4*)&deg[base + j];
        v[j] = q.x; v[j + 1] = q.y; v[j + 2] = q.z; v[j + 3] = q.w;
        sum += q.x + q.y + q.z + q.w;
    }
    int x = sum;
#pragma unroll
    for (int off = 1; off < 64; off <<= 1) {
        int y = __shfl_up(x, off);
        if (lane >= off) x += y;
    }
    __shared__ int wtot[4];
    if (lane == 63) wtot[wid] = x;
    __syncthreads();
    int woff = 0;
    for (int wi = 0; wi < wid; ++wi) woff += wtot[wi];
    int run = tpre + woff + (x - sum);
    int outv[16];
#pragma unroll
    for (int j = 0; j < 16; ++j) { outv[j] = run; run += v[j]; }
#pragma unroll
    for (int j = 0; j < 16; j += 4) {
        *(int4*)&rowptr[base + j] = make_int4(outv[j], outv[j+1], outv[j+2], outv[j+3]);
        *(int4*)&cursor[base + j] = make_int4(0, 0, 0, 0);
    }
}

__global__ void fill_kernel(const int* __restrict__ ei, int E, int N,
                            const int* __restrict__ rowptr, int* __restrict__ cursor,
                            int* __restrict__ csr_src) {
    int e = blockIdx.x * blockDim.x + threadIdx.x;
    if (e >= E + N) return;
    int s, d;
    if (e < E) { s = ei[e]; d = ei[E + e]; } else { s = d = e - E; }
    int pos = atomicAdd(&cursor[d], 1);
    csr_src[rowptr[d] + pos] = s;
}

// ---------------- fused attn+agg v8: wave/node, no-max softmax, 2-deep SW pipeline ----------------
template<int M, int C, typename TOUT>
__global__ __launch_bounds__(256) void fused_attn_agg(
        const int* __restrict__ rowptr, const int* __restrict__ csr_src,
        const float* __restrict__ as_, const float* __restrict__ ad_,
        const unsigned short* __restrict__ hfeat, const float* __restrict__ bias,
        TOUT* __restrict__ outp, int N, int do_relu) {
    constexpr int VEC = M / 64;   // 4 (L1) or 2 (L2)
    __shared__ __align__(16) uint2 pb0[4][64];  // {byte_off, p_head0}
    __shared__ __align__(16) uint2 pb1[4][64];  // {byte_off, p_head1}
    int n    = (blockIdx.x * blockDim.x + threadIdx.x) >> 6;
    int lane = threadIdx.x & 63;
    int w    = (threadIdx.x >> 6) & 3;
    if (n >= N) return;
    int cbase = lane * VEC;
    int hh    = cbase / C;
    int r0 = rowptr[n], r1 = rowptr[n + 1];
    const float2* as2 = (const float2*)as_;
    float2 adv = ((const float2*)ad_)[n];
    float sa0 = 0.f, sa1 = 0.f;
    float acc[VEC];
#pragma unroll
    for (int v = 0; v < VEC; ++v) acc[v] = 0.f;
    const uint2* ap = (hh == 0) ? pb0[w] : pb1[w];
    const char* hbc = (const char*)hfeat + (size_t)cbase * 2;

    for (int base = r0; base < r1; base += 64) {
        int cnt = min(64, r1 - base);
        int srcl = 0;
        float sc0 = -INFINITY, sc1 = -INFINITY;
        if (lane < cnt) {
            srcl = csr_src[base + lane];
            float2 asv = as2[srcl];
            float e0 = asv.x + adv.x;
            float e1 = asv.y + adv.y;
            sc0 = (e0 > 0.f) ? e0 : NEG_SLOPE * e0;
            sc1 = (e1 > 0.f) ? e1 : NEG_SLOPE * e1;
        }
        float p0 = expf(sc0), p1 = expf(sc1);   // 0 for tail lanes
        sa0 += p0; sa1 += p1;
        unsigned off = (unsigned)srcl * (M * 2);  // inactive lanes -> row 0 (p=0, safe)
        pb0[w][lane] = make_uint2(off, __float_as_uint(p0));
        pb1[w][lane] = make_uint2(off, __float_as_uint(p1));
        // 2-deep software-pipelined gather: prefetch next LDS entry + globals
        if constexpr (VEC == 4) {
            uint4 qA = *(const uint4*)&ap[0];
            uint2 gA0 = *(const uint2*)(hbc + qA.x);
            uint2 gA1 = *(const uint2*)(hbc + qA.z);
            for (int e = 0; e < cnt; e += 2) {
                int en = (e + 2 < cnt) ? (e + 2) : e;
                uint4 qB = *(const uint4*)&ap[en];
                uint2 gB0 = *(const uint2*)(hbc + qB.x);
                uint2 gB1 = *(const uint2*)(hbc + qB.z);
                float pa = __uint_as_float(qA.y);
                float pc = __uint_as_float(qA.w);
                acc[0] += pa * bflo(gA0.x); acc[1] += pa * bfhi(gA0.x);
                acc[2] += pa * bflo(gA0.y); acc[3] += pa * bfhi(gA0.y);
                acc[0] += pc * bflo(gA1.x); acc[1] += pc * bfhi(gA1.x);
                acc[2] += pc * bflo(gA1.y); acc[3] += pc * bfhi(gA1.y);
                qA = qB; gA0 = gB0; gA1 = gB1;
            }
        } else {
            uint4 qA = *(const uint4*)&ap[0];
            unsigned gA0 = *(const unsigned*)(hbc + qA.x);
            unsigned gA1 = *(const unsigned*)(hbc + qA.z);
            for (int e = 0; e < cnt; e += 2) {
                int en = (e + 2 < cnt) ? (e + 2) : e;
                uint4 qB = *(const uint4*)&ap[en];
                unsigned gB0 = *(const unsigned*)(hbc + qB.x);
                unsigned gB1 = *(const unsigned*)(hbc + qB.z);
                float pa = __uint_as_float(qA.y);
                float pc = __uint_as_float(qA.w);
                acc[0] += pa * bflo(gA0); acc[1] += pa * bfhi(gA0);
                acc[0] += pc * bflo(gA1); acc[1] += pc * bfhi(gA1);
                qA = qB; gA0 = gB0; gA1 = gB1;
            }
        }
    }
#pragma unroll
    for (int off = 32; off; off >>= 1) {
        sa0 += __shfl_xor(sa0, off);
        sa1 += __shfl_xor(sa1, off);
    }
    float ssum = (hh == 0) ? sa0 : sa1;
    float inv = 1.f / (ssum + EPS_F);
    float o[VEC];
#pragma unroll
    for (int v = 0; v < VEC; ++v) {
        float val = acc[v] * inv + bias[cbase + v];
        o[v] = do_relu ? fmaxf(val, 0.f) : val;
    }
    if constexpr (sizeof(TOUT) == 2) {
        unsigned short* op = (unsigned short*)outp + (size_t)n * M + cbase;
        if constexpr (VEC == 4) {
            uint2 pk;
            pk.x = (unsigned)f2bf(o[0]) | ((unsigned)f2bf(o[1]) << 16);
            pk.y = (unsigned)f2bf(o[2]) | ((unsigned)f2bf(o[3]) << 16);
            *(uint2*)op = pk;
        } else {
            *(unsigned*)op = (unsigned)f2bf(o[0]) | ((unsigned)f2bf(o[1]) << 16);
        }
    } else {
        float* op = (float*)outp + (size_t)n * M + cbase;
        if constexpr (VEC == 4) *(float4*)op = make_float4(o[0], o[1], o[2], o[3]);
        else                    *(float2*)op = make_float2(o[0], o[1]);
    }
}

// ---------------- decode v2: one wave per 2 edges, float4 lanes ----------------
__global__ void decode_kernel(const int* __restrict__ pei, int Ep,
                              const float* __restrict__ z, int D,
                              float* __restrict__ out) {
    int wv   = (blockIdx.x * blockDim.x + threadIdx.x) >> 6;
    int lane = threadIdx.x & 63;
    int half = lane >> 5, sl = lane & 31;   // 32 lanes per edge; sl*4 covers D=128
    int e  = wv * 2 + half;
    int ec = min(e, Ep - 1);
    int a = pei[ec], b = pei[Ep + ec];
    float4 xa = *(const float4*)(z + (size_t)a * D + sl * 4);
    float4 xb = *(const float4*)(z + (size_t)b * D + sl * 4);
    float s = xa.x * xb.x + xa.y * xb.y + xa.z * xb.z + xa.w * xb.w;
#pragma unroll
    for (int off = 16; off; off >>= 1) s += __shfl_xor(s, off);
    if (sl == 0 && e < Ep) out[e] = s;
}

extern "C" void kernel_launch(void* const* d_in, const int* in_sizes, int n_in,
                              void* d_out, int out_size, void* d_ws, size_t ws_size,
                              hipStream_t stream) {
    const float* x   = (const float*)d_in[0];
    const int*   ei  = (const int*)d_in[1];
    const int*   pei = (const int*)d_in[2];
    const float* W1  = (const float*)d_in[3];
    const float* a1s = (const float*)d_in[4];
    const float* a1d = (const float*)d_in[5];
    const float* b1  = (const float*)d_in[6];
    const float* W2  = (const float*)d_in[7];
    const float* a2s = (const float*)d_in[8];
    const float* a2d = (const float*)d_in[9];
    const float* b2  = (const float*)d_in[10];
    float* out = (float*)d_out;

    const int M1  = in_sizes[6];            // 256
    const int Fin = in_sizes[3] / M1;       // 128
    const int N   = in_sizes[0] / Fin;      // 50000
    const int E   = in_sizes[1] / 2;        // 800000
    const int Ep  = in_sizes[2] / 2;        // 100000
    const int M2  = in_sizes[10];           // 128
    const int Etot = E + N;
    const int NT  = (N + STILE - 1) / STILE;   // scan tiles (13)

    // workspace layout (16B-aligned sections)
    unsigned short* hbf  = (unsigned short*)d_ws;         // N*M1 bf16 gather table
    unsigned short* h1bf = hbf + (size_t)N * M1;          // N*M1 bf16 h1
    float* zbuf    = (float*)(h1bf + (size_t)N * M1);     // N*M2 f32 z
    float* as_     = zbuf + (size_t)N * M2;               // N*2
    float* ad_     = as_ + (size_t)N * 2;                 // N*2
    int*   deg     = (int*)(ad_ + (size_t)N * 2);         // NT*STILE (padded)
    int*   rowptr  = deg + (size_t)NT * STILE;            // NT*STILE (padded; rowptr[N] valid)
    int*   cursor  = rowptr + (size_t)NT * STILE;         // NT*STILE (padded)
    int*   tsum    = cursor + (size_t)NT * STILE;         // 64
    int*   csr_src = tsum + 64;                           // Etot
    unsigned short* wt1 = (unsigned short*)(csr_src + Etot);   // M1*Fin bf16 (W1^T)
    unsigned short* wt2 = wt1 + (size_t)M1 * Fin;              // M2*M1 bf16 (W2^T)

    dim3 blk256(256);

    // ---- node 1: zero deg ----
    hipMemsetAsync(deg, 0, (size_t)NT * STILE * sizeof(int), stream);

    // ---- node 2: {W prep || histogram} ----
    int nPrepBlk = (M1 * Fin + M2 * M1 + 255) / 256;
    int nHistBlk = (Etot + 255) / 256;
    k_prep_hist<<<nPrepBlk + nHistBlk, blk256, 0, stream>>>(
        W1, wt1, Fin, M1, W2, wt2, M1, M2, nPrepBlk, ei, E, N, deg);

    // ---- node 3: {GEMM L1 || scan_part} ----
    int GB = (N + 63) / 64;
    k_gemm1_scan<<<GB + NT, blk256, 0, stream>>>(
        x, wt1, hbf, as_, ad_, a1s, a1d, N, GB, deg, tsum);

    // ---- node 4-5: scan_final, fill ----
    scan_final<<<NT, blk256, 0, stream>>>(deg, tsum, rowptr, cursor);
    fill_kernel<<<nHistBlk, blk256, 0, stream>>>(ei, E, N, rowptr, cursor, csr_src);

    // ---- node 6: attn L1 -> bf16 h1 ----
    fused_attn_agg<256, 128, unsigned short><<<(N + 3) / 4, blk256, 0, stream>>>(
        rowptr, csr_src, as_, ad_, hbf, b1, h1bf, N, 1);

    // ---- node 7: GEMM L2 ----
    k_gemm2<<<(N + 63) / 64, blk256, 0, stream>>>(
        h1bf, wt2, hbf, as_, ad_, a2s, a2d, N);

    // ---- node 8: attn L2 -> f32 z ----
    fused_attn_agg<128, 64, float><<<(N + 3) / 4, blk256, 0, stream>>>(
        rowptr, csr_src, as_, ad_, hbf, b2, zbuf, N, 0);

    // ---- node 9: decode (wave per 2 edges) ----
    {
        int waves = (Ep + 1) / 2;
        decode_kernel<<<(waves * 64 + 255) / 256, blk256, 0, stream>>>(
            pei, Ep, zbuf, M2, out);
    }
}

// Round 15
// 239.189 us; speedup vs baseline: 7.1535x; 1.0154x over previous
//
#include <hip/hip_runtime.h>

#define NEG_SLOPE 0.2f
#define EPS_F 1e-16f
#define STILE 4096

typedef short short8 __attribute__((ext_vector_type(8)));
typedef float f32x4 __attribute__((ext_vector_type(4)));

// round-to-nearest-even f32 -> bf16 (finite inputs)
__device__ __forceinline__ unsigned short f2bf(float x) {
    unsigned u = __float_as_uint(x);
    return (unsigned short)((u + 0x7FFFu + ((u >> 16) & 1u)) >> 16);
}
__device__ __forceinline__ float bflo(unsigned q) { return __uint_as_float(q << 16); }
__device__ __forceinline__ float bfhi(unsigned q) { return __uint_as_float(q & 0xFFFF0000u); }

// ================= device bodies =================

// GEMM body: Y_bf16[N,MB] = X[N,K] @ Wt^T; Wt[MB][K] staged in LDS (row pad +8 shorts).
template<int MB, int K, typename TIN>
__device__ __forceinline__ void gemm_body(
        const TIN* __restrict__ X, const unsigned short* __restrict__ Wt,
        unsigned short* __restrict__ Y, float* __restrict__ as_out,
        float* __restrict__ ad_out, const float* __restrict__ a_srcf,
        const float* __restrict__ a_dstf, int N, int bid,
        unsigned short* lds) {
    constexpr int NT_ = MB / 16;
    constexpr int C   = MB / 2;
    constexpr int KS  = K / 32;
    constexpr int KP  = K + 8;
    int tid  = threadIdx.x;
    int w    = tid >> 6, lane = tid & 63;
    int li   = lane & 15, kc = lane >> 4;
    int n0   = bid * 64 + w * 16;
    int arow = min(n0 + li, N - 1);

    constexpr int CHUNKS = MB * K / 8;
#pragma unroll
    for (int c = 0; c < CHUNKS / 256; ++c) {
        int id = tid + c * 256;
        int m = id / (K / 8), k8 = id % (K / 8);
        *(uint4*)&lds[m * KP + k8 * 8] = *(const uint4*)&Wt[m * K + k8 * 8];
    }
    short8 a[KS];
#pragma unroll
    for (int ks = 0; ks < KS; ++ks) {
        if constexpr (sizeof(TIN) == 4) {
            const float* xp = (const float*)X + (size_t)arow * K + ks * 32 + kc * 8;
            float4 xa = *(const float4*)xp;
            float4 xb = *(const float4*)(xp + 4);
            a[ks][0] = (short)f2bf(xa.x); a[ks][1] = (short)f2bf(xa.y);
            a[ks][2] = (short)f2bf(xa.z); a[ks][3] = (short)f2bf(xa.w);
            a[ks][4] = (short)f2bf(xb.x); a[ks][5] = (short)f2bf(xb.y);
            a[ks][6] = (short)f2bf(xb.z); a[ks][7] = (short)f2bf(xb.w);
        } else {
            a[ks] = *(const short8*)((const unsigned short*)X + (size_t)arow * K + ks * 32 + kc * 8);
        }
    }
    __syncthreads();

    f32x4 acc[NT_];
#pragma unroll
    for (int ct = 0; ct < NT_; ++ct) acc[ct] = (f32x4){0.f, 0.f, 0.f, 0.f};
#pragma unroll
    for (int ct = 0; ct < NT_; ++ct) {
        const unsigned short* wb = lds + (ct * 16 + li) * KP + kc * 8;
#pragma unroll
        for (int ks = 0; ks < KS; ++ks) {
            short8 b = *(const short8*)(wb + ks * 32);
            acc[ct] = __builtin_amdgcn_mfma_f32_16x16x32_bf16(a[ks], b, acc[ct], 0, 0, 0);
        }
    }

    float av[NT_], dv[NT_];
#pragma unroll
    for (int ct = 0; ct < NT_; ++ct) {
        av[ct] = a_srcf[ct * 16 + li];
        dv[ct] = a_dstf[ct * 16 + li];
    }
    int row_base = n0 + kc * 4;
#pragma unroll
    for (int r = 0; r < 4; ++r) {
        int n = row_base + r;
        float vs0 = 0.f, vs1 = 0.f, vd0 = 0.f, vd1 = 0.f;
#pragma unroll
        for (int ct = 0; ct < NT_; ++ct) {
            float v = acc[ct][r];
            if (ct * 16 < C) { vs0 = fmaf(v, av[ct], vs0); vd0 = fmaf(v, dv[ct], vd0); }
            else             { vs1 = fmaf(v, av[ct], vs1); vd1 = fmaf(v, dv[ct], vd1); }
        }
#pragma unroll
        for (int off = 1; off < 16; off <<= 1) {
            vs0 += __shfl_xor(vs0, off);
            vs1 += __shfl_xor(vs1, off);
            vd0 += __shfl_xor(vd0, off);
            vd1 += __shfl_xor(vd1, off);
        }
        if (n < N) {
            if (li == 0) {
                as_out[n * 2] = vs0; as_out[n * 2 + 1] = vs1;
                ad_out[n * 2] = vd0; ad_out[n * 2 + 1] = vd1;
            }
#pragma unroll
            for (int ct = 0; ct < NT_; ++ct)
                Y[(size_t)n * MB + ct * 16 + li] = f2bf(acc[ct][r]);
        }
    }
}

__device__ __forceinline__ void scan_part_body(const int* __restrict__ deg,
                                               int* __restrict__ tsum, int b) {
    __shared__ int wsh[4];
    int t = threadIdx.x;
    int base = b * STILE + t * 16;
    int sum = 0;
#pragma unroll
    for (int j = 0; j < 16; j += 4) {
        int4 q = *(const int4*)&deg[base + j];
        sum += q.x + q.y + q.z + q.w;
    }
#pragma unroll
    for (int off = 32; off; off >>= 1) sum += __shfl_down(sum, off);
    if ((t & 63) == 0) wsh[t >> 6] = sum;
    __syncthreads();
    if (t == 0) tsum[b] = wsh[0] + wsh[1] + wsh[2] + wsh[3];
}

__device__ __forceinline__ void fill_body(const int* __restrict__ ei, int E, int N,
                                          const int* __restrict__ rowptr,
                                          int* __restrict__ cursor,
                                          int* __restrict__ csr_src, int bid) {
    int e = bid * 256 + threadIdx.x;
    if (e >= E + N) return;
    int s, d;
    if (e < E) { s = ei[e]; d = ei[E + e]; } else { s = d = e - E; }
    int pos = atomicAdd(&cursor[d], 1);
    csr_src[rowptr[d] + pos] = s;
}

// ================= kernels =================

__global__ void k_prep_hist(const float* __restrict__ W1, unsigned short* __restrict__ Wt1,
                            int K1, int M1,
                            const float* __restrict__ W2, unsigned short* __restrict__ Wt2,
                            int K2, int M2, int nPrepBlk,
                            const int* __restrict__ ei, int E, int N,
                            int* __restrict__ deg) {
    if ((int)blockIdx.x < nPrepBlk) {
        int i = blockIdx.x * 256 + threadIdx.x;
        int n1 = M1 * K1;
        if (i < n1) {
            int m = i / K1, k = i - m * K1;
            Wt1[i] = f2bf(W1[(size_t)k * M1 + m]);
        } else {
            int j = i - n1;
            if (j < M2 * K2) {
                int m = j / K2, k = j - m * K2;
                Wt2[j] = f2bf(W2[(size_t)k * M2 + m]);
            }
        }
    } else {
        int e = (blockIdx.x - nPrepBlk) * 256 + threadIdx.x;
        if (e >= E + N) return;
        int d = (e < E) ? ei[E + e] : e - E;
        atomicAdd(&deg[d], 1);
    }
}

__global__ __launch_bounds__(256) void k_scan_part(const int* __restrict__ deg,
                                                   int* __restrict__ tsum) {
    scan_part_body(deg, tsum, blockIdx.x);
}

__global__ __launch_bounds__(256) void scan_final(const int* __restrict__ deg,
                                                  const int* __restrict__ tsum,
                                                  int* __restrict__ rowptr,
                                                  int* __restrict__ cursor) {
    int b = blockIdx.x, t = threadIdx.x, lane = t & 63, wid = t >> 6;
    int base = b * STILE + t * 16;
    int tpre = 0;
    for (int j = 0; j < b; ++j) tpre += tsum[j];
    int v[16];
    int sum = 0;
#pragma unroll
    for (int j = 0; j < 16; j += 4) {
        int4 q = *(const int4*)&deg[base + j];
        v[j] = q.x; v[j + 1] = q.y; v[j + 2] = q.z; v[j + 3] = q.w;
        sum += q.x + q.y + q.z + q.w;
    }
    int x = sum;
#pragma unroll
    for (int off = 1; off < 64; off <<= 1) {
        int y = __shfl_up(x, off);
        if (lane >= off) x += y;
    }
    __shared__ int wtot[4];
    if (lane == 63) wtot[wid] = x;
    __syncthreads();
    int woff = 0;
    for (int wi = 0; wi < wid; ++wi) woff += wtot[wi];
    int run = tpre + woff + (x - sum);
    int outv[16];
#pragma unroll
    for (int j = 0; j < 16; ++j) { outv[j] = run; run += v[j]; }
#pragma unroll
    for (int j = 0; j < 16; j += 4) {
        *(int4*)&rowptr[base + j] = make_int4(outv[j], outv[j+1], outv[j+2], outv[j+3]);
        *(int4*)&cursor[base + j] = make_int4(0, 0, 0, 0);
    }
}

// {GEMM L1 || CSR fill} — both depend only on completed node-2/3/4 work
__global__ __launch_bounds__(256) void k_gemm1_fill(
        const float* __restrict__ X, const unsigned short* __restrict__ Wt,
        unsigned short* __restrict__ Y, float* __restrict__ as_out,
        float* __restrict__ ad_out, const float* __restrict__ a_srcf,
        const float* __restrict__ a_dstf, int N, int GB,
        const int* __restrict__ ei, int E,
        const int* __restrict__ rowptr, int* __restrict__ cursor,
        int* __restrict__ csr_src) {
    __shared__ __align__(16) unsigned short lds[256 * (128 + 8)];
    if ((int)blockIdx.x < GB)
        gemm_body<256, 128, float>(X, Wt, Y, as_out, ad_out, a_srcf, a_dstf, N,
                                   blockIdx.x, lds);
    else
        fill_body(ei, E, N, rowptr, cursor, csr_src, blockIdx.x - GB);
}

__global__ __launch_bounds__(256) void k_gemm2(
        const unsigned short* __restrict__ X, const unsigned short* __restrict__ Wt,
        unsigned short* __restrict__ Y, float* __restrict__ as_out,
        float* __restrict__ ad_out, const float* __restrict__ a_srcf,
        const float* __restrict__ a_dstf, int N) {
    __shared__ __align__(16) unsigned short lds[128 * (256 + 8)];
    gemm_body<128, 256, unsigned short>(X, Wt, Y, as_out, ad_out, a_srcf, a_dstf, N,
                                        blockIdx.x, lds);
}

// ---------------- fused attn+agg: wave/node, no-max softmax, LDS b128 broadcast ----------------
template<int M, int C, typename TOUT>
__global__ __launch_bounds__(256) void fused_attn_agg(
        const int* __restrict__ rowptr, const int* __restrict__ csr_src,
        const float* __restrict__ as_, const float* __restrict__ ad_,
        const unsigned short* __restrict__ hfeat, const float* __restrict__ bias,
        TOUT* __restrict__ outp, int N, int do_relu) {
    constexpr int VEC = M / 64;   // 4 (L1) or 2 (L2)
    __shared__ __align__(16) uint2 pb0[4][64];  // {byte_off, p_head0}
    __shared__ __align__(16) uint2 pb1[4][64];  // {byte_off, p_head1}
    int n    = (blockIdx.x * blockDim.x + threadIdx.x) >> 6;
    int lane = threadIdx.x & 63;
    int w    = (threadIdx.x >> 6) & 3;
    if (n >= N) return;
    int cbase = lane * VEC;
    int hh    = cbase / C;
    int r0 = rowptr[n], r1 = rowptr[n + 1];
    const float2* as2 = (const float2*)as_;
    float2 adv = ((const float2*)ad_)[n];
    float sa0 = 0.f, sa1 = 0.f;
    float acc[VEC];
#pragma unroll
    for (int v = 0; v < VEC; ++v) acc[v] = 0.f;
    const uint2* ap = (hh == 0) ? pb0[w] : pb1[w];
    const char* hbc = (const char*)hfeat + (size_t)cbase * 2;

    for (int base = r0; base < r1; base += 64) {
        int cnt = min(64, r1 - base);
        int srcl = 0;
        float sc0 = -INFINITY, sc1 = -INFINITY;
        if (lane < cnt) {
            srcl = csr_src[base + lane];
            float2 asv = as2[srcl];
            float e0 = asv.x + adv.x;
            float e1 = asv.y + adv.y;
            sc0 = (e0 > 0.f) ? e0 : NEG_SLOPE * e0;
            sc1 = (e1 > 0.f) ? e1 : NEG_SLOPE * e1;
        }
        float p0 = expf(sc0), p1 = expf(sc1);   // 0 for tail lanes
        sa0 += p0; sa1 += p1;
        unsigned off = (unsigned)srcl * (M * 2);
        pb0[w][lane] = make_uint2(off, __float_as_uint(p0));
        pb1[w][lane] = make_uint2(off, __float_as_uint(p1));
        for (int e = 0; e < cnt; e += 2) {
            uint4 qq = *(const uint4*)&ap[e];
            float pa = __uint_as_float(qq.y);
            float pc = __uint_as_float(qq.w);
            const char* hp0 = hbc + qq.x;
            const char* hp1 = hbc + qq.z;
            if constexpr (VEC == 4) {
                uint2 g0 = *(const uint2*)hp0;
                uint2 g1 = *(const uint2*)hp1;
                acc[0] += pa * bflo(g0.x); acc[1] += pa * bfhi(g0.x);
                acc[2] += pa * bflo(g0.y); acc[3] += pa * bfhi(g0.y);
                acc[0] += pc * bflo(g1.x); acc[1] += pc * bfhi(g1.x);
                acc[2] += pc * bflo(g1.y); acc[3] += pc * bfhi(g1.y);
            } else {
                unsigned g0 = *(const unsigned*)hp0;
                unsigned g1 = *(const unsigned*)hp1;
                acc[0] += pa * bflo(g0); acc[1] += pa * bfhi(g0);
                acc[0] += pc * bflo(g1); acc[1] += pc * bfhi(g1);
            }
        }
    }
#pragma unroll
    for (int off = 32; off; off >>= 1) {
        sa0 += __shfl_xor(sa0, off);
        sa1 += __shfl_xor(sa1, off);
    }
    float ssum = (hh == 0) ? sa0 : sa1;
    float inv = 1.f / (ssum + EPS_F);
    float o[VEC];
#pragma unroll
    for (int v = 0; v < VEC; ++v) {
        float val = acc[v] * inv + bias[cbase + v];
        o[v] = do_relu ? fmaxf(val, 0.f) : val;
    }
    if constexpr (sizeof(TOUT) == 2) {
        unsigned short* op = (unsigned short*)outp + (size_t)n * M + cbase;
        if constexpr (VEC == 4) {
            uint2 pk;
            pk.x = (unsigned)f2bf(o[0]) | ((unsigned)f2bf(o[1]) << 16);
            pk.y = (unsigned)f2bf(o[2]) | ((unsigned)f2bf(o[3]) << 16);
            *(uint2*)op = pk;
        } else {
            *(unsigned*)op = (unsigned)f2bf(o[0]) | ((unsigned)f2bf(o[1]) << 16);
        }
    } else {
        float* op = (float*)outp + (size_t)n * M + cbase;
        if constexpr (VEC == 4) *(float4*)op = make_float4(o[0], o[1], o[2], o[3]);
        else                    *(float2*)op = make_float2(o[0], o[1]);
    }
}

// ---------------- decode v3: one wave per 2 edges, bf16 z ----------------
__global__ void decode_kernel(const int* __restrict__ pei, int Ep,
                              const unsigned short* __restrict__ z, int D,
                              float* __restrict__ out) {
    int wv   = (blockIdx.x * blockDim.x + threadIdx.x) >> 6;
    int lane = threadIdx.x & 63;
    int half = lane >> 5, sl = lane & 31;   // 32 lanes per edge; sl*4 covers D=128
    int e  = wv * 2 + half;
    int ec = min(e, Ep - 1);
    int a = pei[ec], b = pei[Ep + ec];
    uint2 qa = *(const uint2*)(z + (size_t)a * D + sl * 4);
    uint2 qb = *(const uint2*)(z + (size_t)b * D + sl * 4);
    float s = bflo(qa.x) * bflo(qb.x) + bfhi(qa.x) * bfhi(qb.x)
            + bflo(qa.y) * bflo(qb.y) + bfhi(qa.y) * bfhi(qb.y);
#pragma unroll
    for (int off = 16; off; off >>= 1) s += __shfl_xor(s, off);
    if (sl == 0 && e < Ep) out[e] = s;
}

extern "C" void kernel_launch(void* const* d_in, const int* in_sizes, int n_in,
                              void* d_out, int out_size, void* d_ws, size_t ws_size,
                              hipStream_t stream) {
    const float* x   = (const float*)d_in[0];
    const int*   ei  = (const int*)d_in[1];
    const int*   pei = (const int*)d_in[2];
    const float* W1  = (const float*)d_in[3];
    const float* a1s = (const float*)d_in[4];
    const float* a1d = (const float*)d_in[5];
    const float* b1  = (const float*)d_in[6];
    const float* W2  = (const float*)d_in[7];
    const float* a2s = (const float*)d_in[8];
    const float* a2d = (const float*)d_in[9];
    const float* b2  = (const float*)d_in[10];
    float* out = (float*)d_out;

    const int M1  = in_sizes[6];            // 256
    const int Fin = in_sizes[3] / M1;       // 128
    const int N   = in_sizes[0] / Fin;      // 50000
    const int E   = in_sizes[1] / 2;        // 800000
    const int Ep  = in_sizes[2] / 2;        // 100000
    const int M2  = in_sizes[10];           // 128
    const int Etot = E + N;
    const int NT  = (N + STILE - 1) / STILE;   // scan tiles (13)

    // workspace layout (16B-aligned sections)
    unsigned short* hbf  = (unsigned short*)d_ws;         // N*M1 bf16 gather table
    unsigned short* h1bf = hbf + (size_t)N * M1;          // N*M1 bf16 h1
    unsigned short* zbf  = h1bf + (size_t)N * M1;         // N*M2 bf16 z
    float* as_     = (float*)(zbf + (size_t)N * M2);      // N*2
    float* ad_     = as_ + (size_t)N * 2;                 // N*2
    int*   deg     = (int*)(ad_ + (size_t)N * 2);         // NT*STILE (padded)
    int*   rowptr  = deg + (size_t)NT * STILE;            // NT*STILE (padded; rowptr[N] valid)
    int*   cursor  = rowptr + (size_t)NT * STILE;         // NT*STILE (padded)
    int*   tsum    = cursor + (size_t)NT * STILE;         // 64
    int*   csr_src = tsum + 64;                           // Etot
    unsigned short* wt1 = (unsigned short*)(csr_src + Etot);   // M1*Fin bf16 (W1^T)
    unsigned short* wt2 = wt1 + (size_t)M1 * Fin;              // M2*M1 bf16 (W2^T)

    dim3 blk256(256);

    // ---- node 1: zero deg ----
    hipMemsetAsync(deg, 0, (size_t)NT * STILE * sizeof(int), stream);

    // ---- node 2: {W prep || histogram} ----
    int nPrepBlk = (M1 * Fin + M2 * M1 + 255) / 256;
    int nHistBlk = (Etot + 255) / 256;
    k_prep_hist<<<nPrepBlk + nHistBlk, blk256, 0, stream>>>(
        W1, wt1, Fin, M1, W2, wt2, M1, M2, nPrepBlk, ei, E, N, deg);

    // ---- node 3-4: scan ----
    k_scan_part<<<NT, blk256, 0, stream>>>(deg, tsum);
    scan_final<<<NT, blk256, 0, stream>>>(deg, tsum, rowptr, cursor);

    // ---- node 5: {GEMM L1 || CSR fill} ----
    int GB = (N + 63) / 64;
    k_gemm1_fill<<<GB + nHistBlk, blk256, 0, stream>>>(
        x, wt1, hbf, as_, ad_, a1s, a1d, N, GB,
        ei, E, rowptr, cursor, csr_src);

    // ---- node 6: attn L1 -> bf16 h1 ----
    fused_attn_agg<256, 128, unsigned short><<<(N + 3) / 4, blk256, 0, stream>>>(
        rowptr, csr_src, as_, ad_, hbf, b1, h1bf, N, 1);

    // ---- node 7: GEMM L2 ----
    k_gemm2<<<(N + 63) / 64, blk256, 0, stream>>>(
        h1bf, wt2, hbf, as_, ad_, a2s, a2d, N);

    // ---- node 8: attn L2 -> bf16 z ----
    fused_attn_agg<128, 64, unsigned short><<<(N + 3) / 4, blk256, 0, stream>>>(
        rowptr, csr_src, as_, ad_, hbf, b2, zbf, N, 0);

    // ---- node 9: decode (bf16 z, wave per 2 edges) ----
    {
        int waves = (Ep + 1) / 2;
        decode_kernel<<<(waves * 64 + 255) / 256, blk256, 0, stream>>>(
            pei, Ep, zbf, M2, out);
    }
}

// Round 16
// 208.403 us; speedup vs baseline: 8.2102x; 1.1477x over previous
//
#include <hip/hip_runtime.h>

#define NEG_SLOPE 0.2f
#define EPS_F 1e-16f
#define STILE 4096

typedef short short8 __attribute__((ext_vector_type(8)));
typedef float f32x4 __attribute__((ext_vector_type(4)));

// round-to-nearest-even f32 -> bf16 (finite inputs)
__device__ __forceinline__ unsigned short f2bf(float x) {
    unsigned u = __float_as_uint(x);
    return (unsigned short)((u + 0x7FFFu + ((u >> 16) & 1u)) >> 16);
}
__device__ __forceinline__ float bflo(unsigned q) { return __uint_as_float(q << 16); }
__device__ __forceinline__ float bfhi(unsigned q) { return __uint_as_float(q & 0xFFFF0000u); }

// ================= device bodies =================

// GEMM body: Y_bf16[N,MB] = X[N,K] @ Wt^T; Wt[MB][K] staged in LDS (row pad +8 shorts).
template<int MB, int K, typename TIN>
__device__ __forceinline__ void gemm_body(
        const TIN* __restrict__ X, const unsigned short* __restrict__ Wt,
        unsigned short* __restrict__ Y, float* __restrict__ as_out,
        float* __restrict__ ad_out, const float* __restrict__ a_srcf,
        const float* __restrict__ a_dstf, int N, int bid,
        unsigned short* lds) {
    constexpr int NT_ = MB / 16;
    constexpr int C   = MB / 2;
    constexpr int KS  = K / 32;
    constexpr int KP  = K + 8;
    int tid  = threadIdx.x;
    int w    = tid >> 6, lane = tid & 63;
    int li   = lane & 15, kc = lane >> 4;
    int n0   = bid * 64 + w * 16;
    int arow = min(n0 + li, N - 1);

    constexpr int CHUNKS = MB * K / 8;
#pragma unroll
    for (int c = 0; c < CHUNKS / 256; ++c) {
        int id = tid + c * 256;
        int m = id / (K / 8), k8 = id % (K / 8);
        *(uint4*)&lds[m * KP + k8 * 8] = *(const uint4*)&Wt[m * K + k8 * 8];
    }
    short8 a[KS];
#pragma unroll
    for (int ks = 0; ks < KS; ++ks) {
        if constexpr (sizeof(TIN) == 4) {
            const float* xp = (const float*)X + (size_t)arow * K + ks * 32 + kc * 8;
            float4 xa = *(const float4*)xp;
            float4 xb = *(const float4*)(xp + 4);
            a[ks][0] = (short)f2bf(xa.x); a[ks][1] = (short)f2bf(xa.y);
            a[ks][2] = (short)f2bf(xa.z); a[ks][3] = (short)f2bf(xa.w);
            a[ks][4] = (short)f2bf(xb.x); a[ks][5] = (short)f2bf(xb.y);
            a[ks][6] = (short)f2bf(xb.z); a[ks][7] = (short)f2bf(xb.w);
        } else {
            a[ks] = *(const short8*)((const unsigned short*)X + (size_t)arow * K + ks * 32 + kc * 8);
        }
    }
    __syncthreads();

    f32x4 acc[NT_];
#pragma unroll
    for (int ct = 0; ct < NT_; ++ct) acc[ct] = (f32x4){0.f, 0.f, 0.f, 0.f};
#pragma unroll
    for (int ct = 0; ct < NT_; ++ct) {
        const unsigned short* wb = lds + (ct * 16 + li) * KP + kc * 8;
#pragma unroll
        for (int ks = 0; ks < KS; ++ks) {
            short8 b = *(const short8*)(wb + ks * 32);
            acc[ct] = __builtin_amdgcn_mfma_f32_16x16x32_bf16(a[ks], b, acc[ct], 0, 0, 0);
        }
    }

    float av[NT_], dv[NT_];
#pragma unroll
    for (int ct = 0; ct < NT_; ++ct) {
        av[ct] = a_srcf[ct * 16 + li];
        dv[ct] = a_dstf[ct * 16 + li];
    }
    int row_base = n0 + kc * 4;
#pragma unroll
    for (int r = 0; r < 4; ++r) {
        int n = row_base + r;
        float vs0 = 0.f, vs1 = 0.f, vd0 = 0.f, vd1 = 0.f;
#pragma unroll
        for (int ct = 0; ct < NT_; ++ct) {
            float v = acc[ct][r];
            if (ct * 16 < C) { vs0 = fmaf(v, av[ct], vs0); vd0 = fmaf(v, dv[ct], vd0); }
            else             { vs1 = fmaf(v, av[ct], vs1); vd1 = fmaf(v, dv[ct], vd1); }
        }
#pragma unroll
        for (int off = 1; off < 16; off <<= 1) {
            vs0 += __shfl_xor(vs0, off);
            vs1 += __shfl_xor(vs1, off);
            vd0 += __shfl_xor(vd0, off);
            vd1 += __shfl_xor(vd1, off);
        }
        if (n < N) {
            if (li == 0) {
                as_out[n * 2] = vs0; as_out[n * 2 + 1] = vs1;
                ad_out[n * 2] = vd0; ad_out[n * 2 + 1] = vd1;
            }
#pragma unroll
            for (int ct = 0; ct < NT_; ++ct)
                Y[(size_t)n * MB + ct * 16 + li] = f2bf(acc[ct][r]);
        }
    }
}

__device__ __forceinline__ void scan_part_body(const int* __restrict__ deg,
                                               int* __restrict__ tsum, int b) {
    __shared__ int wsh[4];
    int t = threadIdx.x;
    int base = b * STILE + t * 16;
    int sum = 0;
#pragma unroll
    for (int j = 0; j < 16; j += 4) {
        int4 q = *(const int4*)&deg[base + j];
        sum += q.x + q.y + q.z + q.w;
    }
#pragma unroll
    for (int off = 32; off; off >>= 1) sum += __shfl_down(sum, off);
    if ((t & 63) == 0) wsh[t >> 6] = sum;
    __syncthreads();
    if (t == 0) tsum[b] = wsh[0] + wsh[1] + wsh[2] + wsh[3];
}

// ================= kernels =================

// {W prep || histogram(+pos)} — hist stores each edge's within-segment position
__global__ void k_prep_hist(const float* __restrict__ W1, unsigned short* __restrict__ Wt1,
                            int K1, int M1,
                            const float* __restrict__ W2, unsigned short* __restrict__ Wt2,
                            int K2, int M2, int nPrepBlk,
                            const int* __restrict__ ei, int E, int N,
                            int* __restrict__ deg, int* __restrict__ pos) {
    if ((int)blockIdx.x < nPrepBlk) {
        int i = blockIdx.x * 256 + threadIdx.x;
        int n1 = M1 * K1;
        if (i < n1) {
            int m = i / K1, k = i - m * K1;
            Wt1[i] = f2bf(W1[(size_t)k * M1 + m]);
        } else {
            int j = i - n1;
            if (j < M2 * K2) {
                int m = j / K2, k = j - m * K2;
                Wt2[j] = f2bf(W2[(size_t)k * M2 + m]);
            }
        }
    } else {
        int e = (blockIdx.x - nPrepBlk) * 256 + threadIdx.x;
        if (e >= E + N) return;
        int d = (e < E) ? ei[E + e] : e - E;
        pos[e] = atomicAdd(&deg[d], 1);
    }
}

// {GEMM L1 || scan_part} — gemm needs Wt1 (done), scan needs deg (done)
__global__ __launch_bounds__(256) void k_gemm1_scan(
        const float* __restrict__ X, const unsigned short* __restrict__ Wt,
        unsigned short* __restrict__ Y, float* __restrict__ as_out,
        float* __restrict__ ad_out, const float* __restrict__ a_srcf,
        const float* __restrict__ a_dstf, int N, int GB,
        const int* __restrict__ deg, int* __restrict__ tsum) {
    __shared__ __align__(16) unsigned short lds[256 * (128 + 8)];
    if ((int)blockIdx.x < GB)
        gemm_body<256, 128, float>(X, Wt, Y, as_out, ad_out, a_srcf, a_dstf, N,
                                   blockIdx.x, lds);
    else
        scan_part_body(deg, tsum, blockIdx.x - GB);
}

__global__ __launch_bounds__(256) void scan_final(const int* __restrict__ deg,
                                                  const int* __restrict__ tsum,
                                                  int* __restrict__ rowptr) {
    int b = blockIdx.x, t = threadIdx.x, lane = t & 63, wid = t >> 6;
    int base = b * STILE + t * 16;
    int tpre = 0;
    for (int j = 0; j < b; ++j) tpre += tsum[j];
    int v[16];
    int sum = 0;
#pragma unroll
    for (int j = 0; j < 16; j += 4) {
        int4 q = *(const int4*)&deg[base + j];
        v[j] = q.x; v[j + 1] = q.y; v[j + 2] = q.z; v[j + 3] = q.w;
        sum += q.x + q.y + q.z + q.w;
    }
    int x = sum;
#pragma unroll
    for (int off = 1; off < 64; off <<= 1) {
        int y = __shfl_up(x, off);
        if (lane >= off) x += y;
    }
    __shared__ int wtot[4];
    if (lane == 63) wtot[wid] = x;
    __syncthreads();
    int woff = 0;
    for (int wi = 0; wi < wid; ++wi) woff += wtot[wi];
    int run = tpre + woff + (x - sum);
    int outv[16];
#pragma unroll
    for (int j = 0; j < 16; ++j) { outv[j] = run; run += v[j]; }
#pragma unroll
    for (int j = 0; j < 16; j += 4)
        *(int4*)&rowptr[base + j] = make_int4(outv[j], outv[j+1], outv[j+2], outv[j+3]);
}

// atomic-free CSR fill: position precomputed by hist
__global__ void fill_kernel(const int* __restrict__ ei, int E, int N,
                            const int* __restrict__ rowptr, const int* __restrict__ pos,
                            int* __restrict__ csr_src) {
    int e = blockIdx.x * blockDim.x + threadIdx.x;
    if (e >= E + N) return;
    int s, d;
    if (e < E) { s = ei[e]; d = ei[E + e]; } else { s = d = e - E; }
    csr_src[rowptr[d] + pos[e]] = s;
}

__global__ __launch_bounds__(256) void k_gemm2(
        const unsigned short* __restrict__ X, const unsigned short* __restrict__ Wt,
        unsigned short* __restrict__ Y, float* __restrict__ as_out,
        float* __restrict__ ad_out, const float* __restrict__ a_srcf,
        const float* __restrict__ a_dstf, int N) {
    __shared__ __align__(16) unsigned short lds[128 * (256 + 8)];
    gemm_body<128, 256, unsigned short>(X, Wt, Y, as_out, ad_out, a_srcf, a_dstf, N,
                                        blockIdx.x, lds);
}

// ---------------- fused attn+agg: wave/node, no-max softmax, LDS b128 broadcast ----------------
template<int M, int C, typename TOUT>
__global__ __launch_bounds__(256) void fused_attn_agg(
        const int* __restrict__ rowptr, const int* __restrict__ csr_src,
        const float* __restrict__ as_, const float* __restrict__ ad_,
        const unsigned short* __restrict__ hfeat, const float* __restrict__ bias,
        TOUT* __restrict__ outp, int N, int do_relu) {
    constexpr int VEC = M / 64;   // 4 (L1) or 2 (L2)
    __shared__ __align__(16) uint2 pb0[4][64];  // {byte_off, p_head0}
    __shared__ __align__(16) uint2 pb1[4][64];  // {byte_off, p_head1}
    int n    = (blockIdx.x * blockDim.x + threadIdx.x) >> 6;
    int lane = threadIdx.x & 63;
    int w    = (threadIdx.x >> 6) & 3;
    if (n >= N) return;
    int cbase = lane * VEC;
    int hh    = cbase / C;
    int r0 = rowptr[n], r1 = rowptr[n + 1];
    const float2* as2 = (const float2*)as_;
    float2 adv = ((const float2*)ad_)[n];
    float sa0 = 0.f, sa1 = 0.f;
    float acc[VEC];
#pragma unroll
    for (int v = 0; v < VEC; ++v) acc[v] = 0.f;
    const uint2* ap = (hh == 0) ? pb0[w] : pb1[w];
    const char* hbc = (const char*)hfeat + (size_t)cbase * 2;

    for (int base = r0; base < r1; base += 64) {
        int cnt = min(64, r1 - base);
        int srcl = 0;
        float sc0 = -INFINITY, sc1 = -INFINITY;
        if (lane < cnt) {
            srcl = csr_src[base + lane];
            float2 asv = as2[srcl];
            float e0 = asv.x + adv.x;
            float e1 = asv.y + adv.y;
            sc0 = (e0 > 0.f) ? e0 : NEG_SLOPE * e0;
            sc1 = (e1 > 0.f) ? e1 : NEG_SLOPE * e1;
        }
        float p0 = expf(sc0), p1 = expf(sc1);   // 0 for tail lanes
        sa0 += p0; sa1 += p1;
        unsigned off = (unsigned)srcl * (M * 2);
        pb0[w][lane] = make_uint2(off, __float_as_uint(p0));
        pb1[w][lane] = make_uint2(off, __float_as_uint(p1));
        for (int e = 0; e < cnt; e += 2) {
            uint4 qq = *(const uint4*)&ap[e];
            float pa = __uint_as_float(qq.y);
            float pc = __uint_as_float(qq.w);
            const char* hp0 = hbc + qq.x;
            const char* hp1 = hbc + qq.z;
            if constexpr (VEC == 4) {
                uint2 g0 = *(const uint2*)hp0;
                uint2 g1 = *(const uint2*)hp1;
                acc[0] += pa * bflo(g0.x); acc[1] += pa * bfhi(g0.x);
                acc[2] += pa * bflo(g0.y); acc[3] += pa * bfhi(g0.y);
                acc[0] += pc * bflo(g1.x); acc[1] += pc * bfhi(g1.x);
                acc[2] += pc * bflo(g1.y); acc[3] += pc * bfhi(g1.y);
            } else {
                unsigned g0 = *(const unsigned*)hp0;
                unsigned g1 = *(const unsigned*)hp1;
                acc[0] += pa * bflo(g0); acc[1] += pa * bfhi(g0);
                acc[0] += pc * bflo(g1); acc[1] += pc * bfhi(g1);
            }
        }
    }
#pragma unroll
    for (int off = 32; off; off >>= 1) {
        sa0 += __shfl_xor(sa0, off);
        sa1 += __shfl_xor(sa1, off);
    }
    float ssum = (hh == 0) ? sa0 : sa1;
    float inv = 1.f / (ssum + EPS_F);
    float o[VEC];
#pragma unroll
    for (int v = 0; v < VEC; ++v) {
        float val = acc[v] * inv + bias[cbase + v];
        o[v] = do_relu ? fmaxf(val, 0.f) : val;
    }
    if constexpr (sizeof(TOUT) == 2) {
        unsigned short* op = (unsigned short*)outp + (size_t)n * M + cbase;
        if constexpr (VEC == 4) {
            uint2 pk;
            pk.x = (unsigned)f2bf(o[0]) | ((unsigned)f2bf(o[1]) << 16);
            pk.y = (unsigned)f2bf(o[2]) | ((unsigned)f2bf(o[3]) << 16);
            *(uint2*)op = pk;
        } else {
            *(unsigned*)op = (unsigned)f2bf(o[0]) | ((unsigned)f2bf(o[1]) << 16);
        }
    } else {
        float* op = (float*)outp + (size_t)n * M + cbase;
        if constexpr (VEC == 4) *(float4*)op = make_float4(o[0], o[1], o[2], o[3]);
        else                    *(float2*)op = make_float2(o[0], o[1]);
    }
}

// ---------------- decode: one wave per 2 edges, bf16 z ----------------
__global__ void decode_kernel(const int* __restrict__ pei, int Ep,
                              const unsigned short* __restrict__ z, int D,
                              float* __restrict__ out) {
    int wv   = (blockIdx.x * blockDim.x + threadIdx.x) >> 6;
    int lane = threadIdx.x & 63;
    int half = lane >> 5, sl = lane & 31;   // 32 lanes per edge; sl*4 covers D=128
    int e  = wv * 2 + half;
    int ec = min(e, Ep - 1);
    int a = pei[ec], b = pei[Ep + ec];
    uint2 qa = *(const uint2*)(z + (size_t)a * D + sl * 4);
    uint2 qb = *(const uint2*)(z + (size_t)b * D + sl * 4);
    float s = bflo(qa.x) * bflo(qb.x) + bfhi(qa.x) * bfhi(qb.x)
            + bflo(qa.y) * bflo(qb.y) + bfhi(qa.y) * bfhi(qb.y);
#pragma unroll
    for (int off = 16; off; off >>= 1) s += __shfl_xor(s, off);
    if (sl == 0 && e < Ep) out[e] = s;
}

extern "C" void kernel_launch(void* const* d_in, const int* in_sizes, int n_in,
                              void* d_out, int out_size, void* d_ws, size_t ws_size,
                              hipStream_t stream) {
    const float* x   = (const float*)d_in[0];
    const int*   ei  = (const int*)d_in[1];
    const int*   pei = (const int*)d_in[2];
    const float* W1  = (const float*)d_in[3];
    const float* a1s = (const float*)d_in[4];
    const float* a1d = (const float*)d_in[5];
    const float* b1  = (const float*)d_in[6];
    const float* W2  = (const float*)d_in[7];
    const float* a2s = (const float*)d_in[8];
    const float* a2d = (const float*)d_in[9];
    const float* b2  = (const float*)d_in[10];
    float* out = (float*)d_out;

    const int M1  = in_sizes[6];            // 256
    const int Fin = in_sizes[3] / M1;       // 128
    const int N   = in_sizes[0] / Fin;      // 50000
    const int E   = in_sizes[1] / 2;        // 800000
    const int Ep  = in_sizes[2] / 2;        // 100000
    const int M2  = in_sizes[10];           // 128
    const int Etot = E + N;
    const int NT  = (N + STILE - 1) / STILE;   // scan tiles (13)

    // workspace layout (16B-aligned sections)
    unsigned short* hbf  = (unsigned short*)d_ws;         // N*M1 bf16 gather table
    unsigned short* h1bf = hbf + (size_t)N * M1;          // N*M1 bf16 h1
    unsigned short* zbf  = h1bf + (size_t)N * M1;         // N*M2 bf16 z
    float* as_     = (float*)(zbf + (size_t)N * M2);      // N*2
    float* ad_     = as_ + (size_t)N * 2;                 // N*2
    int*   deg     = (int*)(ad_ + (size_t)N * 2);         // NT*STILE (padded)
    int*   rowptr  = deg + (size_t)NT * STILE;            // NT*STILE (padded; rowptr[N] valid)
    int*   tsum    = rowptr + (size_t)NT * STILE;         // 64
    int*   pos     = tsum + 64;                           // Etot
    int*   csr_src = pos + Etot;                          // Etot
    unsigned short* wt1 = (unsigned short*)(csr_src + Etot);   // M1*Fin bf16 (W1^T)
    unsigned short* wt2 = wt1 + (size_t)M1 * Fin;              // M2*M1 bf16 (W2^T)

    dim3 blk256(256);

    // ---- node 1: zero deg ----
    hipMemsetAsync(deg, 0, (size_t)NT * STILE * sizeof(int), stream);

    // ---- node 2: {W prep || histogram(+pos)} ----
    int nPrepBlk = (M1 * Fin + M2 * M1 + 255) / 256;
    int nHistBlk = (Etot + 255) / 256;
    k_prep_hist<<<nPrepBlk + nHistBlk, blk256, 0, stream>>>(
        W1, wt1, Fin, M1, W2, wt2, M1, M2, nPrepBlk, ei, E, N, deg, pos);

    // ---- node 3: {GEMM L1 || scan_part} ----
    int GB = (N + 63) / 64;
    k_gemm1_scan<<<GB + NT, blk256, 0, stream>>>(
        x, wt1, hbf, as_, ad_, a1s, a1d, N, GB, deg, tsum);

    // ---- node 4: scan_final ----
    scan_final<<<NT, blk256, 0, stream>>>(deg, tsum, rowptr);

    // ---- node 5: atomic-free fill ----
    fill_kernel<<<nHistBlk, blk256, 0, stream>>>(ei, E, N, rowptr, pos, csr_src);

    // ---- node 6: attn L1 -> bf16 h1 ----
    fused_attn_agg<256, 128, unsigned short><<<(N + 3) / 4, blk256, 0, stream>>>(
        rowptr, csr_src, as_, ad_, hbf, b1, h1bf, N, 1);

    // ---- node 7: GEMM L2 ----
    k_gemm2<<<(N + 63) / 64, blk256, 0, stream>>>(
        h1bf, wt2, hbf, as_, ad_, a2s, a2d, N);

    // ---- node 8: attn L2 -> bf16 z ----
    fused_attn_agg<128, 64, unsigned short><<<(N + 3) / 4, blk256, 0, stream>>>(
        rowptr, csr_src, as_, ad_, hbf, b2, zbf, N, 0);

    // ---- node 9: decode (bf16 z, wave per 2 edges) ----
    {
        int waves = (Ep + 1) / 2;
        decode_kernel<<<(waves * 64 + 255) / 256, blk256, 0, stream>>>(
            pei, Ep, zbf, M2, out);
    }
}